// Round 1
// baseline (8457.776 us; speedup 1.0000x reference)
//
#include <hip/hip_runtime.h>
#include <math.h>

// ECMNet: B=2, F=2048, T=750, C=20, G=3, Tg=250, topK=93
namespace {
constexpr int kF = 2048;
constexpr int kT = 750;
constexpr int kC = 20;
constexpr int kTg = 250;
constexpr int kTop = 93;
}

__device__ __forceinline__ float leaky_act(float v) { return v > 0.f ? v : 0.01f * v; }

// ---------------------------------------------------------------------------
// conv k=3 pad=1 over length 750, fused bias + leaky. in/out: [2][2048][750]
// W: [co][ci][k] (co*6144 + ci*3 + k). 64co x 64t tile, 4x4 per thread.
// ---------------------------------------------------------------------------
__global__ __launch_bounds__(256) void conv_main_kernel(
    const float* __restrict__ in, const float* __restrict__ W,
    const float* __restrict__ bias, float* __restrict__ out) {
  __shared__ float sW[16][3][64];
  __shared__ float sX[16][68];
  const int b = blockIdx.z;
  const int co0 = blockIdx.y * 64;
  const int t0 = blockIdx.x * 64;
  const int tid = threadIdx.x;
  const int tx = tid & 15, ty = tid >> 4;
  float acc[4][4] = {};
  const float* inb = in + b * (kF * kT);
  for (int ci0 = 0; ci0 < kF; ci0 += 16) {
#pragma unroll
    for (int l = 0; l < 12; ++l) {
      int i = tid + l * 256;
      int kk = i % 48;  // (ci,k) pair, contiguous in W row
      int col = i / 48; // local co
      sW[kk / 3][kk % 3][col] =
          W[(co0 + col) * (kF * 3) + (ci0 + kk / 3) * 3 + (kk % 3)];
    }
#pragma unroll
    for (int l = 0; l < 5; ++l) {
      int i = tid + l * 256;
      if (i < 16 * 66) {
        int ci = i / 66, col = i % 66;
        int t = t0 - 1 + col;
        sX[ci][col] = (t >= 0 && t < kT) ? inb[(ci0 + ci) * kT + t] : 0.f;
      }
    }
    __syncthreads();
#pragma unroll
    for (int ci = 0; ci < 16; ++ci) {
      float xa[6];
#pragma unroll
      for (int m = 0; m < 6; ++m) xa[m] = sX[ci][tx * 4 + m];
#pragma unroll
      for (int k = 0; k < 3; ++k) {
        float a0 = sW[ci][k][ty * 4 + 0];
        float a1 = sW[ci][k][ty * 4 + 1];
        float a2 = sW[ci][k][ty * 4 + 2];
        float a3 = sW[ci][k][ty * 4 + 3];
#pragma unroll
        for (int j = 0; j < 4; ++j) {
          float xv = xa[j + k];
          acc[0][j] += a0 * xv;
          acc[1][j] += a1 * xv;
          acc[2][j] += a2 * xv;
          acc[3][j] += a3 * xv;
        }
      }
    }
    __syncthreads();
  }
#pragma unroll
  for (int i = 0; i < 4; ++i) {
    int co = co0 + ty * 4 + i;
    float bv = bias[co];
#pragma unroll
    for (int j = 0; j < 4; ++j) {
      int t = t0 + tx * 4 + j;
      if (t < kT) out[b * (kF * kT) + co * kT + t] = leaky_act(acc[i][j] + bv);
    }
  }
}

// ---------------------------------------------------------------------------
// conv k=3 pad=1 over length-3 samples. in/out layout [n][l][2048ch].
// Column index colg = n*3 + t.  64co x 64col tile.
// ---------------------------------------------------------------------------
__global__ __launch_bounds__(256) void post_conv_kernel(
    const float* __restrict__ in, const float* __restrict__ W,
    const float* __restrict__ bias, float* __restrict__ out, int ncols) {
  __shared__ float sW[16][3][64];
  __shared__ float sIn[16][3][64];
  const int co0 = blockIdx.y * 64;
  const int col0 = blockIdx.x * 64;
  const int tid = threadIdx.x;
  const int tx = tid & 15, ty = tid >> 4;
  float acc[4][4] = {};
  for (int ci0 = 0; ci0 < kF; ci0 += 16) {
#pragma unroll
    for (int l = 0; l < 12; ++l) {
      int i = tid + l * 256;
      int kk = i % 48;
      int col = i / 48;
      sW[kk / 3][kk % 3][col] =
          W[(co0 + col) * (kF * 3) + (ci0 + kk / 3) * 3 + (kk % 3)];
    }
#pragma unroll
    for (int l = 0; l < 12; ++l) {
      int i = tid + l * 256;
      int ci = i & 15;
      int k = (i >> 4) % 3;
      int col = i / 48;
      int colg = col0 + col;
      int n = colg / 3, t = colg % 3;
      int ll = t + k - 1;
      float v = 0.f;
      if (colg < ncols && ll >= 0 && ll < 3) v = in[(n * 3 + ll) * kF + ci0 + ci];
      sIn[ci][k][col] = v;
    }
    __syncthreads();
#pragma unroll
    for (int ci = 0; ci < 16; ++ci) {
#pragma unroll
      for (int k = 0; k < 3; ++k) {
        float a0 = sW[ci][k][ty * 4 + 0];
        float a1 = sW[ci][k][ty * 4 + 1];
        float a2 = sW[ci][k][ty * 4 + 2];
        float a3 = sW[ci][k][ty * 4 + 3];
        float x0 = sIn[ci][k][tx * 4 + 0];
        float x1 = sIn[ci][k][tx * 4 + 1];
        float x2 = sIn[ci][k][tx * 4 + 2];
        float x3 = sIn[ci][k][tx * 4 + 3];
        acc[0][0] += a0 * x0; acc[0][1] += a0 * x1; acc[0][2] += a0 * x2; acc[0][3] += a0 * x3;
        acc[1][0] += a1 * x0; acc[1][1] += a1 * x1; acc[1][2] += a1 * x2; acc[1][3] += a1 * x3;
        acc[2][0] += a2 * x0; acc[2][1] += a2 * x1; acc[2][2] += a2 * x2; acc[2][3] += a2 * x3;
        acc[3][0] += a3 * x0; acc[3][1] += a3 * x1; acc[3][2] += a3 * x2; acc[3][3] += a3 * x3;
      }
    }
    __syncthreads();
  }
#pragma unroll
  for (int i = 0; i < 4; ++i) {
    int co = co0 + ty * 4 + i;
    float bv = bias[co];
#pragma unroll
    for (int j = 0; j < 4; ++j) {
      int colg = col0 + tx * 4 + j;
      if (colg < ncols) out[colg * kF + co] = leaky_act(acc[i][j] + bv);
    }
  }
}

// ---------------------------------------------------------------------------
// xT[((b*3+g)*250 + j)*2048 + f] = x[b][f][j*3+g]   (tiled transpose)
// ---------------------------------------------------------------------------
__global__ __launch_bounds__(256) void transpose_kernel(
    const float* __restrict__ x, float* __restrict__ xT) {
  __shared__ float tile[64][65];
  const int b = blockIdx.z;
  const int t0 = blockIdx.x * 64, f0 = blockIdx.y * 64;
  const int tx = threadIdx.x & 63, ty4 = threadIdx.x >> 6;  // 0..3
#pragma unroll
  for (int i = 0; i < 16; ++i) {
    int lf = ty4 + i * 4;
    int t = t0 + tx;
    tile[lf][tx] = (t < kT) ? x[(b * kF + f0 + lf) * kT + t] : 0.f;
  }
  __syncthreads();
#pragma unroll
  for (int i = 0; i < 16; ++i) {
    int lt = ty4 + i * 4;
    int t = t0 + lt;
    if (t < kT) {
      int g = t % 3, j = t / 3;
      xT[((b * 3 + g) * kTg + j) * kF + f0 + tx] = tile[tx][lt];
    }
  }
}

// seq[b,c,t] = sum_ci wc[c,ci] * h2[b,ci,t]
__global__ __launch_bounds__(256) void seqcas_kernel(
    const float* __restrict__ h2, const float* __restrict__ wc,
    float* __restrict__ seq) {
  const int b = blockIdx.z, c = blockIdx.y;
  const int t = blockIdx.x * 256 + threadIdx.x;
  if (t >= kT) return;
  const float* hb = h2 + b * (kF * kT) + t;
  const float* w = wc + c * kF;
  float acc = 0.f;
#pragma unroll 8
  for (int ci = 0; ci < kF; ++ci) acc += w[ci] * hb[ci * kT];
  seq[(b * kC + c) * kT + t] = acc;
}

// wa[b,c,t] = sigmoid(batt[c] + sum_a watt[c,a]*seq[b,a,t])
__global__ __launch_bounds__(256) void wa_kernel(
    const float* __restrict__ seq, const float* __restrict__ watt,
    const float* __restrict__ batt, float* __restrict__ wa) {
  const int idx = blockIdx.x * 256 + threadIdx.x;
  if (idx >= 2 * kT) return;
  const int b = idx / kT, t = idx % kT;
  float s[kC];
#pragma unroll
  for (int a = 0; a < kC; ++a) s[a] = seq[(b * kC + a) * kT + t];
#pragma unroll
  for (int c = 0; c < kC; ++c) {
    float acc = batt[c];
#pragma unroll
    for (int a = 0; a < kC; ++a) acc += watt[c * kC + a] * s[a];
    wa[(b * kC + c) * kT + t] = 1.f / (1.f + expf(-acc));
  }
}

// top-93 mean over T per (b,c) row. One block per row, iterative argmax.
__global__ __launch_bounds__(256) void score_pre_kernel(
    const float* __restrict__ seq, float* __restrict__ out) {
  __shared__ float vals[768];
  __shared__ float rv[256];
  __shared__ int ri[256];
  const int n = blockIdx.x;
  const int tid = threadIdx.x;
  for (int i = tid; i < 768; i += 256) vals[i] = (i < kT) ? seq[n * kT + i] : -1e30f;
  __syncthreads();
  float sum = 0.f;
  for (int it = 0; it < kTop; ++it) {
    float mv = -1e30f;
    int mi = 0;
    for (int i = tid; i < 768; i += 256) {
      float v = vals[i];
      if (v > mv) { mv = v; mi = i; }
    }
    rv[tid] = mv; ri[tid] = mi;
    __syncthreads();
    for (int s = 128; s > 0; s >>= 1) {
      if (tid < s && rv[tid + s] > rv[tid]) { rv[tid] = rv[tid + s]; ri[tid] = ri[tid + s]; }
      __syncthreads();
    }
    if (tid == 0) { sum += rv[0]; vals[ri[0]] = -1e30f; }
    __syncthreads();
  }
  if (tid == 0) out[n] = sum / (float)kTop;
}

// featL[((b*20+c)*3+g)*2048 + ci] = sum_j wa[b,c,j*3+g] * xT[(b,g,j),ci]
__global__ __launch_bounds__(256) void feat_kernel(
    const float* __restrict__ xT, const float* __restrict__ wa,
    float* __restrict__ featL) {
  __shared__ float was[kC][kTg];
  const int b = blockIdx.z, g = blockIdx.y;
  const int ci = blockIdx.x * 256 + threadIdx.x;
  for (int i = threadIdx.x; i < kC * kTg; i += 256) {
    int c = i / kTg, j = i % kTg;
    was[c][j] = wa[(b * kC + c) * kT + j * 3 + g];
  }
  __syncthreads();
  float acc[kC] = {};
  const float* xp = xT + ((b * 3 + g) * kTg) * kF + ci;
  for (int j = 0; j < kTg; ++j) {
    float xv = xp[j * kF];
#pragma unroll
    for (int c = 0; c < kC; ++c) acc[c] += was[c][j] * xv;
  }
#pragma unroll
  for (int c = 0; c < kC; ++c) featL[((b * kC + c) * 3 + g) * kF + ci] = acc[c];
}

// aggL[((b*400 + c*20 + a)*3+g)*2048 + ci] = sum_j wa[b,a]* (1-wa[b,c]) * xT
// block: (ci tile, c=chunk, b*3+g)
__global__ __launch_bounds__(256) void agg_kernel(
    const float* __restrict__ xT, const float* __restrict__ wa,
    float* __restrict__ aggL) {
  __shared__ float ws[kC][kTg];
  const int bg = blockIdx.z;
  const int b = bg / 3, g = bg % 3;
  const int c = blockIdx.y;  // suppressed class chunk
  const int ci = blockIdx.x * 256 + threadIdx.x;
  for (int i = threadIdx.x; i < kC * kTg; i += 256) {
    int a = i / kTg, j = i % kTg;
    float waj = wa[(b * kC + a) * kT + j * 3 + g];
    float wbj = 1.f - wa[(b * kC + c) * kT + j * 3 + g];
    ws[a][j] = waj * wbj;
  }
  __syncthreads();
  float acc[kC] = {};
  const float* xp = xT + ((b * 3 + g) * kTg) * kF + ci;
  for (int j = 0; j < kTg; ++j) {
    float xv = xp[j * kF];
#pragma unroll
    for (int a = 0; a < kC; ++a) acc[a] += ws[a][j] * xv;
  }
#pragma unroll
  for (int a = 0; a < kC; ++a)
    aggL[((b * 400 + c * kC + a) * 3 + g) * kF + ci] = acc[a];
}

// score[n] = (1/3) sum_g sum_co h[(n*3+g)*2048+co] * wc[(n%20)*2048+co]
__global__ __launch_bounds__(256) void cls_kernel(
    const float* __restrict__ h, const float* __restrict__ wc,
    float* __restrict__ out) {
  __shared__ float red[256];
  const int n = blockIdx.x;
  const int tid = threadIdx.x;
  const float* w = wc + (n % kC) * kF;
  const float* h0 = h + (size_t)n * 3 * kF;
  float acc = 0.f;
  for (int co = tid; co < kF; co += 256)
    acc += w[co] * (h0[co] + h0[kF + co] + h0[2 * kF + co]);
  red[tid] = acc;
  __syncthreads();
  for (int s = 128; s > 0; s >>= 1) {
    if (tid < s) red[tid] += red[tid + s];
    __syncthreads();
  }
  if (tid == 0) out[n] = red[0] * (1.f / 3.f);
}

// collect + concat + softmax -> out[80 + b*40 + i]
__global__ void final_kernel(const float* __restrict__ score_post,
                             const float* __restrict__ sc_buf,
                             const int* __restrict__ label,
                             float* __restrict__ out) {
  __shared__ float z[2 * kC];
  __shared__ float collect[kC];
  const int b = blockIdx.x;
  const int tid = threadIdx.x;
  if (tid < kC) {
    int a = tid;
    float s = 0.f, ngt = 0.f;
    for (int c = 0; c < kC; ++c) {
      float m = label[b * kC + c] > 0 ? 1.f : 0.f;
      ngt += m;
      s += m * sc_buf[b * 400 + c * kC + a];
    }
    if (ngt < 1.f) ngt = 1.f;
    float col = s / ngt;
    if (label[b * kC + a] > 0) col = sc_buf[b * 400 + a * kC + a];
    collect[a] = col;
  }
  __syncthreads();
  if (tid < 2 * kC) z[tid] = (tid < kC) ? score_post[b * kC + tid] : collect[tid - kC];
  __syncthreads();
  if (tid == 0) {
    float mx = z[0];
    for (int i = 1; i < 2 * kC; ++i) mx = fmaxf(mx, z[i]);
    float s = 0.f;
    for (int i = 0; i < 2 * kC; ++i) { z[i] = expf(z[i] - mx); s += z[i]; }
    for (int i = 0; i < 2 * kC; ++i) out[80 + b * 2 * kC + i] = z[i] / s;
  }
}

extern "C" void kernel_launch(void* const* d_in, const int* in_sizes, int n_in,
                              void* d_out, int out_size, void* d_ws, size_t ws_size,
                              hipStream_t stream) {
  (void)in_sizes; (void)n_in; (void)out_size; (void)ws_size;
  const float* x    = (const float*)d_in[0];
  const float* w1   = (const float*)d_in[1];
  const float* b1   = (const float*)d_in[2];
  const float* w2   = (const float*)d_in[3];
  const float* b2   = (const float*)d_in[4];
  const float* wc   = (const float*)d_in[5];
  const float* watt = (const float*)d_in[6];
  const float* batt = (const float*)d_in[7];
  const int*   lbl  = (const int*)d_in[8];
  float* out = (float*)d_out;
  float* ws  = (float*)d_ws;

  // workspace layout (floats); aggL aliases h1/h2 (dead by then); pb2 aliases aggL
  float* xT    = ws;                 // 3,072,000
  float* h1    = ws + 3072000;       // 3,072,000
  float* h2    = ws + 6144000;       // 3,072,000
  float* aggL  = ws + 3072000;       // 4,915,200 (reuses h1 + h2 head)
  float* pb1   = ws + 7987200;       // 4,915,200
  float* pb2   = aggL;               // alias (aggL dead after bg conv1)
  float* seq   = ws + 12902400;      // 30,000
  float* wab   = ws + 12932400;      // 30,000
  float* featL = ws + 12962400;      // 245,760
  float* pf1   = ws + 13208160;      // 245,760
  float* pf2   = ws + 13453920;      // 245,760
  float* scb   = ws + 13699680;      // 800   (total ~54.8 MB)

  dim3 blk(256);
  // main path
  transpose_kernel<<<dim3(12, 32, 2), blk, 0, stream>>>(x, xT);
  conv_main_kernel<<<dim3(12, 32, 2), blk, 0, stream>>>(x, w1, b1, h1);
  conv_main_kernel<<<dim3(12, 32, 2), blk, 0, stream>>>(h1, w2, b2, h2);
  seqcas_kernel<<<dim3(3, kC, 2), blk, 0, stream>>>(h2, wc, seq);
  wa_kernel<<<dim3(6), blk, 0, stream>>>(seq, watt, batt, wab);
  score_pre_kernel<<<dim3(40), blk, 0, stream>>>(seq, out);  // out[0..39]
  // foreground post path
  feat_kernel<<<dim3(8, 3, 2), blk, 0, stream>>>(xT, wab, featL);
  post_conv_kernel<<<dim3(2, 32, 1), blk, 0, stream>>>(featL, w1, b1, pf1, 120);
  post_conv_kernel<<<dim3(2, 32, 1), blk, 0, stream>>>(pf1, w2, b2, pf2, 120);
  cls_kernel<<<dim3(40), blk, 0, stream>>>(pf2, wc, out + 40);  // out[40..79]
  // background stream
  agg_kernel<<<dim3(8, kC, 6), blk, 0, stream>>>(xT, wab, aggL);
  post_conv_kernel<<<dim3(38, 32, 1), blk, 0, stream>>>(aggL, w1, b1, pb1, 2400);
  post_conv_kernel<<<dim3(38, 32, 1), blk, 0, stream>>>(pb1, w2, b2, pb2, 2400);
  cls_kernel<<<dim3(800), blk, 0, stream>>>(pb2, wc, scb);
  // final collect + softmax
  final_kernel<<<dim3(2), dim3(64), 0, stream>>>(out + 40, scb, lbl, out);
}

// Round 2
// 893.788 us; speedup vs baseline: 9.4628x; 9.4628x over previous
//
#include <hip/hip_runtime.h>
#include <math.h>

// ECMNet on gfx950 — bf16 MFMA GEMM pipeline.
// B=2, F=2048, T=750, C=20, G=3, Tg=250, topK=93, K(gemm)=6144
namespace {
constexpr int kF = 2048;
constexpr int kT = 750;
constexpr int kC = 20;
constexpr int kTop = 93;
constexpr int kK = 6144;          // 2048 ci * 3 taps
constexpr int N_MAIN = 1500;      // 2 batches * 750
constexpr int NP_MAIN = 1536;     // padded to 128
constexpr int N_POST = 2520;      // 840 samples * 3
constexpr int NP_POST = 2560;
}

typedef __bf16 bf16x8 __attribute__((ext_vector_type(8)));
typedef float f32x4 __attribute__((ext_vector_type(4)));

__device__ __forceinline__ ushort f2bf(float f) {
  uint u = __builtin_bit_cast(uint, f);
  uint r = u + 0x7FFFu + ((u >> 16) & 1u);
  return (ushort)(r >> 16);
}
__device__ __forceinline__ float bf2f(ushort u) {
  return __builtin_bit_cast(float, ((uint)u) << 16);
}
__device__ __forceinline__ float leaky(float v) { return v > 0.f ? v : 0.01f * v; }

__device__ __forceinline__ void gload_lds16(const ushort* g, ushort* l) {
  __builtin_amdgcn_global_load_lds(
      (const __attribute__((address_space(1))) void*)g,
      (__attribute__((address_space(3))) void*)l, 16, 0, 0);
}

// ---------------------------------------------------------------------------
// fp32 -> bf16 conversion
// ---------------------------------------------------------------------------
__global__ __launch_bounds__(256) void convert_kernel(
    const float* __restrict__ src, ushort* __restrict__ dst, int n) {
  int i = (blockIdx.x * 256 + threadIdx.x) * 4;
  if (i + 3 < n) {
    float4 f = *(const float4*)(src + i);
    ushort4 o;
    o.x = f2bf(f.x); o.y = f2bf(f.y); o.z = f2bf(f.z); o.w = f2bf(f.w);
    *(ushort4*)(dst + i) = o;
  } else {
    for (; i < n; ++i) dst[i] = f2bf(src[i]);
  }
}

// ---------------------------------------------------------------------------
// x [2][2048][750] fp32 -> xTt [(b*750+t)][2048] bf16 (plain transpose)
//                      -> xTb [((b*3+g)*250+j)][2048] bf16 (strided for feat/agg)
// ---------------------------------------------------------------------------
__global__ __launch_bounds__(256) void transpose_kernel(
    const float* __restrict__ x, ushort* __restrict__ xTt,
    ushort* __restrict__ xTb) {
  __shared__ float tile[64][65];
  const int b = blockIdx.z;
  const int t0 = blockIdx.x * 64, f0 = blockIdx.y * 64;
  const int tx = threadIdx.x & 63, ty4 = threadIdx.x >> 6;  // 0..3
#pragma unroll
  for (int i = 0; i < 16; ++i) {
    int lf = ty4 + i * 4;
    int t = t0 + tx;
    tile[lf][tx] = (t < kT) ? x[((size_t)b * kF + f0 + lf) * kT + t] : 0.f;
  }
  __syncthreads();
#pragma unroll
  for (int i = 0; i < 16; ++i) {
    int lt = ty4 + i * 4;
    int t = t0 + lt;
    if (t < kT) {
      ushort hv = f2bf(tile[tx][lt]);
      xTt[(size_t)(b * kT + t) * kF + f0 + tx] = hv;
      int g = t % 3, j = t / 3;
      xTb[(size_t)((b * 3 + g) * 250 + j) * kF + f0 + tx] = hv;
    }
  }
}

// ---------------------------------------------------------------------------
// im2col: src [ns*L][2048] bf16 -> dst [ns*L][6144] bf16
// dst[(s*L+t)][ci*3+kk] = (0 <= t+kk-1 < L) ? src[(s*L+t+kk-1)][ci] : 0
// one block per column; thread handles 8 ci.
// ---------------------------------------------------------------------------
__global__ __launch_bounds__(256) void im2col_kernel(
    const ushort* __restrict__ src, ushort* __restrict__ dst, int L) {
  const int col = blockIdx.x;  // s*L + t
  const int t = col % L;
  const int ci0 = threadIdx.x * 8;
  ushort v[3][8];
#pragma unroll
  for (int kk = 0; kk < 3; ++kk) {
    int tt = t + kk - 1;
    if (tt >= 0 && tt < L) {
      const ushort4* p = (const ushort4*)(src + (size_t)(col + kk - 1) * kF + ci0);
      ushort4 a = p[0], b = p[1];
      v[kk][0] = a.x; v[kk][1] = a.y; v[kk][2] = a.z; v[kk][3] = a.w;
      v[kk][4] = b.x; v[kk][5] = b.y; v[kk][6] = b.z; v[kk][7] = b.w;
    } else {
#pragma unroll
      for (int j = 0; j < 8; ++j) v[kk][j] = 0;
    }
  }
  ushort o[24];
#pragma unroll
  for (int j = 0; j < 8; ++j)
#pragma unroll
    for (int kk = 0; kk < 3; ++kk) o[j * 3 + kk] = v[kk][j];
  ushort4* q = (ushort4*)(dst + (size_t)col * kK + ci0 * 3);
#pragma unroll
  for (int s = 0; s < 6; ++s) {
    ushort4 w;
    w.x = o[s * 4 + 0]; w.y = o[s * 4 + 1]; w.z = o[s * 4 + 2]; w.w = o[s * 4 + 3];
    q[s] = w;
  }
}

// ---------------------------------------------------------------------------
// GEMM: Y[col][co] = leaky(bias[co] + sum_K A[co][K] * B[col][K])
// A = Wb [2048][6144] bf16, B = Xcol [Npad][6144] bf16.
// 128x128 tile, BK=64, 4 waves (2x2), each wave 64x64 via 4x4 frags 16x16x32.
// global_load_lds (16B) staging, linear LDS, 2-barrier K-loop (m97 structure).
// ---------------------------------------------------------------------------
__global__ __launch_bounds__(256) void gemm_kernel(
    const ushort* __restrict__ A, const ushort* __restrict__ B,
    const float* __restrict__ bias, ushort* __restrict__ Y, int ncols) {
  __shared__ ushort sA[128 * 64];
  __shared__ ushort sB[128 * 64];
  const int tid = threadIdx.x;
  const int w = tid >> 6, lane = tid & 63;
  const int wm = w >> 1, wn = w & 1;
  const int co0 = blockIdx.y * 128;
  const int col0 = blockIdx.x * 128;
  const int srow = lane >> 3;        // 0..7
  const int selem = (lane & 7) * 8;  // k element offset within 64
  const ushort* Abase = A + (size_t)co0 * kK;
  const ushort* Bbase = B + (size_t)col0 * kK;
  f32x4 acc[4][4];
#pragma unroll
  for (int i = 0; i < 4; ++i)
#pragma unroll
    for (int j = 0; j < 4; ++j) acc[i][j] = (f32x4){0.f, 0.f, 0.f, 0.f};

  for (int kt = 0; kt < kK / 64; ++kt) {
    const int k0 = kt * 64;
#pragma unroll
    for (int i = 0; i < 4; ++i) {
      int r = (w * 4 + i) * 8 + srow;
      gload_lds16(Abase + (size_t)r * kK + k0 + selem, &sA[(w * 4 + i) * 512]);
    }
#pragma unroll
    for (int i = 0; i < 4; ++i) {
      int r = (w * 4 + i) * 8 + srow;
      gload_lds16(Bbase + (size_t)r * kK + k0 + selem, &sB[(w * 4 + i) * 512]);
    }
    __syncthreads();  // drains vmcnt (compiler-inserted) before use
#pragma unroll
    for (int ksub = 0; ksub < 2; ++ksub) {
      bf16x8 af[4], bfv[4];
#pragma unroll
      for (int fm = 0; fm < 4; ++fm) {
        int row = wm * 64 + fm * 16 + (lane & 15);
        af[fm] = *(const bf16x8*)&sA[row * 64 + ksub * 32 + (lane >> 4) * 8];
      }
#pragma unroll
      for (int fn = 0; fn < 4; ++fn) {
        int row = wn * 64 + fn * 16 + (lane & 15);
        bfv[fn] = *(const bf16x8*)&sB[row * 64 + ksub * 32 + (lane >> 4) * 8];
      }
#pragma unroll
      for (int fm = 0; fm < 4; ++fm)
#pragma unroll
        for (int fn = 0; fn < 4; ++fn)
          acc[fm][fn] = __builtin_amdgcn_mfma_f32_16x16x32_bf16(
              af[fm], bfv[fn], acc[fm][fn], 0, 0, 0);
    }
    __syncthreads();
  }
  // epilogue: bias + leaky, write [col][co] bf16
#pragma unroll
  for (int fm = 0; fm < 4; ++fm) {
#pragma unroll
    for (int fn = 0; fn < 4; ++fn) {
      int col = col0 + wn * 64 + fn * 16 + (lane & 15);
      if (col >= ncols) continue;
#pragma unroll
      for (int r = 0; r < 4; ++r) {
        int row = co0 + wm * 64 + fm * 16 + (lane >> 4) * 4 + r;
        float v = acc[fm][fn][r] + bias[row];
        Y[(size_t)col * kF + row] = f2bf(leaky(v));
      }
    }
  }
}

// ---------------------------------------------------------------------------
// seq[b][c][t] = sum_ci wcb[c][ci] * h2[(b*750+t)][ci]   (wave per t)
// ---------------------------------------------------------------------------
__global__ __launch_bounds__(256) void seqcas_kernel(
    const ushort* __restrict__ h2, const ushort* __restrict__ wcb,
    float* __restrict__ seq) {
  const int w = threadIdx.x >> 6, lane = threadIdx.x & 63;
  const int idx = blockIdx.x * 4 + w;  // b*750 + t
  if (idx >= N_MAIN) return;
  const ushort* hr = h2 + (size_t)idx * kF;
  float acc[kC];
#pragma unroll
  for (int c = 0; c < kC; ++c) acc[c] = 0.f;
#pragma unroll
  for (int ch = 0; ch < 4; ++ch) {
    const int ci0 = ch * 512 + lane * 8;
    ushort4 ha = *(const ushort4*)(hr + ci0);
    ushort4 hb = *(const ushort4*)(hr + ci0 + 4);
    float hx[8] = {bf2f(ha.x), bf2f(ha.y), bf2f(ha.z), bf2f(ha.w),
                   bf2f(hb.x), bf2f(hb.y), bf2f(hb.z), bf2f(hb.w)};
#pragma unroll
    for (int c = 0; c < kC; ++c) {
      const ushort* wr = wcb + c * kF + ci0;
      ushort4 wa4 = *(const ushort4*)wr;
      ushort4 wb4 = *(const ushort4*)(wr + 4);
      acc[c] += bf2f(wa4.x) * hx[0] + bf2f(wa4.y) * hx[1] +
                bf2f(wa4.z) * hx[2] + bf2f(wa4.w) * hx[3] +
                bf2f(wb4.x) * hx[4] + bf2f(wb4.y) * hx[5] +
                bf2f(wb4.z) * hx[6] + bf2f(wb4.w) * hx[7];
    }
  }
#pragma unroll
  for (int off = 32; off; off >>= 1)
#pragma unroll
    for (int c = 0; c < kC; ++c) acc[c] += __shfl_xor(acc[c], off);
  if (lane == 0) {
    int b = idx / kT, t = idx % kT;
#pragma unroll
    for (int c = 0; c < kC; ++c) seq[(size_t)(b * kC + c) * kT + t] = acc[c];
  }
}

// wa[b,c,t] = sigmoid(batt[c] + sum_a watt[c,a]*seq[b,a,t])
__global__ __launch_bounds__(256) void wa_kernel(
    const float* __restrict__ seq, const float* __restrict__ watt,
    const float* __restrict__ batt, float* __restrict__ wa) {
  const int idx = blockIdx.x * 256 + threadIdx.x;
  if (idx >= 2 * kT) return;
  const int b = idx / kT, t = idx % kT;
  float s[kC];
#pragma unroll
  for (int a = 0; a < kC; ++a) s[a] = seq[(size_t)(b * kC + a) * kT + t];
#pragma unroll
  for (int c = 0; c < kC; ++c) {
    float acc = batt[c];
#pragma unroll
    for (int a = 0; a < kC; ++a) acc += watt[c * kC + a] * s[a];
    wa[(size_t)(b * kC + c) * kT + t] = 1.f / (1.f + expf(-acc));
  }
}

// top-93 mean over T per (b,c) row
__global__ __launch_bounds__(256) void score_pre_kernel(
    const float* __restrict__ seq, float* __restrict__ out) {
  __shared__ float vals[768];
  __shared__ float rv[256];
  __shared__ int ri[256];
  const int n = blockIdx.x;
  const int tid = threadIdx.x;
  for (int i = tid; i < 768; i += 256) vals[i] = (i < kT) ? seq[(size_t)n * kT + i] : -1e30f;
  __syncthreads();
  float sum = 0.f;
  for (int it = 0; it < kTop; ++it) {
    float mv = -1e30f;
    int mi = 0;
    for (int i = tid; i < 768; i += 256) {
      float v = vals[i];
      if (v > mv) { mv = v; mi = i; }
    }
    rv[tid] = mv; ri[tid] = mi;
    __syncthreads();
    for (int s = 128; s > 0; s >>= 1) {
      if (tid < s && rv[tid + s] > rv[tid]) { rv[tid] = rv[tid + s]; ri[tid] = ri[tid + s]; }
      __syncthreads();
    }
    if (tid == 0) { sum += rv[0]; vals[ri[0]] = -1e30f; }
    __syncthreads();
  }
  if (tid == 0) out[n] = sum / (float)kTop;
}

// fg: FeatY[((b*20+c)*3+g)][ci] = sum_j wa[b,c,j*3+g] * xTb[(b,g,j)][ci]
__global__ __launch_bounds__(256) void feat_kernel(
    const ushort* __restrict__ xTb, const float* __restrict__ wa,
    ushort* __restrict__ FeatY) {
  __shared__ float was[kC][250];
  const int b = blockIdx.z, g = blockIdx.y;
  const int ci = blockIdx.x * 256 + threadIdx.x;
  for (int i = threadIdx.x; i < kC * 250; i += 256) {
    int c = i / 250, j = i % 250;
    was[c][j] = wa[(size_t)(b * kC + c) * kT + j * 3 + g];
  }
  __syncthreads();
  float acc[kC] = {};
  const ushort* xp = xTb + (size_t)((b * 3 + g) * 250) * kF + ci;
  for (int j = 0; j < 250; ++j) {
    float xv = bf2f(xp[(size_t)j * kF]);
#pragma unroll
    for (int c = 0; c < kC; ++c) acc[c] += was[c][j] * xv;
  }
#pragma unroll
  for (int c = 0; c < kC; ++c)
    FeatY[(size_t)((b * kC + c) * 3 + g) * kF + ci] = f2bf(acc[c]);
}

// bg: FeatY[((40+b*400+c*20+a)*3+g)][ci] = sum_j wa[b,a]*(1-wa[b,c]) * xTb
__global__ __launch_bounds__(256) void agg_kernel(
    const ushort* __restrict__ xTb, const float* __restrict__ wa,
    ushort* __restrict__ FeatY) {
  __shared__ float ws2[kC][250];
  const int bg = blockIdx.z;
  const int b = bg / 3, g = bg % 3;
  const int c = blockIdx.y;
  const int ci = blockIdx.x * 256 + threadIdx.x;
  for (int i = threadIdx.x; i < kC * 250; i += 256) {
    int a = i / 250, j = i % 250;
    float waj = wa[(size_t)(b * kC + a) * kT + j * 3 + g];
    float wbj = 1.f - wa[(size_t)(b * kC + c) * kT + j * 3 + g];
    ws2[a][j] = waj * wbj;
  }
  __syncthreads();
  float acc[kC] = {};
  const ushort* xp = xTb + (size_t)((b * 3 + g) * 250) * kF + ci;
  for (int j = 0; j < 250; ++j) {
    float xv = bf2f(xp[(size_t)j * kF]);
#pragma unroll
    for (int a = 0; a < kC; ++a) acc[a] += ws2[a][j] * xv;
  }
#pragma unroll
  for (int a = 0; a < kC; ++a)
    FeatY[(size_t)((40 + b * 400 + c * kC + a) * 3 + g) * kF + ci] = f2bf(acc[a]);
}

// score[n] = (1/3) sum_g sum_co h[(n*3+g)][co] * wc[class(n)][co]
__global__ __launch_bounds__(256) void cls_kernel(
    const ushort* __restrict__ h, const float* __restrict__ wc,
    float* __restrict__ out40, float* __restrict__ scb) {
  __shared__ float red[256];
  const int n = blockIdx.x;
  const int tid = threadIdx.x;
  const int cls = (n < 40) ? (n % kC) : ((n - 40) % kC);
  const int co0 = tid * 8;
  const float4 w0 = *(const float4*)(wc + (size_t)cls * kF + co0);
  const float4 w1 = *(const float4*)(wc + (size_t)cls * kF + co0 + 4);
  float acc = 0.f;
#pragma unroll
  for (int g = 0; g < 3; ++g) {
    const ushort* hr = h + (size_t)(n * 3 + g) * kF + co0;
    ushort4 a = *(const ushort4*)hr;
    ushort4 b4 = *(const ushort4*)(hr + 4);
    acc += bf2f(a.x) * w0.x + bf2f(a.y) * w0.y + bf2f(a.z) * w0.z + bf2f(a.w) * w0.w +
           bf2f(b4.x) * w1.x + bf2f(b4.y) * w1.y + bf2f(b4.z) * w1.z + bf2f(b4.w) * w1.w;
  }
  red[tid] = acc;
  __syncthreads();
  for (int s = 128; s > 0; s >>= 1) {
    if (tid < s) red[tid] += red[tid + s];
    __syncthreads();
  }
  if (tid == 0) {
    float v = red[0] * (1.f / 3.f);
    if (n < 40) out40[n] = v; else scb[n - 40] = v;
  }
}

// collect + concat + softmax -> out[80 + b*40 + i]
__global__ void final_kernel(const float* __restrict__ score_post,
                             const float* __restrict__ sc_buf,
                             const int* __restrict__ label,
                             float* __restrict__ out) {
  __shared__ float z[2 * kC];
  __shared__ float collect[kC];
  const int b = blockIdx.x;
  const int tid = threadIdx.x;
  if (tid < kC) {
    int a = tid;
    float s = 0.f, ngt = 0.f;
    for (int c = 0; c < kC; ++c) {
      float m = label[b * kC + c] > 0 ? 1.f : 0.f;
      ngt += m;
      s += m * sc_buf[b * 400 + c * kC + a];
    }
    if (ngt < 1.f) ngt = 1.f;
    float col = s / ngt;
    if (label[b * kC + a] > 0) col = sc_buf[b * 400 + a * kC + a];
    collect[a] = col;
  }
  __syncthreads();
  if (tid < 2 * kC) z[tid] = (tid < kC) ? score_post[b * kC + tid] : collect[tid - kC];
  __syncthreads();
  if (tid == 0) {
    float mx = z[0];
    for (int i = 1; i < 2 * kC; ++i) mx = fmaxf(mx, z[i]);
    float s = 0.f;
    for (int i = 0; i < 2 * kC; ++i) { z[i] = expf(z[i] - mx); s += z[i]; }
    for (int i = 0; i < 2 * kC; ++i) out[80 + b * 2 * kC + i] = z[i] / s;
  }
}

extern "C" void kernel_launch(void* const* d_in, const int* in_sizes, int n_in,
                              void* d_out, int out_size, void* d_ws, size_t ws_size,
                              hipStream_t stream) {
  (void)in_sizes; (void)n_in; (void)out_size; (void)ws_size;
  const float* x    = (const float*)d_in[0];
  const float* w1   = (const float*)d_in[1];
  const float* b1   = (const float*)d_in[2];
  const float* w2   = (const float*)d_in[3];
  const float* b2   = (const float*)d_in[4];
  const float* wc   = (const float*)d_in[5];
  const float* watt = (const float*)d_in[6];
  const float* batt = (const float*)d_in[7];
  const int*   lbl  = (const int*)d_in[8];
  float* out = (float*)d_out;
  char*  wsb = (char*)d_ws;

  // workspace layout (bytes); requires ~142 MiB. aliases noted.
  ushort* Wb1   = (ushort*)(wsb + 0);            // 25,165,824
  ushort* Wb2   = (ushort*)(wsb + 25165824);     // 25,165,824
  ushort* wcb   = (ushort*)(wsb + 50331648);     // 81,920
  ushort* xTb   = (ushort*)(wsb + 50413568);     // 6,144,000
  ushort* xTt   = (ushort*)(wsb + 56557568);     // 6,144,000
  ushort* Xc1   = (ushort*)(wsb + 62701568);     // 18,874,368 (1536x6144)
  ushort* Xc2   = (ushort*)(wsb + 81575936);     // 18,874,368 -> ends 100,450,304
  ushort* Pcol1 = (ushort*)(wsb + 62701568);     // 31,457,280 overlay (Xc1+Xc2 dead)
  ushort* hP2   = (ushort*)(wsb + 62701568);     // 10,485,760 overlay (Pcol1 dead)
  ushort* h2    = (ushort*)(wsb + 100450304);    // 6,291,456
  ushort* Pcol2 = (ushort*)(wsb + 106741760);    // 31,457,280 -> ends 138,199,040
  ushort* Ybuf  = (ushort*)(wsb + 138199040);    // 10,485,760 (Y1 / FeatY / Yp)
  float*  seq   = (float*)(wsb + 148684800);     // 120,000
  float*  wab   = (float*)(wsb + 148804800);     // 120,000
  float*  scb   = (float*)(wsb + 148924800);     // 3,200   total ~148.93 MB

  dim3 blk(256);
  // weight conversions
  convert_kernel<<<dim3(12288), blk, 0, stream>>>(w1, Wb1, 2048 * kK);
  convert_kernel<<<dim3(12288), blk, 0, stream>>>(w2, Wb2, 2048 * kK);
  convert_kernel<<<dim3(40), blk, 0, stream>>>(wc, wcb, kC * kF);
  // main path
  transpose_kernel<<<dim3(12, 32, 2), blk, 0, stream>>>(x, xTt, xTb);
  im2col_kernel<<<dim3(N_MAIN), blk, 0, stream>>>(xTt, Xc1, kT);
  gemm_kernel<<<dim3(NP_MAIN / 128, 16), blk, 0, stream>>>(Wb1, Xc1, b1, Ybuf, N_MAIN);
  im2col_kernel<<<dim3(N_MAIN), blk, 0, stream>>>(Ybuf, Xc2, kT);
  gemm_kernel<<<dim3(NP_MAIN / 128, 16), blk, 0, stream>>>(Wb2, Xc2, b2, h2, N_MAIN);
  seqcas_kernel<<<dim3(375), blk, 0, stream>>>(h2, wcb, seq);
  wa_kernel<<<dim3(6), blk, 0, stream>>>(seq, watt, batt, wab);
  score_pre_kernel<<<dim3(40), blk, 0, stream>>>(seq, out);  // out[0..39]
  // fg + bg aggregated features -> FeatY (840 samples x 3 positions)
  feat_kernel<<<dim3(8, 3, 2), blk, 0, stream>>>(xTb, wab, Ybuf);
  agg_kernel<<<dim3(8, kC, 6), blk, 0, stream>>>(xTb, wab, Ybuf);
  im2col_kernel<<<dim3(N_POST), blk, 0, stream>>>(Ybuf, Pcol1, 3);
  gemm_kernel<<<dim3(NP_POST / 128, 16), blk, 0, stream>>>(Wb1, Pcol1, b1, Ybuf, N_POST);
  im2col_kernel<<<dim3(N_POST), blk, 0, stream>>>(Ybuf, Pcol2, 3);
  gemm_kernel<<<dim3(NP_POST / 128, 16), blk, 0, stream>>>(Wb2, Pcol2, b2, hP2, N_POST);
  cls_kernel<<<dim3(840), blk, 0, stream>>>(hP2, wc, out + 40, scb);
  final_kernel<<<dim3(2), dim3(64), 0, stream>>>(out + 40, scb, lbl, out);
}

// Round 3
// 718.144 us; speedup vs baseline: 11.7773x; 1.2446x over previous
//
#include <hip/hip_runtime.h>
#include <math.h>

// ECMNet on gfx950 — bf16 MFMA direct-conv GEMM pipeline with split-K.
// B=2, F=2048, T=750, C=20, G=3, Tg=250, topK=93
namespace {
constexpr int kF = 2048;
constexpr int kT = 750;
constexpr int kC = 20;
constexpr int kTop = 93;
}

typedef __bf16 bf16x8 __attribute__((ext_vector_type(8)));
typedef float f32x4 __attribute__((ext_vector_type(4)));

__device__ __forceinline__ ushort f2bf(float f) {
  uint u = __builtin_bit_cast(uint, f);
  uint r = u + 0x7FFFu + ((u >> 16) & 1u);
  return (ushort)(r >> 16);
}
__device__ __forceinline__ float bf2f(ushort u) {
  return __builtin_bit_cast(float, ((uint)u) << 16);
}
__device__ __forceinline__ float leaky(float v) { return v > 0.f ? v : 0.01f * v; }

__device__ __forceinline__ void gload_lds16(const ushort* g, ushort* l) {
  __builtin_amdgcn_global_load_lds(
      (const __attribute__((address_space(1))) void*)g,
      (__attribute__((address_space(3))) void*)l, 16, 0, 0);
}

// ---------------------------------------------------------------------------
// weights [co][ci][3] fp32 -> Wt [tap][co][ci] bf16 (both w1,w2); zero page
// ---------------------------------------------------------------------------
__global__ __launch_bounds__(256) void convert_w_kernel(
    const float* __restrict__ w1, const float* __restrict__ w2,
    ushort* __restrict__ Wt1, ushort* __restrict__ Wt2,
    ushort* __restrict__ zpage) {
  const int co = blockIdx.x;
  const float* w = (blockIdx.y == 0) ? w1 : w2;
  ushort* Wt = (blockIdx.y == 0) ? Wt1 : Wt2;
  const int ci0 = threadIdx.x * 8;
  float v[24];
  const float4* p = (const float4*)(w + (size_t)co * 6144 + ci0 * 3);
#pragma unroll
  for (int s = 0; s < 6; ++s) {
    float4 f = p[s];
    v[s * 4 + 0] = f.x; v[s * 4 + 1] = f.y; v[s * 4 + 2] = f.z; v[s * 4 + 3] = f.w;
  }
#pragma unroll
  for (int tap = 0; tap < 3; ++tap) {
    ushort o[8];
#pragma unroll
    for (int j = 0; j < 8; ++j) o[j] = f2bf(v[j * 3 + tap]);
    ushort4 a = {o[0], o[1], o[2], o[3]}, b = {o[4], o[5], o[6], o[7]};
    ushort4* q = (ushort4*)(Wt + (size_t)tap * kF * kF + (size_t)co * kF + ci0);
    q[0] = a; q[1] = b;
  }
  if (blockIdx.x == 0 && blockIdx.y == 0) {
    ((float4*)zpage)[threadIdx.x] = (float4){0.f, 0.f, 0.f, 0.f};  // 4 KB zeros
  }
}

// fp32 -> bf16 plain (for wc)
__global__ __launch_bounds__(256) void convert_kernel(
    const float* __restrict__ src, ushort* __restrict__ dst, int n) {
  int i = (blockIdx.x * 256 + threadIdx.x) * 4;
  if (i + 3 < n) {
    float4 f = *(const float4*)(src + i);
    ushort4 o;
    o.x = f2bf(f.x); o.y = f2bf(f.y); o.z = f2bf(f.z); o.w = f2bf(f.w);
    *(ushort4*)(dst + i) = o;
  } else {
    for (; i < n; ++i) dst[i] = f2bf(src[i]);
  }
}

// ---------------------------------------------------------------------------
// x [2][2048][750] fp32 -> xTt [(b*750+t)][2048] bf16
//                       -> xTb [((b*3+g)*250+j)][2048] bf16
// ---------------------------------------------------------------------------
__global__ __launch_bounds__(256) void transpose_kernel(
    const float* __restrict__ x, ushort* __restrict__ xTt,
    ushort* __restrict__ xTb) {
  __shared__ float tile[64][65];
  const int b = blockIdx.z;
  const int t0 = blockIdx.x * 64, f0 = blockIdx.y * 64;
  const int tx = threadIdx.x & 63, ty4 = threadIdx.x >> 6;
#pragma unroll
  for (int i = 0; i < 16; ++i) {
    int lf = ty4 + i * 4;
    int t = t0 + tx;
    tile[lf][tx] = (t < kT) ? x[((size_t)b * kF + f0 + lf) * kT + t] : 0.f;
  }
  __syncthreads();
#pragma unroll
  for (int i = 0; i < 16; ++i) {
    int lt = ty4 + i * 4;
    int t = t0 + lt;
    if (t < kT) {
      ushort hv = f2bf(tile[tx][lt]);
      xTt[(size_t)(b * kT + t) * kF + f0 + tx] = hv;
      int g = t % 3, j = t / 3;
      xTb[(size_t)((b * 3 + g) * 250 + j) * kF + f0 + tx] = hv;
    }
  }
}

// ---------------------------------------------------------------------------
// Direct-conv GEMM, split-K. A = Wt [3][2048][2048] bf16; B = [cols][2048].
// Output partials Cpart[z][col][row] fp32. 128x128 tile, BK=64, 4 waves.
// Conv tap handled via per-lane B source address (col+tap-1, zero page OOB).
// ---------------------------------------------------------------------------
template <int L>
__global__ __launch_bounds__(256) void gemm_conv_kernel(
    const ushort* __restrict__ A, const ushort* __restrict__ B,
    const ushort* __restrict__ zpage, float* __restrict__ Cpart,
    int ncols, int NP, int ktn) {
  __shared__ ushort sA[128 * 64];
  __shared__ ushort sB[128 * 64];
  const int tid = threadIdx.x;
  const int w = tid >> 6, lane = tid & 63;
  const int wm = w >> 1, wn = w & 1;
  const int co0 = blockIdx.y * 128;
  const int col0 = blockIdx.x * 128;
  const int kt0 = blockIdx.z * ktn;
  const int srow = lane >> 3;
  const int selem = (lane & 7) * 8;
  f32x4 acc[4][4];
#pragma unroll
  for (int i = 0; i < 4; ++i)
#pragma unroll
    for (int j = 0; j < 4; ++j) acc[i][j] = (f32x4){0.f, 0.f, 0.f, 0.f};

  for (int kt = kt0; kt < kt0 + ktn; ++kt) {
    const int tap = kt >> 5;          // 32 K-steps per tap (2048/64)
    const int kin = (kt & 31) * 64;
    const size_t aoff = (size_t)tap * kF * kF + kin + selem;
#pragma unroll
    for (int i = 0; i < 4; ++i) {
      int r = (w * 4 + i) * 8 + srow;
      gload_lds16(A + aoff + (size_t)(co0 + r) * kF, &sA[(w * 4 + i) * 512]);
    }
#pragma unroll
    for (int i = 0; i < 4; ++i) {
      int r = (w * 4 + i) * 8 + srow;
      int col = col0 + r;
      int t = col - (col / L) * L;
      int tt = t + tap - 1;
      const ushort* src = (col < ncols && tt >= 0 && tt < L)
          ? B + (size_t)(col + tap - 1) * kF + kin + selem
          : zpage + selem;
      gload_lds16(src, &sB[(w * 4 + i) * 512]);
    }
    __syncthreads();
#pragma unroll
    for (int ksub = 0; ksub < 2; ++ksub) {
      bf16x8 af[4], bfv[4];
#pragma unroll
      for (int fm = 0; fm < 4; ++fm) {
        int row = wm * 64 + fm * 16 + (lane & 15);
        af[fm] = *(const bf16x8*)&sA[row * 64 + ksub * 32 + (lane >> 4) * 8];
      }
#pragma unroll
      for (int fn = 0; fn < 4; ++fn) {
        int row = wn * 64 + fn * 16 + (lane & 15);
        bfv[fn] = *(const bf16x8*)&sB[row * 64 + ksub * 32 + (lane >> 4) * 8];
      }
#pragma unroll
      for (int fm = 0; fm < 4; ++fm)
#pragma unroll
        for (int fn = 0; fn < 4; ++fn)
          acc[fm][fn] = __builtin_amdgcn_mfma_f32_16x16x32_bf16(
              af[fm], bfv[fn], acc[fm][fn], 0, 0, 0);
    }
    __syncthreads();
  }
  float* Cz = Cpart + (size_t)blockIdx.z * NP * kF;
#pragma unroll
  for (int fm = 0; fm < 4; ++fm) {
#pragma unroll
    for (int fn = 0; fn < 4; ++fn) {
      int col = col0 + wn * 64 + fn * 16 + (lane & 15);
      int row = co0 + wm * 64 + fm * 16 + ((lane >> 4) << 2);
      *(f32x4*)&Cz[(size_t)col * kF + row] = acc[fm][fn];
    }
  }
}

// ---------------------------------------------------------------------------
// reduce partials over S + bias + leaky -> bf16 [col][2048]
// ---------------------------------------------------------------------------
__global__ __launch_bounds__(256) void reduce_kernel(
    const float* __restrict__ Cpart, const float* __restrict__ bias,
    ushort* __restrict__ Y, int NP, int S) {
  const int col = blockIdx.x;
  const int row0 = (blockIdx.y * 256 + threadIdx.x) * 4;
  f32x4 a = *(const f32x4*)&Cpart[(size_t)col * kF + row0];
  for (int s = 1; s < S; ++s)
    a += *(const f32x4*)&Cpart[((size_t)s * NP + col) * kF + row0];
  f32x4 bv = *(const f32x4*)&bias[row0];
  ushort4 o;
  o.x = f2bf(leaky(a[0] + bv[0]));
  o.y = f2bf(leaky(a[1] + bv[1]));
  o.z = f2bf(leaky(a[2] + bv[2]));
  o.w = f2bf(leaky(a[3] + bv[3]));
  *(ushort4*)&Y[(size_t)col * kF + row0] = o;
}

// ---------------------------------------------------------------------------
// seq[b][c][t] = sum_ci wcb[c][ci] * h2[(b*750+t)][ci]
// ---------------------------------------------------------------------------
__global__ __launch_bounds__(256) void seqcas_kernel(
    const ushort* __restrict__ h2, const ushort* __restrict__ wcb,
    float* __restrict__ seq) {
  const int w = threadIdx.x >> 6, lane = threadIdx.x & 63;
  const int idx = blockIdx.x * 4 + w;
  if (idx >= 2 * kT) return;
  const ushort* hr = h2 + (size_t)idx * kF;
  float acc[kC];
#pragma unroll
  for (int c = 0; c < kC; ++c) acc[c] = 0.f;
#pragma unroll
  for (int ch = 0; ch < 4; ++ch) {
    const int ci0 = ch * 512 + lane * 8;
    ushort4 ha = *(const ushort4*)(hr + ci0);
    ushort4 hb = *(const ushort4*)(hr + ci0 + 4);
    float hx[8] = {bf2f(ha.x), bf2f(ha.y), bf2f(ha.z), bf2f(ha.w),
                   bf2f(hb.x), bf2f(hb.y), bf2f(hb.z), bf2f(hb.w)};
#pragma unroll
    for (int c = 0; c < kC; ++c) {
      const ushort* wr = wcb + c * kF + ci0;
      ushort4 wa4 = *(const ushort4*)wr;
      ushort4 wb4 = *(const ushort4*)(wr + 4);
      acc[c] += bf2f(wa4.x) * hx[0] + bf2f(wa4.y) * hx[1] +
                bf2f(wa4.z) * hx[2] + bf2f(wa4.w) * hx[3] +
                bf2f(wb4.x) * hx[4] + bf2f(wb4.y) * hx[5] +
                bf2f(wb4.z) * hx[6] + bf2f(wb4.w) * hx[7];
    }
  }
#pragma unroll
  for (int off = 32; off; off >>= 1)
#pragma unroll
    for (int c = 0; c < kC; ++c) acc[c] += __shfl_xor(acc[c], off);
  if (lane == 0) {
    int b = idx / kT, t = idx % kT;
#pragma unroll
    for (int c = 0; c < kC; ++c) seq[(size_t)(b * kC + c) * kT + t] = acc[c];
  }
}

// wa[b,c,t] = sigmoid(batt[c] + sum_a watt[c,a]*seq[b,a,t])
__global__ __launch_bounds__(256) void wa_kernel(
    const float* __restrict__ seq, const float* __restrict__ watt,
    const float* __restrict__ batt, float* __restrict__ wa) {
  const int idx = blockIdx.x * 256 + threadIdx.x;
  if (idx >= 2 * kT) return;
  const int b = idx / kT, t = idx % kT;
  float s[kC];
#pragma unroll
  for (int a = 0; a < kC; ++a) s[a] = seq[(size_t)(b * kC + a) * kT + t];
#pragma unroll
  for (int c = 0; c < kC; ++c) {
    float acc = batt[c];
#pragma unroll
    for (int a = 0; a < kC; ++a) acc += watt[c * kC + a] * s[a];
    wa[(size_t)(b * kC + c) * kT + t] = 1.f / (1.f + expf(-acc));
  }
}

// top-93 mean over T per (b,c) row — one wave per row, barrier-free
__global__ __launch_bounds__(64) void score_pre_kernel(
    const float* __restrict__ seq, float* __restrict__ out) {
  const int n = blockIdx.x;
  const int lane = threadIdx.x;
  float v[12];
#pragma unroll
  for (int i = 0; i < 12; ++i) {
    int idx = lane + i * 64;
    v[i] = (idx < kT) ? seq[(size_t)n * kT + idx] : -1e30f;
  }
  float sum = 0.f;
  for (int it = 0; it < kTop; ++it) {
    float lm = v[0];
#pragma unroll
    for (int i = 1; i < 12; ++i) lm = fmaxf(lm, v[i]);
    float wm = lm;
#pragma unroll
    for (int off = 32; off; off >>= 1) wm = fmaxf(wm, __shfl_xor(wm, off));
    sum += wm;
    unsigned long long ball = __ballot(lm == wm);
    int first = __ffsll(ball) - 1;
    bool own = (lane == first);
    bool done = false;
#pragma unroll
    for (int i = 0; i < 12; ++i) {
      bool hit = own && !done && (v[i] == wm);
      if (hit) { v[i] = -1e30f; done = true; }
    }
  }
  if (lane == 0) out[n] = sum / (float)kTop;
}

// fg: FeatY[((b*20+c)*3+g)][ci] = sum_j wa[b,c,j*3+g] * xTb[(b,g,j)][ci]
__global__ __launch_bounds__(256) void feat_kernel(
    const ushort* __restrict__ xTb, const float* __restrict__ wa,
    ushort* __restrict__ FeatY) {
  __shared__ float was[kC][250];
  const int b = blockIdx.z, g = blockIdx.y;
  const int ci = blockIdx.x * 256 + threadIdx.x;
  for (int i = threadIdx.x; i < kC * 250; i += 256) {
    int c = i / 250, j = i % 250;
    was[c][j] = wa[(size_t)(b * kC + c) * kT + j * 3 + g];
  }
  __syncthreads();
  float acc[kC] = {};
  const ushort* xp = xTb + (size_t)((b * 3 + g) * 250) * kF + ci;
  for (int j = 0; j < 250; ++j) {
    float xv = bf2f(xp[(size_t)j * kF]);
#pragma unroll
    for (int c = 0; c < kC; ++c) acc[c] += was[c][j] * xv;
  }
#pragma unroll
  for (int c = 0; c < kC; ++c)
    FeatY[(size_t)((b * kC + c) * 3 + g) * kF + ci] = f2bf(acc[c]);
}

// bg: FeatY[((40+b*400+c*20+a)*3+g)][ci] = sum_j wa[b,a]*(1-wa[b,c]) * xTb
__global__ __launch_bounds__(256) void agg_kernel(
    const ushort* __restrict__ xTb, const float* __restrict__ wa,
    ushort* __restrict__ FeatY) {
  __shared__ float ws2[kC][250];
  const int bg = blockIdx.z;
  const int b = bg / 3, g = bg % 3;
  const int c = blockIdx.y;
  const int ci = blockIdx.x * 256 + threadIdx.x;
  for (int i = threadIdx.x; i < kC * 250; i += 256) {
    int a = i / 250, j = i % 250;
    float waj = wa[(size_t)(b * kC + a) * kT + j * 3 + g];
    float wbj = 1.f - wa[(size_t)(b * kC + c) * kT + j * 3 + g];
    ws2[a][j] = waj * wbj;
  }
  __syncthreads();
  float acc[kC] = {};
  const ushort* xp = xTb + (size_t)((b * 3 + g) * 250) * kF + ci;
  for (int j = 0; j < 250; ++j) {
    float xv = bf2f(xp[(size_t)j * kF]);
#pragma unroll
    for (int a = 0; a < kC; ++a) acc[a] += ws2[a][j] * xv;
  }
#pragma unroll
  for (int a = 0; a < kC; ++a)
    FeatY[(size_t)((40 + b * 400 + c * kC + a) * 3 + g) * kF + ci] = f2bf(acc[a]);
}

// score[n] = (1/3) sum_g sum_co h[(n*3+g)][co] * wc[class(n)][co]
__global__ __launch_bounds__(256) void cls_kernel(
    const ushort* __restrict__ h, const float* __restrict__ wc,
    float* __restrict__ out40, float* __restrict__ scb) {
  __shared__ float red[256];
  const int n = blockIdx.x;
  const int tid = threadIdx.x;
  const int cls = (n < 40) ? (n % kC) : ((n - 40) % kC);
  const int co0 = tid * 8;
  const float4 w0 = *(const float4*)(wc + (size_t)cls * kF + co0);
  const float4 w1 = *(const float4*)(wc + (size_t)cls * kF + co0 + 4);
  float acc = 0.f;
#pragma unroll
  for (int g = 0; g < 3; ++g) {
    const ushort* hr = h + (size_t)(n * 3 + g) * kF + co0;
    ushort4 a = *(const ushort4*)hr;
    ushort4 b4 = *(const ushort4*)(hr + 4);
    acc += bf2f(a.x) * w0.x + bf2f(a.y) * w0.y + bf2f(a.z) * w0.z + bf2f(a.w) * w0.w +
           bf2f(b4.x) * w1.x + bf2f(b4.y) * w1.y + bf2f(b4.z) * w1.z + bf2f(b4.w) * w1.w;
  }
  red[tid] = acc;
  __syncthreads();
  for (int s = 128; s > 0; s >>= 1) {
    if (tid < s) red[tid] += red[tid + s];
    __syncthreads();
  }
  if (tid == 0) {
    float v = red[0] * (1.f / 3.f);
    if (n < 40) out40[n] = v; else scb[n - 40] = v;
  }
}

// collect + concat + softmax -> out[80 + b*40 + i]
__global__ void final_kernel(const float* __restrict__ score_post,
                             const float* __restrict__ sc_buf,
                             const int* __restrict__ label,
                             float* __restrict__ out) {
  __shared__ float z[2 * kC];
  __shared__ float collect[kC];
  const int b = blockIdx.x;
  const int tid = threadIdx.x;
  if (tid < kC) {
    int a = tid;
    float s = 0.f, ngt = 0.f;
    for (int c = 0; c < kC; ++c) {
      float m = label[b * kC + c] > 0 ? 1.f : 0.f;
      ngt += m;
      s += m * sc_buf[b * 400 + c * kC + a];
    }
    if (ngt < 1.f) ngt = 1.f;
    float col = s / ngt;
    if (label[b * kC + a] > 0) col = sc_buf[b * 400 + a * kC + a];
    collect[a] = col;
  }
  __syncthreads();
  if (tid < 2 * kC) z[tid] = (tid < kC) ? score_post[b * kC + tid] : collect[tid - kC];
  __syncthreads();
  if (tid == 0) {
    float mx = z[0];
    for (int i = 1; i < 2 * kC; ++i) mx = fmaxf(mx, z[i]);
    float s = 0.f;
    for (int i = 0; i < 2 * kC; ++i) { z[i] = expf(z[i] - mx); s += z[i]; }
    for (int i = 0; i < 2 * kC; ++i) out[80 + b * 2 * kC + i] = z[i] / s;
  }
}

extern "C" void kernel_launch(void* const* d_in, const int* in_sizes, int n_in,
                              void* d_out, int out_size, void* d_ws, size_t ws_size,
                              hipStream_t stream) {
  (void)in_sizes; (void)n_in; (void)out_size; (void)ws_size;
  const float* x    = (const float*)d_in[0];
  const float* w1   = (const float*)d_in[1];
  const float* b1   = (const float*)d_in[2];
  const float* w2   = (const float*)d_in[3];
  const float* b2   = (const float*)d_in[4];
  const float* wc   = (const float*)d_in[5];
  const float* watt = (const float*)d_in[6];
  const float* batt = (const float*)d_in[7];
  const int*   lbl  = (const int*)d_in[8];
  float* out = (float*)d_out;
  char*  wsb = (char*)d_ws;

  // workspace layout (bytes), peak ~140.1 MB (< R2's 148.9)
  ushort* Wt1   = (ushort*)(wsb + 0);           // 25,165,824  [3][2048][2048]
  ushort* Wt2   = (ushort*)(wsb + 25165824);    // 25,165,824
  ushort* wcb   = (ushort*)(wsb + 50331648);    // 81,920
  ushort* zpage = (ushort*)(wsb + 50413568);    // 4,096
  ushort* xTb   = (ushort*)(wsb + 50417664);    // 6,144,000
  ushort* xTt   = (ushort*)(wsb + 56561664);    // 6,144,000
  ushort* Ybuf  = (ushort*)(wsb + 62705664);    // 10,321,920 (Y1 / FeatY / Yp)
  ushort* h2    = (ushort*)(wsb + 73027584);    // 6,144,000
  ushort* hP2   = (ushort*)(wsb + 79171584);    // 10,321,920
  float*  seq   = (float*)(wsb + 89493504);     // 120,000
  float*  wab   = (float*)(wsb + 89613504);     // 120,000
  float*  scb   = (float*)(wsb + 89733504);     // 3,200
  float*  Ppart = (float*)(wsb + 89736704);     // 50,331,648 -> 140,068,352

  dim3 blk(256);
  convert_w_kernel<<<dim3(2048, 2), blk, 0, stream>>>(w1, w2, Wt1, Wt2, zpage);
  convert_kernel<<<dim3(40), blk, 0, stream>>>(wc, wcb, kC * kF);
  transpose_kernel<<<dim3(12, 32, 2), blk, 0, stream>>>(x, xTt, xTb);
  // main conv1: S=4, 768 blocks
  gemm_conv_kernel<750><<<dim3(12, 16, 4), blk, 0, stream>>>(
      Wt1, xTt, zpage, Ppart, 1500, 1536, 24);
  reduce_kernel<<<dim3(1500, 2), blk, 0, stream>>>(Ppart, b1, Ybuf, 1536, 4);
  // main conv2
  gemm_conv_kernel<750><<<dim3(12, 16, 4), blk, 0, stream>>>(
      Wt2, Ybuf, zpage, Ppart, 1500, 1536, 24);
  reduce_kernel<<<dim3(1500, 2), blk, 0, stream>>>(Ppart, b2, h2, 1536, 4);
  // attention path
  seqcas_kernel<<<dim3(375), blk, 0, stream>>>(h2, wcb, seq);
  wa_kernel<<<dim3(6), blk, 0, stream>>>(seq, watt, batt, wab);
  score_pre_kernel<<<dim3(40), dim3(64), 0, stream>>>(seq, out);  // out[0..39]
  // fg + bg aggregated features -> FeatY (840 samples x 3 cols = 2520)
  feat_kernel<<<dim3(8, 3, 2), blk, 0, stream>>>(xTb, wab, Ybuf);
  agg_kernel<<<dim3(8, kC, 6), blk, 0, stream>>>(xTb, wab, Ybuf);
  // post conv1: S=2, 640 blocks
  gemm_conv_kernel<3><<<dim3(20, 16, 2), blk, 0, stream>>>(
      Wt1, Ybuf, zpage, Ppart, 2520, 2560, 48);
  reduce_kernel<<<dim3(2520, 2), blk, 0, stream>>>(Ppart, b1, Ybuf, 2560, 2);
  // post conv2
  gemm_conv_kernel<3><<<dim3(20, 16, 2), blk, 0, stream>>>(
      Wt2, Ybuf, zpage, Ppart, 2520, 2560, 48);
  reduce_kernel<<<dim3(2520, 2), blk, 0, stream>>>(Ppart, b2, hP2, 2560, 2);
  // classifiers + final
  cls_kernel<<<dim3(840), blk, 0, stream>>>(hP2, wc, out + 40, scb);
  final_kernel<<<dim3(2), dim3(64), 0, stream>>>(out + 40, scb, lbl, out);
}

// Round 4
// 665.826 us; speedup vs baseline: 12.7027x; 1.0786x over previous
//
#include <hip/hip_runtime.h>
#include <math.h>

// ECMNet on gfx950 — bf16 MFMA direct-conv GEMM, split-K + LDS XOR-swizzle.
// B=2, F=2048, T=750, C=20, G=3, Tg=250, topK=93
namespace {
constexpr int kF = 2048;
constexpr int kT = 750;
constexpr int kC = 20;
constexpr int kTop = 93;
}

typedef __bf16 bf16x8 __attribute__((ext_vector_type(8)));
typedef float f32x4 __attribute__((ext_vector_type(4)));

__device__ __forceinline__ ushort f2bf(float f) {
  uint u = __builtin_bit_cast(uint, f);
  uint r = u + 0x7FFFu + ((u >> 16) & 1u);
  return (ushort)(r >> 16);
}
__device__ __forceinline__ float bf2f(ushort u) {
  return __builtin_bit_cast(float, ((uint)u) << 16);
}
__device__ __forceinline__ float leaky(float v) { return v > 0.f ? v : 0.01f * v; }

__device__ __forceinline__ void gload_lds16(const ushort* g, ushort* l) {
  __builtin_amdgcn_global_load_lds(
      (const __attribute__((address_space(1))) void*)g,
      (__attribute__((address_space(3))) void*)l, 16, 0, 0);
}

// ---------------------------------------------------------------------------
// weights [co][ci][3] fp32 -> Wt [tap][co][ci] bf16 (both w1,w2); zero page
// ---------------------------------------------------------------------------
__global__ __launch_bounds__(256) void convert_w_kernel(
    const float* __restrict__ w1, const float* __restrict__ w2,
    ushort* __restrict__ Wt1, ushort* __restrict__ Wt2,
    ushort* __restrict__ zpage) {
  const int co = blockIdx.x;
  const float* w = (blockIdx.y == 0) ? w1 : w2;
  ushort* Wt = (blockIdx.y == 0) ? Wt1 : Wt2;
  const int ci0 = threadIdx.x * 8;
  float v[24];
  const float4* p = (const float4*)(w + (size_t)co * 6144 + ci0 * 3);
#pragma unroll
  for (int s = 0; s < 6; ++s) {
    float4 f = p[s];
    v[s * 4 + 0] = f.x; v[s * 4 + 1] = f.y; v[s * 4 + 2] = f.z; v[s * 4 + 3] = f.w;
  }
#pragma unroll
  for (int tap = 0; tap < 3; ++tap) {
    ushort o[8];
#pragma unroll
    for (int j = 0; j < 8; ++j) o[j] = f2bf(v[j * 3 + tap]);
    ushort4 a = {o[0], o[1], o[2], o[3]}, b = {o[4], o[5], o[6], o[7]};
    ushort4* q = (ushort4*)(Wt + (size_t)tap * kF * kF + (size_t)co * kF + ci0);
    q[0] = a; q[1] = b;
  }
  if (blockIdx.x == 0 && blockIdx.y == 0) {
    ((float4*)zpage)[threadIdx.x] = (float4){0.f, 0.f, 0.f, 0.f};  // 4 KB zeros
  }
}

// fp32 -> bf16 plain (for wc)
__global__ __launch_bounds__(256) void convert_kernel(
    const float* __restrict__ src, ushort* __restrict__ dst, int n) {
  int i = (blockIdx.x * 256 + threadIdx.x) * 4;
  if (i + 3 < n) {
    float4 f = *(const float4*)(src + i);
    ushort4 o;
    o.x = f2bf(f.x); o.y = f2bf(f.y); o.z = f2bf(f.z); o.w = f2bf(f.w);
    *(ushort4*)(dst + i) = o;
  } else {
    for (; i < n; ++i) dst[i] = f2bf(src[i]);
  }
}

// ---------------------------------------------------------------------------
// x [2][2048][750] fp32 -> xTt [(b*750+t)][2048] bf16
//                       -> xTb [((b*3+g)*250+j)][2048] bf16
// ---------------------------------------------------------------------------
__global__ __launch_bounds__(256) void transpose_kernel(
    const float* __restrict__ x, ushort* __restrict__ xTt,
    ushort* __restrict__ xTb) {
  __shared__ float tile[64][65];
  const int b = blockIdx.z;
  const int t0 = blockIdx.x * 64, f0 = blockIdx.y * 64;
  const int tx = threadIdx.x & 63, ty4 = threadIdx.x >> 6;
#pragma unroll
  for (int i = 0; i < 16; ++i) {
    int lf = ty4 + i * 4;
    int t = t0 + tx;
    tile[lf][tx] = (t < kT) ? x[((size_t)b * kF + f0 + lf) * kT + t] : 0.f;
  }
  __syncthreads();
#pragma unroll
  for (int i = 0; i < 16; ++i) {
    int lt = ty4 + i * 4;
    int t = t0 + lt;
    if (t < kT) {
      ushort hv = f2bf(tile[tx][lt]);
      xTt[(size_t)(b * kT + t) * kF + f0 + tx] = hv;
      int g = t % 3, j = t / 3;
      xTb[(size_t)((b * 3 + g) * 250 + j) * kF + f0 + tx] = hv;
    }
  }
}

// ---------------------------------------------------------------------------
// Direct-conv GEMM, split-K. A = Wt [3][2048][2048] bf16; B = [cols][2048].
// Output partials Cpart[z][col][row] fp32. 128x128 tile, BK=64, 4 waves.
// LDS layout XOR-swizzled (T2): linear gload_lds dest + pre-swizzled global
// source column + XOR'd read column (rule #21: both sides, same involution).
// ---------------------------------------------------------------------------
template <int L>
__global__ __launch_bounds__(256) void gemm_conv_kernel(
    const ushort* __restrict__ A, const ushort* __restrict__ B,
    const ushort* __restrict__ zpage, float* __restrict__ Cpart,
    int ncols, int NP, int ktn) {
  __shared__ ushort sA[128 * 64];
  __shared__ ushort sB[128 * 64];
  const int tid = threadIdx.x;
  const int w = tid >> 6, lane = tid & 63;
  const int wm = w >> 1, wn = w & 1;
  const int co0 = blockIdx.y * 128;
  const int col0 = blockIdx.x * 128;
  const int kt0 = blockIdx.z * ktn;
  const int srow = lane >> 3;                              // 0..7
  const int selem = (((lane & 7) ^ srow) * 8);             // swizzled k-chunk
  f32x4 acc[4][4];
#pragma unroll
  for (int i = 0; i < 4; ++i)
#pragma unroll
    for (int j = 0; j < 4; ++j) acc[i][j] = (f32x4){0.f, 0.f, 0.f, 0.f};

  for (int kt = kt0; kt < kt0 + ktn; ++kt) {
    const int tap = kt >> 5;          // 32 K-steps per tap (2048/64)
    const int kin = (kt & 31) * 64;
    const size_t aoff = (size_t)tap * kF * kF + kin + selem;
#pragma unroll
    for (int i = 0; i < 4; ++i) {
      int r = (w * 4 + i) * 8 + srow;
      gload_lds16(A + aoff + (size_t)(co0 + r) * kF, &sA[(w * 4 + i) * 512]);
    }
#pragma unroll
    for (int i = 0; i < 4; ++i) {
      int r = (w * 4 + i) * 8 + srow;
      int col = col0 + r;
      int t = col - (col / L) * L;
      int tt = t + tap - 1;
      const ushort* src = (col < ncols && tt >= 0 && tt < L)
          ? B + (size_t)(col + tap - 1) * kF + kin + selem
          : zpage + selem;
      gload_lds16(src, &sB[(w * 4 + i) * 512]);
    }
    __syncthreads();
#pragma unroll
    for (int ksub = 0; ksub < 2; ++ksub) {
      bf16x8 af[4], bfv[4];
      const int rlow = lane & 7;                 // row&7 for both A and B frags
#pragma unroll
      for (int fm = 0; fm < 4; ++fm) {
        int row = wm * 64 + fm * 16 + (lane & 15);
        int c16 = (ksub * 4 + (lane >> 4)) ^ rlow;
        af[fm] = *(const bf16x8*)&sA[row * 64 + c16 * 8];
      }
#pragma unroll
      for (int fn = 0; fn < 4; ++fn) {
        int row = wn * 64 + fn * 16 + (lane & 15);
        int c16 = (ksub * 4 + (lane >> 4)) ^ rlow;
        bfv[fn] = *(const bf16x8*)&sB[row * 64 + c16 * 8];
      }
#pragma unroll
      for (int fm = 0; fm < 4; ++fm)
#pragma unroll
        for (int fn = 0; fn < 4; ++fn)
          acc[fm][fn] = __builtin_amdgcn_mfma_f32_16x16x32_bf16(
              af[fm], bfv[fn], acc[fm][fn], 0, 0, 0);
    }
    __syncthreads();
  }
  float* Cz = Cpart + (size_t)blockIdx.z * NP * kF;
#pragma unroll
  for (int fm = 0; fm < 4; ++fm) {
#pragma unroll
    for (int fn = 0; fn < 4; ++fn) {
      int col = col0 + wn * 64 + fn * 16 + (lane & 15);
      int row = co0 + wm * 64 + fm * 16 + ((lane >> 4) << 2);
      *(f32x4*)&Cz[(size_t)col * kF + row] = acc[fm][fn];
    }
  }
}

// ---------------------------------------------------------------------------
// reduce partials over S + bias + leaky -> bf16 [col][2048]
// ---------------------------------------------------------------------------
__global__ __launch_bounds__(256) void reduce_kernel(
    const float* __restrict__ Cpart, const float* __restrict__ bias,
    ushort* __restrict__ Y, int NP, int S) {
  const int col = blockIdx.x;
  const int row0 = (blockIdx.y * 256 + threadIdx.x) * 4;
  f32x4 a = *(const f32x4*)&Cpart[(size_t)col * kF + row0];
  for (int s = 1; s < S; ++s)
    a += *(const f32x4*)&Cpart[((size_t)s * NP + col) * kF + row0];
  f32x4 bv = *(const f32x4*)&bias[row0];
  ushort4 o;
  o.x = f2bf(leaky(a[0] + bv[0]));
  o.y = f2bf(leaky(a[1] + bv[1]));
  o.z = f2bf(leaky(a[2] + bv[2]));
  o.w = f2bf(leaky(a[3] + bv[3]));
  *(ushort4*)&Y[(size_t)col * kF + row0] = o;
}

// ---------------------------------------------------------------------------
// seq[b][c][t] = sum_ci wcb[c][ci] * h2[(b*750+t)][ci]
// ---------------------------------------------------------------------------
__global__ __launch_bounds__(256) void seqcas_kernel(
    const ushort* __restrict__ h2, const ushort* __restrict__ wcb,
    float* __restrict__ seq) {
  const int w = threadIdx.x >> 6, lane = threadIdx.x & 63;
  const int idx = blockIdx.x * 4 + w;
  if (idx >= 2 * kT) return;
  const ushort* hr = h2 + (size_t)idx * kF;
  float acc[kC];
#pragma unroll
  for (int c = 0; c < kC; ++c) acc[c] = 0.f;
#pragma unroll
  for (int ch = 0; ch < 4; ++ch) {
    const int ci0 = ch * 512 + lane * 8;
    ushort4 ha = *(const ushort4*)(hr + ci0);
    ushort4 hb = *(const ushort4*)(hr + ci0 + 4);
    float hx[8] = {bf2f(ha.x), bf2f(ha.y), bf2f(ha.z), bf2f(ha.w),
                   bf2f(hb.x), bf2f(hb.y), bf2f(hb.z), bf2f(hb.w)};
#pragma unroll
    for (int c = 0; c < kC; ++c) {
      const ushort* wr = wcb + c * kF + ci0;
      ushort4 wa4 = *(const ushort4*)wr;
      ushort4 wb4 = *(const ushort4*)(wr + 4);
      acc[c] += bf2f(wa4.x) * hx[0] + bf2f(wa4.y) * hx[1] +
                bf2f(wa4.z) * hx[2] + bf2f(wa4.w) * hx[3] +
                bf2f(wb4.x) * hx[4] + bf2f(wb4.y) * hx[5] +
                bf2f(wb4.z) * hx[6] + bf2f(wb4.w) * hx[7];
    }
  }
#pragma unroll
  for (int off = 32; off; off >>= 1)
#pragma unroll
    for (int c = 0; c < kC; ++c) acc[c] += __shfl_xor(acc[c], off);
  if (lane == 0) {
    int b = idx / kT, t = idx % kT;
#pragma unroll
    for (int c = 0; c < kC; ++c) seq[(size_t)(b * kC + c) * kT + t] = acc[c];
  }
}

// wa[b,c,t] = sigmoid(batt[c] + sum_a watt[c,a]*seq[b,a,t])
__global__ __launch_bounds__(256) void wa_kernel(
    const float* __restrict__ seq, const float* __restrict__ watt,
    const float* __restrict__ batt, float* __restrict__ wa) {
  const int idx = blockIdx.x * 256 + threadIdx.x;
  if (idx >= 2 * kT) return;
  const int b = idx / kT, t = idx % kT;
  float s[kC];
#pragma unroll
  for (int a = 0; a < kC; ++a) s[a] = seq[(size_t)(b * kC + a) * kT + t];
#pragma unroll
  for (int c = 0; c < kC; ++c) {
    float acc = batt[c];
#pragma unroll
    for (int a = 0; a < kC; ++a) acc += watt[c * kC + a] * s[a];
    wa[(size_t)(b * kC + c) * kT + t] = 1.f / (1.f + expf(-acc));
  }
}

// top-93 mean over T per (b,c) row — one wave per row, barrier-free
__global__ __launch_bounds__(64) void score_pre_kernel(
    const float* __restrict__ seq, float* __restrict__ out) {
  const int n = blockIdx.x;
  const int lane = threadIdx.x;
  float v[12];
#pragma unroll
  for (int i = 0; i < 12; ++i) {
    int idx = lane + i * 64;
    v[i] = (idx < kT) ? seq[(size_t)n * kT + idx] : -1e30f;
  }
  float sum = 0.f;
  for (int it = 0; it < kTop; ++it) {
    float lm = v[0];
#pragma unroll
    for (int i = 1; i < 12; ++i) lm = fmaxf(lm, v[i]);
    float wm = lm;
#pragma unroll
    for (int off = 32; off; off >>= 1) wm = fmaxf(wm, __shfl_xor(wm, off));
    sum += wm;
    unsigned long long ball = __ballot(lm == wm);
    int first = __ffsll(ball) - 1;
    bool own = (lane == first);
    bool done = false;
#pragma unroll
    for (int i = 0; i < 12; ++i) {
      bool hit = own && !done && (v[i] == wm);
      if (hit) { v[i] = -1e30f; done = true; }
    }
  }
  if (lane == 0) out[n] = sum / (float)kTop;
}

// fg: FeatY[((b*20+c)*3+g)][ci] = sum_j wa[b,c,j*3+g] * xTb[(b,g,j)][ci]
__global__ __launch_bounds__(256) void feat_kernel(
    const ushort* __restrict__ xTb, const float* __restrict__ wa,
    ushort* __restrict__ FeatY) {
  __shared__ float was[kC][250];
  const int b = blockIdx.z, g = blockIdx.y;
  const int ci = blockIdx.x * 256 + threadIdx.x;
  for (int i = threadIdx.x; i < kC * 250; i += 256) {
    int c = i / 250, j = i % 250;
    was[c][j] = wa[(size_t)(b * kC + c) * kT + j * 3 + g];
  }
  __syncthreads();
  float acc[kC] = {};
  const ushort* xp = xTb + (size_t)((b * 3 + g) * 250) * kF + ci;
  for (int j = 0; j < 250; ++j) {
    float xv = bf2f(xp[(size_t)j * kF]);
#pragma unroll
    for (int c = 0; c < kC; ++c) acc[c] += was[c][j] * xv;
  }
#pragma unroll
  for (int c = 0; c < kC; ++c)
    FeatY[(size_t)((b * kC + c) * 3 + g) * kF + ci] = f2bf(acc[c]);
}

// bg: FeatY[((40+b*400+c*20+a)*3+g)][ci] = sum_j wa[b,a]*(1-wa[b,c]) * xTb
__global__ __launch_bounds__(256) void agg_kernel(
    const ushort* __restrict__ xTb, const float* __restrict__ wa,
    ushort* __restrict__ FeatY) {
  __shared__ float ws2[kC][250];
  const int bg = blockIdx.z;
  const int b = bg / 3, g = bg % 3;
  const int c = blockIdx.y;
  const int ci = blockIdx.x * 256 + threadIdx.x;
  for (int i = threadIdx.x; i < kC * 250; i += 256) {
    int a = i / 250, j = i % 250;
    float waj = wa[(size_t)(b * kC + a) * kT + j * 3 + g];
    float wbj = 1.f - wa[(size_t)(b * kC + c) * kT + j * 3 + g];
    ws2[a][j] = waj * wbj;
  }
  __syncthreads();
  float acc[kC] = {};
  const ushort* xp = xTb + (size_t)((b * 3 + g) * 250) * kF + ci;
  for (int j = 0; j < 250; ++j) {
    float xv = bf2f(xp[(size_t)j * kF]);
#pragma unroll
    for (int a = 0; a < kC; ++a) acc[a] += ws2[a][j] * xv;
  }
#pragma unroll
  for (int a = 0; a < kC; ++a)
    FeatY[(size_t)((40 + b * 400 + c * kC + a) * 3 + g) * kF + ci] = f2bf(acc[a]);
}

// score[n] = (1/3) sum_g sum_co h[(n*3+g)][co] * wc[class(n)][co]
__global__ __launch_bounds__(256) void cls_kernel(
    const ushort* __restrict__ h, const float* __restrict__ wc,
    float* __restrict__ out40, float* __restrict__ scb) {
  __shared__ float red[256];
  const int n = blockIdx.x;
  const int tid = threadIdx.x;
  const int cls = (n < 40) ? (n % kC) : ((n - 40) % kC);
  const int co0 = tid * 8;
  const float4 w0 = *(const float4*)(wc + (size_t)cls * kF + co0);
  const float4 w1 = *(const float4*)(wc + (size_t)cls * kF + co0 + 4);
  float acc = 0.f;
#pragma unroll
  for (int g = 0; g < 3; ++g) {
    const ushort* hr = h + (size_t)(n * 3 + g) * kF + co0;
    ushort4 a = *(const ushort4*)hr;
    ushort4 b4 = *(const ushort4*)(hr + 4);
    acc += bf2f(a.x) * w0.x + bf2f(a.y) * w0.y + bf2f(a.z) * w0.z + bf2f(a.w) * w0.w +
           bf2f(b4.x) * w1.x + bf2f(b4.y) * w1.y + bf2f(b4.z) * w1.z + bf2f(b4.w) * w1.w;
  }
  red[tid] = acc;
  __syncthreads();
  for (int s = 128; s > 0; s >>= 1) {
    if (tid < s) red[tid] += red[tid + s];
    __syncthreads();
  }
  if (tid == 0) {
    float v = red[0] * (1.f / 3.f);
    if (n < 40) out40[n] = v; else scb[n - 40] = v;
  }
}

// collect + concat + softmax -> out[80 + b*40 + i]
__global__ void final_kernel(const float* __restrict__ score_post,
                             const float* __restrict__ sc_buf,
                             const int* __restrict__ label,
                             float* __restrict__ out) {
  __shared__ float z[2 * kC];
  __shared__ float collect[kC];
  const int b = blockIdx.x;
  const int tid = threadIdx.x;
  if (tid < kC) {
    int a = tid;
    float s = 0.f, ngt = 0.f;
    for (int c = 0; c < kC; ++c) {
      float m = label[b * kC + c] > 0 ? 1.f : 0.f;
      ngt += m;
      s += m * sc_buf[b * 400 + c * kC + a];
    }
    if (ngt < 1.f) ngt = 1.f;
    float col = s / ngt;
    if (label[b * kC + a] > 0) col = sc_buf[b * 400 + a * kC + a];
    collect[a] = col;
  }
  __syncthreads();
  if (tid < 2 * kC) z[tid] = (tid < kC) ? score_post[b * kC + tid] : collect[tid - kC];
  __syncthreads();
  if (tid == 0) {
    float mx = z[0];
    for (int i = 1; i < 2 * kC; ++i) mx = fmaxf(mx, z[i]);
    float s = 0.f;
    for (int i = 0; i < 2 * kC; ++i) { z[i] = expf(z[i] - mx); s += z[i]; }
    for (int i = 0; i < 2 * kC; ++i) out[80 + b * 2 * kC + i] = z[i] / s;
  }
}

extern "C" void kernel_launch(void* const* d_in, const int* in_sizes, int n_in,
                              void* d_out, int out_size, void* d_ws, size_t ws_size,
                              hipStream_t stream) {
  (void)in_sizes; (void)n_in; (void)out_size;
  const float* x    = (const float*)d_in[0];
  const float* w1   = (const float*)d_in[1];
  const float* b1   = (const float*)d_in[2];
  const float* w2   = (const float*)d_in[3];
  const float* b2   = (const float*)d_in[4];
  const float* wc   = (const float*)d_in[5];
  const float* watt = (const float*)d_in[6];
  const float* batt = (const float*)d_in[7];
  const int*   lbl  = (const int*)d_in[8];
  float* out = (float*)d_out;
  char*  wsb = (char*)d_ws;

  // workspace layout (bytes); Ppart sized by dynamic split-K choice below
  ushort* Wt1   = (ushort*)(wsb + 0);           // 25,165,824  [3][2048][2048]
  ushort* Wt2   = (ushort*)(wsb + 25165824);    // 25,165,824
  ushort* wcb   = (ushort*)(wsb + 50331648);    // 81,920
  ushort* zpage = (ushort*)(wsb + 50413568);    // 4,096
  ushort* xTb   = (ushort*)(wsb + 50417664);    // 6,144,000
  ushort* xTt   = (ushort*)(wsb + 56561664);    // 6,144,000
  ushort* Ybuf  = (ushort*)(wsb + 62705664);    // 10,321,920 (Y1 / FeatY / Yp)
  ushort* h2    = (ushort*)(wsb + 73027584);    // 6,144,000
  ushort* hP2   = (ushort*)(wsb + 79171584);    // 10,321,920
  float*  seq   = (float*)(wsb + 89493504);     // 120,000
  float*  wab   = (float*)(wsb + 89613504);     // 120,000
  float*  scb   = (float*)(wsb + 89733504);     // 3,200
  const size_t ppart_off = 89736704;
  float*  Ppart = (float*)(wsb + ppart_off);

  // dynamic split-K: prefer S_main=8 (100.7 MB partials), S_post=4 (83.9 MB)
  const size_t avail = (ws_size > ppart_off) ? ws_size - ppart_off : 0;
  const int S_main = (avail >= (size_t)8 * 1536 * 2048 * 4) ? 8 : 4;
  const int S_post = (avail >= (size_t)4 * 2560 * 2048 * 4) ? 4 : 2;

  dim3 blk(256);
  convert_w_kernel<<<dim3(2048, 2), blk, 0, stream>>>(w1, w2, Wt1, Wt2, zpage);
  convert_kernel<<<dim3(40), blk, 0, stream>>>(wc, wcb, kC * kF);
  transpose_kernel<<<dim3(12, 32, 2), blk, 0, stream>>>(x, xTt, xTb);
  // main conv1
  gemm_conv_kernel<750><<<dim3(12, 16, S_main), blk, 0, stream>>>(
      Wt1, xTt, zpage, Ppart, 1500, 1536, 96 / S_main);
  reduce_kernel<<<dim3(1500, 2), blk, 0, stream>>>(Ppart, b1, Ybuf, 1536, S_main);
  // main conv2
  gemm_conv_kernel<750><<<dim3(12, 16, S_main), blk, 0, stream>>>(
      Wt2, Ybuf, zpage, Ppart, 1500, 1536, 96 / S_main);
  reduce_kernel<<<dim3(1500, 2), blk, 0, stream>>>(Ppart, b2, h2, 1536, S_main);
  // attention path
  seqcas_kernel<<<dim3(375), blk, 0, stream>>>(h2, wcb, seq);
  wa_kernel<<<dim3(6), blk, 0, stream>>>(seq, watt, batt, wab);
  score_pre_kernel<<<dim3(40), dim3(64), 0, stream>>>(seq, out);  // out[0..39]
  // fg + bg aggregated features -> FeatY (840 samples x 3 cols = 2520)
  feat_kernel<<<dim3(8, 3, 2), blk, 0, stream>>>(xTb, wab, Ybuf);
  agg_kernel<<<dim3(8, kC, 6), blk, 0, stream>>>(xTb, wab, Ybuf);
  // post conv1
  gemm_conv_kernel<3><<<dim3(20, 16, S_post), blk, 0, stream>>>(
      Wt1, Ybuf, zpage, Ppart, 2520, 2560, 96 / S_post);
  reduce_kernel<<<dim3(2520, 2), blk, 0, stream>>>(Ppart, b1, Ybuf, 2560, S_post);
  // post conv2
  gemm_conv_kernel<3><<<dim3(20, 16, S_post), blk, 0, stream>>>(
      Wt2, Ybuf, zpage, Ppart, 2520, 2560, S_post == 4 ? 24 : 48);
  reduce_kernel<<<dim3(2520, 2), blk, 0, stream>>>(Ppart, b2, hP2, 2560, S_post);
  // classifiers + final
  cls_kernel<<<dim3(840), blk, 0, stream>>>(hP2, wc, out + 40, scb);
  final_kernel<<<dim3(2), dim3(64), 0, stream>>>(out + 40, scb, lbl, out);
}

// Round 5
// 634.338 us; speedup vs baseline: 13.3332x; 1.0496x over previous
//
#include <hip/hip_runtime.h>
#include <math.h>

// ECMNet on gfx950 — bf16 MFMA direct-conv GEMM, split-K + swizzle +
// 2-phase double-buffered K-loop (issue-early / drain-late, raw s_barrier).
// B=2, F=2048, T=750, C=20, G=3, Tg=250, topK=93
namespace {
constexpr int kF = 2048;
constexpr int kT = 750;
constexpr int kC = 20;
constexpr int kTop = 93;
}

typedef __bf16 bf16x8 __attribute__((ext_vector_type(8)));
typedef float f32x4 __attribute__((ext_vector_type(4)));

__device__ __forceinline__ ushort f2bf(float f) {
  uint u = __builtin_bit_cast(uint, f);
  uint r = u + 0x7FFFu + ((u >> 16) & 1u);
  return (ushort)(r >> 16);
}
__device__ __forceinline__ float bf2f(ushort u) {
  return __builtin_bit_cast(float, ((uint)u) << 16);
}
__device__ __forceinline__ float leaky(float v) { return v > 0.f ? v : 0.01f * v; }

__device__ __forceinline__ void gload_lds16(const ushort* g, ushort* l) {
  __builtin_amdgcn_global_load_lds(
      (const __attribute__((address_space(1))) void*)g,
      (__attribute__((address_space(3))) void*)l, 16, 0, 0);
}

// ---------------------------------------------------------------------------
// weights [co][ci][3] fp32 -> Wt [tap][co][ci] bf16 (both w1,w2); zero page
// ---------------------------------------------------------------------------
__global__ __launch_bounds__(256) void convert_w_kernel(
    const float* __restrict__ w1, const float* __restrict__ w2,
    ushort* __restrict__ Wt1, ushort* __restrict__ Wt2,
    ushort* __restrict__ zpage) {
  const int co = blockIdx.x;
  const float* w = (blockIdx.y == 0) ? w1 : w2;
  ushort* Wt = (blockIdx.y == 0) ? Wt1 : Wt2;
  const int ci0 = threadIdx.x * 8;
  float v[24];
  const float4* p = (const float4*)(w + (size_t)co * 6144 + ci0 * 3);
#pragma unroll
  for (int s = 0; s < 6; ++s) {
    float4 f = p[s];
    v[s * 4 + 0] = f.x; v[s * 4 + 1] = f.y; v[s * 4 + 2] = f.z; v[s * 4 + 3] = f.w;
  }
#pragma unroll
  for (int tap = 0; tap < 3; ++tap) {
    ushort o[8];
#pragma unroll
    for (int j = 0; j < 8; ++j) o[j] = f2bf(v[j * 3 + tap]);
    ushort4 a = {o[0], o[1], o[2], o[3]}, b = {o[4], o[5], o[6], o[7]};
    ushort4* q = (ushort4*)(Wt + (size_t)tap * kF * kF + (size_t)co * kF + ci0);
    q[0] = a; q[1] = b;
  }
  if (blockIdx.x == 0 && blockIdx.y == 0) {
    ((float4*)zpage)[threadIdx.x] = (float4){0.f, 0.f, 0.f, 0.f};  // 4 KB zeros
  }
}

// fp32 -> bf16 plain (for wc)
__global__ __launch_bounds__(256) void convert_kernel(
    const float* __restrict__ src, ushort* __restrict__ dst, int n) {
  int i = (blockIdx.x * 256 + threadIdx.x) * 4;
  if (i + 3 < n) {
    float4 f = *(const float4*)(src + i);
    ushort4 o;
    o.x = f2bf(f.x); o.y = f2bf(f.y); o.z = f2bf(f.z); o.w = f2bf(f.w);
    *(ushort4*)(dst + i) = o;
  } else {
    for (; i < n; ++i) dst[i] = f2bf(src[i]);
  }
}

// ---------------------------------------------------------------------------
// x [2][2048][750] fp32 -> xTt [(b*750+t)][2048] bf16
//                       -> xTb [((b*3+g)*250+j)][2048] bf16
// ---------------------------------------------------------------------------
__global__ __launch_bounds__(256) void transpose_kernel(
    const float* __restrict__ x, ushort* __restrict__ xTt,
    ushort* __restrict__ xTb) {
  __shared__ float tile[64][65];
  const int b = blockIdx.z;
  const int t0 = blockIdx.x * 64, f0 = blockIdx.y * 64;
  const int tx = threadIdx.x & 63, ty4 = threadIdx.x >> 6;
#pragma unroll
  for (int i = 0; i < 16; ++i) {
    int lf = ty4 + i * 4;
    int t = t0 + tx;
    tile[lf][tx] = (t < kT) ? x[((size_t)b * kF + f0 + lf) * kT + t] : 0.f;
  }
  __syncthreads();
#pragma unroll
  for (int i = 0; i < 16; ++i) {
    int lt = ty4 + i * 4;
    int t = t0 + lt;
    if (t < kT) {
      ushort hv = f2bf(tile[tx][lt]);
      xTt[(size_t)(b * kT + t) * kF + f0 + tx] = hv;
      int g = t % 3, j = t / 3;
      xTb[(size_t)((b * 3 + g) * 250 + j) * kF + f0 + tx] = hv;
    }
  }
}

// ---------------------------------------------------------------------------
// Direct-conv GEMM, split-K, 2-phase double-buffered.
// A = Wt [3][2048][2048] bf16; B = [cols][2048] bf16.
// Cpart[z][col][row] fp32. 128x128 tile, BK=64, 4 waves.
// LDS XOR-swizzle (T2) via pre-swizzled global source + XOR'd read column.
// K-loop: STAGE(next buf) -> compute(cur) -> vmcnt(0) -> raw s_barrier.
// Prefetch latency hides under ~32 MFMA + 16 ds_read of the compute phase.
// ---------------------------------------------------------------------------
template <int L>
__global__ __launch_bounds__(256) void gemm_conv_kernel(
    const ushort* __restrict__ A, const ushort* __restrict__ B,
    const ushort* __restrict__ zpage, float* __restrict__ Cpart,
    int ncols, int NP, int ktn) {
  __shared__ ushort sA[2][128 * 64];   // 32 KB x2
  __shared__ ushort sB[2][128 * 64];   // 32 KB x2  (total 64 KB -> 2 blocks/CU)
  const int tid = threadIdx.x;
  const int w = tid >> 6, lane = tid & 63;
  const int wm = w >> 1, wn = w & 1;
  const int co0 = blockIdx.y * 128;
  const int col0 = blockIdx.x * 128;
  const int kt0 = blockIdx.z * ktn;
  const int srow = lane >> 3;                    // 0..7
  const int selem = ((lane & 7) ^ srow) * 8;     // swizzled k-chunk (involution)
  f32x4 acc[4][4];
#pragma unroll
  for (int i = 0; i < 4; ++i)
#pragma unroll
    for (int j = 0; j < 4; ++j) acc[i][j] = (f32x4){0.f, 0.f, 0.f, 0.f};

  auto STAGE = [&](int buf, int kt) {
    const int tap = kt >> 5;          // 32 K-steps per tap (2048/64)
    const int kin = (kt & 31) * 64;
    const size_t aoff = (size_t)tap * kF * kF + kin + selem;
#pragma unroll
    for (int i = 0; i < 4; ++i) {
      int r = (w * 4 + i) * 8 + srow;
      gload_lds16(A + aoff + (size_t)(co0 + r) * kF, &sA[buf][(w * 4 + i) * 512]);
    }
#pragma unroll
    for (int i = 0; i < 4; ++i) {
      int r = (w * 4 + i) * 8 + srow;
      int col = col0 + r;
      int t = col - (col / L) * L;
      int tt = t + tap - 1;
      const ushort* src = (col < ncols && tt >= 0 && tt < L)
          ? B + (size_t)(col + tap - 1) * kF + kin + selem
          : zpage + selem;
      gload_lds16(src, &sB[buf][(w * 4 + i) * 512]);
    }
  };

  // prologue: fill buf 0, drain, sync
  STAGE(0, kt0);
  asm volatile("s_waitcnt vmcnt(0)" ::: "memory");
  __builtin_amdgcn_s_barrier();

  int cur = 0;
  for (int kt = kt0; kt < kt0 + ktn; ++kt) {
    if (kt + 1 < kt0 + ktn) STAGE(cur ^ 1, kt + 1);   // issue-early
#pragma unroll
    for (int ksub = 0; ksub < 2; ++ksub) {
      bf16x8 af[4], bfv[4];
      const int rlow = lane & 7;
#pragma unroll
      for (int fm = 0; fm < 4; ++fm) {
        int row = wm * 64 + fm * 16 + (lane & 15);
        int c16 = (ksub * 4 + (lane >> 4)) ^ rlow;
        af[fm] = *(const bf16x8*)&sA[cur][row * 64 + c16 * 8];
      }
#pragma unroll
      for (int fn = 0; fn < 4; ++fn) {
        int row = wn * 64 + fn * 16 + (lane & 15);
        int c16 = (ksub * 4 + (lane >> 4)) ^ rlow;
        bfv[fn] = *(const bf16x8*)&sB[cur][row * 64 + c16 * 8];
      }
#pragma unroll
      for (int fm = 0; fm < 4; ++fm)
#pragma unroll
        for (int fn = 0; fn < 4; ++fn)
          acc[fm][fn] = __builtin_amdgcn_mfma_f32_16x16x32_bf16(
              af[fm], bfv[fn], acc[fm][fn], 0, 0, 0);
    }
    // drain-late: prefetch had the whole compute phase to land
    asm volatile("s_waitcnt vmcnt(0)" ::: "memory");
    __builtin_amdgcn_s_barrier();
    cur ^= 1;
  }

  float* Cz = Cpart + (size_t)blockIdx.z * NP * kF;
#pragma unroll
  for (int fm = 0; fm < 4; ++fm) {
#pragma unroll
    for (int fn = 0; fn < 4; ++fn) {
      int col = col0 + wn * 64 + fn * 16 + (lane & 15);
      int row = co0 + wm * 64 + fm * 16 + ((lane >> 4) << 2);
      *(f32x4*)&Cz[(size_t)col * kF + row] = acc[fm][fn];
    }
  }
}

// ---------------------------------------------------------------------------
// reduce partials over S + bias + leaky -> bf16 [col][2048]
// ---------------------------------------------------------------------------
__global__ __launch_bounds__(256) void reduce_kernel(
    const float* __restrict__ Cpart, const float* __restrict__ bias,
    ushort* __restrict__ Y, int NP, int S) {
  const int col = blockIdx.x;
  const int row0 = (blockIdx.y * 256 + threadIdx.x) * 4;
  f32x4 a = *(const f32x4*)&Cpart[(size_t)col * kF + row0];
  for (int s = 1; s < S; ++s)
    a += *(const f32x4*)&Cpart[((size_t)s * NP + col) * kF + row0];
  f32x4 bv = *(const f32x4*)&bias[row0];
  ushort4 o;
  o.x = f2bf(leaky(a[0] + bv[0]));
  o.y = f2bf(leaky(a[1] + bv[1]));
  o.z = f2bf(leaky(a[2] + bv[2]));
  o.w = f2bf(leaky(a[3] + bv[3]));
  *(ushort4*)&Y[(size_t)col * kF + row0] = o;
}

// ---------------------------------------------------------------------------
// seq[b][c][t] = sum_ci wcb[c][ci] * h2[(b*750+t)][ci]; fused wa = sigmoid(...)
// ---------------------------------------------------------------------------
__global__ __launch_bounds__(256) void seqcas_kernel(
    const ushort* __restrict__ h2, const ushort* __restrict__ wcb,
    const float* __restrict__ watt, const float* __restrict__ batt,
    float* __restrict__ seq, float* __restrict__ wa) {
  const int w = threadIdx.x >> 6, lane = threadIdx.x & 63;
  const int idx = blockIdx.x * 4 + w;
  if (idx >= 2 * kT) return;
  const ushort* hr = h2 + (size_t)idx * kF;
  float acc[kC];
#pragma unroll
  for (int c = 0; c < kC; ++c) acc[c] = 0.f;
#pragma unroll
  for (int ch = 0; ch < 4; ++ch) {
    const int ci0 = ch * 512 + lane * 8;
    ushort4 ha = *(const ushort4*)(hr + ci0);
    ushort4 hb = *(const ushort4*)(hr + ci0 + 4);
    float hx[8] = {bf2f(ha.x), bf2f(ha.y), bf2f(ha.z), bf2f(ha.w),
                   bf2f(hb.x), bf2f(hb.y), bf2f(hb.z), bf2f(hb.w)};
#pragma unroll
    for (int c = 0; c < kC; ++c) {
      const ushort* wr = wcb + c * kF + ci0;
      ushort4 wa4 = *(const ushort4*)wr;
      ushort4 wb4 = *(const ushort4*)(wr + 4);
      acc[c] += bf2f(wa4.x) * hx[0] + bf2f(wa4.y) * hx[1] +
                bf2f(wa4.z) * hx[2] + bf2f(wa4.w) * hx[3] +
                bf2f(wb4.x) * hx[4] + bf2f(wb4.y) * hx[5] +
                bf2f(wb4.z) * hx[6] + bf2f(wb4.w) * hx[7];
    }
  }
#pragma unroll
  for (int off = 32; off; off >>= 1)
#pragma unroll
    for (int c = 0; c < kC; ++c) acc[c] += __shfl_xor(acc[c], off);
  if (lane == 0) {
    int b = idx / kT, t = idx % kT;
#pragma unroll
    for (int c = 0; c < kC; ++c) seq[(size_t)(b * kC + c) * kT + t] = acc[c];
#pragma unroll
    for (int c = 0; c < kC; ++c) {
      float z = batt[c];
#pragma unroll
      for (int a = 0; a < kC; ++a) z += watt[c * kC + a] * acc[a];
      wa[(size_t)(b * kC + c) * kT + t] = 1.f / (1.f + expf(-z));
    }
  }
}

// top-93 mean over T per (b,c) row — one wave per row, barrier-free
__global__ __launch_bounds__(64) void score_pre_kernel(
    const float* __restrict__ seq, float* __restrict__ out) {
  const int n = blockIdx.x;
  const int lane = threadIdx.x;
  float v[12];
#pragma unroll
  for (int i = 0; i < 12; ++i) {
    int idx = lane + i * 64;
    v[i] = (idx < kT) ? seq[(size_t)n * kT + idx] : -1e30f;
  }
  float sum = 0.f;
  for (int it = 0; it < kTop; ++it) {
    float lm = v[0];
#pragma unroll
    for (int i = 1; i < 12; ++i) lm = fmaxf(lm, v[i]);
    float wm = lm;
#pragma unroll
    for (int off = 32; off; off >>= 1) wm = fmaxf(wm, __shfl_xor(wm, off));
    sum += wm;
    unsigned long long ball = __ballot(lm == wm);
    int first = __ffsll(ball) - 1;
    bool own = (lane == first);
    bool done = false;
#pragma unroll
    for (int i = 0; i < 12; ++i) {
      bool hit = own && !done && (v[i] == wm);
      if (hit) { v[i] = -1e30f; done = true; }
    }
  }
  if (lane == 0) out[n] = sum / (float)kTop;
}

// fg: FeatY[((b*20+c)*3+g)][ci] = sum_j wa[b,c,j*3+g] * xTb[(b,g,j)][ci]
__global__ __launch_bounds__(256) void feat_kernel(
    const ushort* __restrict__ xTb, const float* __restrict__ wa,
    ushort* __restrict__ FeatY) {
  __shared__ float was[kC][250];
  const int b = blockIdx.z, g = blockIdx.y;
  const int ci = blockIdx.x * 256 + threadIdx.x;
  for (int i = threadIdx.x; i < kC * 250; i += 256) {
    int c = i / 250, j = i % 250;
    was[c][j] = wa[(size_t)(b * kC + c) * kT + j * 3 + g];
  }
  __syncthreads();
  float acc[kC] = {};
  const ushort* xp = xTb + (size_t)((b * 3 + g) * 250) * kF + ci;
  for (int j = 0; j < 250; ++j) {
    float xv = bf2f(xp[(size_t)j * kF]);
#pragma unroll
    for (int c = 0; c < kC; ++c) acc[c] += was[c][j] * xv;
  }
#pragma unroll
  for (int c = 0; c < kC; ++c)
    FeatY[(size_t)((b * kC + c) * 3 + g) * kF + ci] = f2bf(acc[c]);
}

// bg: FeatY[((40+b*400+c*20+a)*3+g)][ci] = sum_j wa[b,a]*(1-wa[b,c]) * xTb
__global__ __launch_bounds__(256) void agg_kernel(
    const ushort* __restrict__ xTb, const float* __restrict__ wa,
    ushort* __restrict__ FeatY) {
  __shared__ float ws2[kC][250];
  const int bg = blockIdx.z;
  const int b = bg / 3, g = bg % 3;
  const int c = blockIdx.y;
  const int ci = blockIdx.x * 256 + threadIdx.x;
  for (int i = threadIdx.x; i < kC * 250; i += 256) {
    int a = i / 250, j = i % 250;
    float waj = wa[(size_t)(b * kC + a) * kT + j * 3 + g];
    float wbj = 1.f - wa[(size_t)(b * kC + c) * kT + j * 3 + g];
    ws2[a][j] = waj * wbj;
  }
  __syncthreads();
  float acc[kC] = {};
  const ushort* xp = xTb + (size_t)((b * 3 + g) * 250) * kF + ci;
  for (int j = 0; j < 250; ++j) {
    float xv = bf2f(xp[(size_t)j * kF]);
#pragma unroll
    for (int a = 0; a < kC; ++a) acc[a] += ws2[a][j] * xv;
  }
#pragma unroll
  for (int a = 0; a < kC; ++a)
    FeatY[(size_t)((40 + b * 400 + c * kC + a) * 3 + g) * kF + ci] = f2bf(acc[a]);
}

// score[n] = (1/3) sum_g sum_co h[(n*3+g)][co] * wc[class(n)][co]
__global__ __launch_bounds__(256) void cls_kernel(
    const ushort* __restrict__ h, const float* __restrict__ wc,
    float* __restrict__ out40, float* __restrict__ scb) {
  __shared__ float red[256];
  const int n = blockIdx.x;
  const int tid = threadIdx.x;
  const int cls = (n < 40) ? (n % kC) : ((n - 40) % kC);
  const int co0 = tid * 8;
  const float4 w0 = *(const float4*)(wc + (size_t)cls * kF + co0);
  const float4 w1 = *(const float4*)(wc + (size_t)cls * kF + co0 + 4);
  float acc = 0.f;
#pragma unroll
  for (int g = 0; g < 3; ++g) {
    const ushort* hr = h + (size_t)(n * 3 + g) * kF + co0;
    ushort4 a = *(const ushort4*)hr;
    ushort4 b4 = *(const ushort4*)(hr + 4);
    acc += bf2f(a.x) * w0.x + bf2f(a.y) * w0.y + bf2f(a.z) * w0.z + bf2f(a.w) * w0.w +
           bf2f(b4.x) * w1.x + bf2f(b4.y) * w1.y + bf2f(b4.z) * w1.z + bf2f(b4.w) * w1.w;
  }
  red[tid] = acc;
  __syncthreads();
  for (int s = 128; s > 0; s >>= 1) {
    if (tid < s) red[tid] += red[tid + s];
    __syncthreads();
  }
  if (tid == 0) {
    float v = red[0] * (1.f / 3.f);
    if (n < 40) out40[n] = v; else scb[n - 40] = v;
  }
}

// collect + concat + softmax -> out[80 + b*40 + i]
__global__ void final_kernel(const float* __restrict__ score_post,
                             const float* __restrict__ sc_buf,
                             const int* __restrict__ label,
                             float* __restrict__ out) {
  __shared__ float z[2 * kC];
  __shared__ float collect[kC];
  const int b = blockIdx.x;
  const int tid = threadIdx.x;
  if (tid < kC) {
    int a = tid;
    float s = 0.f, ngt = 0.f;
    for (int c = 0; c < kC; ++c) {
      float m = label[b * kC + c] > 0 ? 1.f : 0.f;
      ngt += m;
      s += m * sc_buf[b * 400 + c * kC + a];
    }
    if (ngt < 1.f) ngt = 1.f;
    float col = s / ngt;
    if (label[b * kC + a] > 0) col = sc_buf[b * 400 + a * kC + a];
    collect[a] = col;
  }
  __syncthreads();
  if (tid < 2 * kC) z[tid] = (tid < kC) ? score_post[b * kC + tid] : collect[tid - kC];
  __syncthreads();
  if (tid == 0) {
    float mx = z[0];
    for (int i = 1; i < 2 * kC; ++i) mx = fmaxf(mx, z[i]);
    float s = 0.f;
    for (int i = 0; i < 2 * kC; ++i) { z[i] = expf(z[i] - mx); s += z[i]; }
    for (int i = 0; i < 2 * kC; ++i) out[80 + b * 2 * kC + i] = z[i] / s;
  }
}

extern "C" void kernel_launch(void* const* d_in, const int* in_sizes, int n_in,
                              void* d_out, int out_size, void* d_ws, size_t ws_size,
                              hipStream_t stream) {
  (void)in_sizes; (void)n_in; (void)out_size;
  const float* x    = (const float*)d_in[0];
  const float* w1   = (const float*)d_in[1];
  const float* b1   = (const float*)d_in[2];
  const float* w2   = (const float*)d_in[3];
  const float* b2   = (const float*)d_in[4];
  const float* wc   = (const float*)d_in[5];
  const float* watt = (const float*)d_in[6];
  const float* batt = (const float*)d_in[7];
  const int*   lbl  = (const int*)d_in[8];
  float* out = (float*)d_out;
  char*  wsb = (char*)d_ws;

  // workspace layout (bytes); Ppart sized by dynamic split-K choice below
  ushort* Wt1   = (ushort*)(wsb + 0);           // 25,165,824  [3][2048][2048]
  ushort* Wt2   = (ushort*)(wsb + 25165824);    // 25,165,824
  ushort* wcb   = (ushort*)(wsb + 50331648);    // 81,920
  ushort* zpage = (ushort*)(wsb + 50413568);    // 4,096
  ushort* xTb   = (ushort*)(wsb + 50417664);    // 6,144,000
  ushort* xTt   = (ushort*)(wsb + 56561664);    // 6,144,000
  ushort* Ybuf  = (ushort*)(wsb + 62705664);    // 10,321,920 (Y1 / FeatY / Yp)
  ushort* h2    = (ushort*)(wsb + 73027584);    // 6,144,000
  ushort* hP2   = (ushort*)(wsb + 79171584);    // 10,321,920
  float*  seq   = (float*)(wsb + 89493504);     // 120,000
  float*  wab   = (float*)(wsb + 89613504);     // 120,000
  float*  scb   = (float*)(wsb + 89733504);     // 3,200
  const size_t ppart_off = 89736704;
  float*  Ppart = (float*)(wsb + ppart_off);

  // dynamic split-K: prefer S_main=8 (100.7 MB partials), S_post=4 (83.9 MB)
  const size_t avail = (ws_size > ppart_off) ? ws_size - ppart_off : 0;
  const int S_main = (avail >= (size_t)8 * 1536 * 2048 * 4) ? 8 : 4;
  const int S_post = (avail >= (size_t)4 * 2560 * 2048 * 4) ? 4 : 2;

  dim3 blk(256);
  convert_w_kernel<<<dim3(2048, 2), blk, 0, stream>>>(w1, w2, Wt1, Wt2, zpage);
  convert_kernel<<<dim3(40), blk, 0, stream>>>(wc, wcb, kC * kF);
  transpose_kernel<<<dim3(12, 32, 2), blk, 0, stream>>>(x, xTt, xTb);
  // main conv1
  gemm_conv_kernel<750><<<dim3(12, 16, S_main), blk, 0, stream>>>(
      Wt1, xTt, zpage, Ppart, 1500, 1536, 96 / S_main);
  reduce_kernel<<<dim3(1500, 2), blk, 0, stream>>>(Ppart, b1, Ybuf, 1536, S_main);
  // main conv2
  gemm_conv_kernel<750><<<dim3(12, 16, S_main), blk, 0, stream>>>(
      Wt2, Ybuf, zpage, Ppart, 1500, 1536, 96 / S_main);
  reduce_kernel<<<dim3(1500, 2), blk, 0, stream>>>(Ppart, b2, h2, 1536, S_main);
  // attention path (wa fused into seqcas)
  seqcas_kernel<<<dim3(375), blk, 0, stream>>>(h2, wcb, watt, batt, seq, wab);
  score_pre_kernel<<<dim3(40), dim3(64), 0, stream>>>(seq, out);  // out[0..39]
  // fg + bg aggregated features -> FeatY (840 samples x 3 cols = 2520)
  feat_kernel<<<dim3(8, 3, 2), blk, 0, stream>>>(xTb, wab, Ybuf);
  agg_kernel<<<dim3(8, kC, 6), blk, 0, stream>>>(xTb, wab, Ybuf);
  // post conv1
  gemm_conv_kernel<3><<<dim3(20, 16, S_post), blk, 0, stream>>>(
      Wt1, Ybuf, zpage, Ppart, 2520, 2560, 96 / S_post);
  reduce_kernel<<<dim3(2520, 2), blk, 0, stream>>>(Ppart, b1, Ybuf, 2560, S_post);
  // post conv2
  gemm_conv_kernel<3><<<dim3(20, 16, S_post), blk, 0, stream>>>(
      Wt2, Ybuf, zpage, Ppart, 2520, 2560, S_post == 4 ? 24 : 48);
  reduce_kernel<<<dim3(2520, 2), blk, 0, stream>>>(Ppart, b2, hP2, 2560, S_post);
  // classifiers + final
  cls_kernel<<<dim3(840), blk, 0, stream>>>(hP2, wc, out + 40, scb);
  final_kernel<<<dim3(2), dim3(64), 0, stream>>>(out + 40, scb, lbl, out);
}

// Round 6
// 519.208 us; speedup vs baseline: 16.2898x; 1.2217x over previous
//
#include <hip/hip_runtime.h>
#include <math.h>

// ECMNet on gfx950 — bf16 MFMA direct-conv GEMM, split-K + swizzle + 2-phase
// dbuf; feat/agg aggregation folded into an MFMA GEMM (R6).
// B=2, F=2048, T=750, C=20, G=3, Tg=250, topK=93
namespace {
constexpr int kF = 2048;
constexpr int kT = 750;
constexpr int kC = 20;
constexpr int kTop = 93;
}

typedef __bf16 bf16x8 __attribute__((ext_vector_type(8)));
typedef float f32x4 __attribute__((ext_vector_type(4)));

__device__ __forceinline__ ushort f2bf(float f) {
  uint u = __builtin_bit_cast(uint, f);
  uint r = u + 0x7FFFu + ((u >> 16) & 1u);
  return (ushort)(r >> 16);
}
__device__ __forceinline__ float bf2f(ushort u) {
  return __builtin_bit_cast(float, ((uint)u) << 16);
}
__device__ __forceinline__ float leaky(float v) { return v > 0.f ? v : 0.01f * v; }

__device__ __forceinline__ void gload_lds16(const ushort* g, ushort* l) {
  __builtin_amdgcn_global_load_lds(
      (const __attribute__((address_space(1))) void*)g,
      (__attribute__((address_space(3))) void*)l, 16, 0, 0);
}

// ---------------------------------------------------------------------------
// weights [co][ci][3] fp32 -> Wt [tap][co][ci] bf16 (both w1,w2); zero page
// ---------------------------------------------------------------------------
__global__ __launch_bounds__(256) void convert_w_kernel(
    const float* __restrict__ w1, const float* __restrict__ w2,
    ushort* __restrict__ Wt1, ushort* __restrict__ Wt2,
    ushort* __restrict__ zpage) {
  const int co = blockIdx.x;
  const float* w = (blockIdx.y == 0) ? w1 : w2;
  ushort* Wt = (blockIdx.y == 0) ? Wt1 : Wt2;
  const int ci0 = threadIdx.x * 8;
  float v[24];
  const float4* p = (const float4*)(w + (size_t)co * 6144 + ci0 * 3);
#pragma unroll
  for (int s = 0; s < 6; ++s) {
    float4 f = p[s];
    v[s * 4 + 0] = f.x; v[s * 4 + 1] = f.y; v[s * 4 + 2] = f.z; v[s * 4 + 3] = f.w;
  }
#pragma unroll
  for (int tap = 0; tap < 3; ++tap) {
    ushort o[8];
#pragma unroll
    for (int j = 0; j < 8; ++j) o[j] = f2bf(v[j * 3 + tap]);
    ushort4 a = {o[0], o[1], o[2], o[3]}, b = {o[4], o[5], o[6], o[7]};
    ushort4* q = (ushort4*)(Wt + (size_t)tap * kF * kF + (size_t)co * kF + ci0);
    q[0] = a; q[1] = b;
  }
  if (blockIdx.x == 0 && blockIdx.y == 0) {
    ((float4*)zpage)[threadIdx.x] = (float4){0.f, 0.f, 0.f, 0.f};  // 4 KB zeros
  }
}

// fp32 -> bf16 plain (for wc)
__global__ __launch_bounds__(256) void convert_kernel(
    const float* __restrict__ src, ushort* __restrict__ dst, int n) {
  int i = (blockIdx.x * 256 + threadIdx.x) * 4;
  if (i + 3 < n) {
    float4 f = *(const float4*)(src + i);
    ushort4 o;
    o.x = f2bf(f.x); o.y = f2bf(f.y); o.z = f2bf(f.z); o.w = f2bf(f.w);
    *(ushort4*)(dst + i) = o;
  } else {
    for (; i < n; ++i) dst[i] = f2bf(src[i]);
  }
}

// ---------------------------------------------------------------------------
// x [2][2048][750] fp32 -> xTt [(b*750+t)][2048] bf16
// ---------------------------------------------------------------------------
__global__ __launch_bounds__(256) void transpose_kernel(
    const float* __restrict__ x, ushort* __restrict__ xTt) {
  __shared__ float tile[64][65];
  const int b = blockIdx.z;
  const int t0 = blockIdx.x * 64, f0 = blockIdx.y * 64;
  const int tx = threadIdx.x & 63, ty4 = threadIdx.x >> 6;
#pragma unroll
  for (int i = 0; i < 16; ++i) {
    int lf = ty4 + i * 4;
    int t = t0 + tx;
    tile[lf][tx] = (t < kT) ? x[((size_t)b * kF + f0 + lf) * kT + t] : 0.f;
  }
  __syncthreads();
#pragma unroll
  for (int i = 0; i < 16; ++i) {
    int lt = ty4 + i * 4;
    int t = t0 + lt;
    if (t < kT)
      xTt[(size_t)(b * kT + t) * kF + f0 + tx] = f2bf(tile[tx][lt]);
  }
}

// ---------------------------------------------------------------------------
// xJ[((b*3+g)*2048+f)][j] = x[b][f][j*3+g] bf16, j in [0,256), pad 0
// ---------------------------------------------------------------------------
__global__ __launch_bounds__(256) void xj_kernel(
    const float* __restrict__ x, ushort* __restrict__ xJ) {
  const int bid = blockIdx.x;           // 0..4095
  const int b = bid >> 11, f = bid & 2047;
  __shared__ float buf[768];
  const float* xr = x + ((size_t)b * kF + f) * kT;
  for (int t = threadIdx.x; t < kT; t += 256) buf[t] = xr[t];
  __syncthreads();
  const int j = threadIdx.x;
#pragma unroll
  for (int g = 0; g < 3; ++g) {
    float v = (j < 250) ? buf[j * 3 + g] : 0.f;
    xJ[(((size_t)(b * 3 + g) * kF + f) << 8) + j] = f2bf(v);
  }
}

// ---------------------------------------------------------------------------
// W2[bg][r][j] bf16: r<20 fg rows wa[c=r]; 20<=r<420 bg rows wa[a]*(1-wa[c]);
// zeros elsewhere. grid (6, 16), 32 rows/block.
// ---------------------------------------------------------------------------
__global__ __launch_bounds__(256) void ww_build_kernel(
    const float* __restrict__ wab, ushort* __restrict__ W2) {
  const int bg = blockIdx.x;
  const int b = bg / 3, g = bg % 3;
  const int r0 = blockIdx.y * 32;
  __shared__ float ws[kC][256];
  for (int i = threadIdx.x; i < kC * 250; i += 256) {
    int c = i / 250, j = i % 250;
    ws[c][j] = wab[(size_t)(b * kC + c) * kT + j * 3 + g];
  }
  __syncthreads();
  ushort* Wb = W2 + (size_t)bg * 512 * 256;
  const int j = threadIdx.x;
#pragma unroll 4
  for (int rr = 0; rr < 32; ++rr) {
    int r = r0 + rr;
    float v = 0.f;
    if (j < 250 && r < 420) {
      if (r < kC) {
        v = ws[r][j];
      } else {
        int idx = r - kC;
        int c = idx / kC, a = idx % kC;
        v = ws[a][j] * (1.f - ws[c][j]);
      }
    }
    Wb[(size_t)r * 256 + j] = f2bf(v);
  }
}

// ---------------------------------------------------------------------------
// ww GEMM: FeatY[(sampleg*3+g)][f] = sum_j W2[bg][s][j] * xJ[bg][f][j]
// A = xJ[bg] [2048][256], B = W2[bg] [512][256]. 128x128 tile, K=256 (4 steps),
// 2-phase dbuf + swizzle (same structure as gemm_conv).
// ---------------------------------------------------------------------------
__global__ __launch_bounds__(256) void ww_gemm_kernel(
    const ushort* __restrict__ xJ, const ushort* __restrict__ W2,
    ushort* __restrict__ FeatY) {
  __shared__ ushort sA[2][128 * 64];
  __shared__ ushort sB[2][128 * 64];
  const int tid = threadIdx.x;
  const int w = tid >> 6, lane = tid & 63;
  const int wm = w >> 1, wn = w & 1;
  const int bg = blockIdx.z;
  const int f0 = blockIdx.y * 128;
  const int s0 = blockIdx.x * 128;
  const ushort* A = xJ + ((size_t)bg * kF << 8);
  const ushort* Bp = W2 + (size_t)bg * 512 * 256;
  const int srow = lane >> 3;
  const int selem = ((lane & 7) ^ srow) * 8;
  f32x4 acc[4][4];
#pragma unroll
  for (int i = 0; i < 4; ++i)
#pragma unroll
    for (int j = 0; j < 4; ++j) acc[i][j] = (f32x4){0.f, 0.f, 0.f, 0.f};

  auto STAGE = [&](int buf, int kt) {
    const int kin = kt * 64;
#pragma unroll
    for (int i = 0; i < 4; ++i) {
      int r = (w * 4 + i) * 8 + srow;
      gload_lds16(A + (size_t)(f0 + r) * 256 + kin + selem,
                  &sA[buf][(w * 4 + i) * 512]);
    }
#pragma unroll
    for (int i = 0; i < 4; ++i) {
      int r = (w * 4 + i) * 8 + srow;
      gload_lds16(Bp + (size_t)(s0 + r) * 256 + kin + selem,
                  &sB[buf][(w * 4 + i) * 512]);
    }
  };

  STAGE(0, 0);
  asm volatile("s_waitcnt vmcnt(0)" ::: "memory");
  __builtin_amdgcn_s_barrier();

  int cur = 0;
  for (int kt = 0; kt < 4; ++kt) {
    if (kt + 1 < 4) STAGE(cur ^ 1, kt + 1);
#pragma unroll
    for (int ksub = 0; ksub < 2; ++ksub) {
      bf16x8 af[4], bfv[4];
      const int rlow = lane & 7;
#pragma unroll
      for (int fm = 0; fm < 4; ++fm) {
        int row = wm * 64 + fm * 16 + (lane & 15);
        int c16 = (ksub * 4 + (lane >> 4)) ^ rlow;
        af[fm] = *(const bf16x8*)&sA[cur][row * 64 + c16 * 8];
      }
#pragma unroll
      for (int fn = 0; fn < 4; ++fn) {
        int row = wn * 64 + fn * 16 + (lane & 15);
        int c16 = (ksub * 4 + (lane >> 4)) ^ rlow;
        bfv[fn] = *(const bf16x8*)&sB[cur][row * 64 + c16 * 8];
      }
#pragma unroll
      for (int fm = 0; fm < 4; ++fm)
#pragma unroll
        for (int fn = 0; fn < 4; ++fn)
          acc[fm][fn] = __builtin_amdgcn_mfma_f32_16x16x32_bf16(
              af[fm], bfv[fn], acc[fm][fn], 0, 0, 0);
    }
    asm volatile("s_waitcnt vmcnt(0)" ::: "memory");
    __builtin_amdgcn_s_barrier();
    cur ^= 1;
  }

  const int b = bg / 3, g = bg % 3;
#pragma unroll
  for (int fm = 0; fm < 4; ++fm) {
#pragma unroll
    for (int fn = 0; fn < 4; ++fn) {
      int s = s0 + wn * 64 + fn * 16 + (lane & 15);
      if (s >= 420) continue;
      int sampleg = (s < kC) ? (b * kC + s) : (40 + b * 400 + (s - kC));
      int row = f0 + wm * 64 + fm * 16 + ((lane >> 4) << 2);
      ushort4 o;
      o.x = f2bf(acc[fm][fn][0]);
      o.y = f2bf(acc[fm][fn][1]);
      o.z = f2bf(acc[fm][fn][2]);
      o.w = f2bf(acc[fm][fn][3]);
      *(ushort4*)&FeatY[(size_t)(sampleg * 3 + g) * kF + row] = o;
    }
  }
}

// ---------------------------------------------------------------------------
// Direct-conv GEMM, split-K, 2-phase double-buffered (unchanged from R5).
// ---------------------------------------------------------------------------
template <int L>
__global__ __launch_bounds__(256) void gemm_conv_kernel(
    const ushort* __restrict__ A, const ushort* __restrict__ B,
    const ushort* __restrict__ zpage, float* __restrict__ Cpart,
    int ncols, int NP, int ktn) {
  __shared__ ushort sA[2][128 * 64];
  __shared__ ushort sB[2][128 * 64];
  const int tid = threadIdx.x;
  const int w = tid >> 6, lane = tid & 63;
  const int wm = w >> 1, wn = w & 1;
  const int co0 = blockIdx.y * 128;
  const int col0 = blockIdx.x * 128;
  const int kt0 = blockIdx.z * ktn;
  const int srow = lane >> 3;
  const int selem = ((lane & 7) ^ srow) * 8;
  f32x4 acc[4][4];
#pragma unroll
  for (int i = 0; i < 4; ++i)
#pragma unroll
    for (int j = 0; j < 4; ++j) acc[i][j] = (f32x4){0.f, 0.f, 0.f, 0.f};

  auto STAGE = [&](int buf, int kt) {
    const int tap = kt >> 5;
    const int kin = (kt & 31) * 64;
    const size_t aoff = (size_t)tap * kF * kF + kin + selem;
#pragma unroll
    for (int i = 0; i < 4; ++i) {
      int r = (w * 4 + i) * 8 + srow;
      gload_lds16(A + aoff + (size_t)(co0 + r) * kF, &sA[buf][(w * 4 + i) * 512]);
    }
#pragma unroll
    for (int i = 0; i < 4; ++i) {
      int r = (w * 4 + i) * 8 + srow;
      int col = col0 + r;
      int t = col - (col / L) * L;
      int tt = t + tap - 1;
      const ushort* src = (col < ncols && tt >= 0 && tt < L)
          ? B + (size_t)(col + tap - 1) * kF + kin + selem
          : zpage + selem;
      gload_lds16(src, &sB[buf][(w * 4 + i) * 512]);
    }
  };

  STAGE(0, kt0);
  asm volatile("s_waitcnt vmcnt(0)" ::: "memory");
  __builtin_amdgcn_s_barrier();

  int cur = 0;
  for (int kt = kt0; kt < kt0 + ktn; ++kt) {
    if (kt + 1 < kt0 + ktn) STAGE(cur ^ 1, kt + 1);
#pragma unroll
    for (int ksub = 0; ksub < 2; ++ksub) {
      bf16x8 af[4], bfv[4];
      const int rlow = lane & 7;
#pragma unroll
      for (int fm = 0; fm < 4; ++fm) {
        int row = wm * 64 + fm * 16 + (lane & 15);
        int c16 = (ksub * 4 + (lane >> 4)) ^ rlow;
        af[fm] = *(const bf16x8*)&sA[cur][row * 64 + c16 * 8];
      }
#pragma unroll
      for (int fn = 0; fn < 4; ++fn) {
        int row = wn * 64 + fn * 16 + (lane & 15);
        int c16 = (ksub * 4 + (lane >> 4)) ^ rlow;
        bfv[fn] = *(const bf16x8*)&sB[cur][row * 64 + c16 * 8];
      }
#pragma unroll
      for (int fm = 0; fm < 4; ++fm)
#pragma unroll
        for (int fn = 0; fn < 4; ++fn)
          acc[fm][fn] = __builtin_amdgcn_mfma_f32_16x16x32_bf16(
              af[fm], bfv[fn], acc[fm][fn], 0, 0, 0);
    }
    asm volatile("s_waitcnt vmcnt(0)" ::: "memory");
    __builtin_amdgcn_s_barrier();
    cur ^= 1;
  }

  float* Cz = Cpart + (size_t)blockIdx.z * NP * kF;
#pragma unroll
  for (int fm = 0; fm < 4; ++fm) {
#pragma unroll
    for (int fn = 0; fn < 4; ++fn) {
      int col = col0 + wn * 64 + fn * 16 + (lane & 15);
      int row = co0 + wm * 64 + fm * 16 + ((lane >> 4) << 2);
      *(f32x4*)&Cz[(size_t)col * kF + row] = acc[fm][fn];
    }
  }
}

// ---------------------------------------------------------------------------
// reduce partials over S + bias + leaky -> bf16 [col][2048]
// ---------------------------------------------------------------------------
__global__ __launch_bounds__(256) void reduce_kernel(
    const float* __restrict__ Cpart, const float* __restrict__ bias,
    ushort* __restrict__ Y, int NP, int S) {
  const int col = blockIdx.x;
  const int row0 = (blockIdx.y * 256 + threadIdx.x) * 4;
  f32x4 a = *(const f32x4*)&Cpart[(size_t)col * kF + row0];
  for (int s = 1; s < S; ++s)
    a += *(const f32x4*)&Cpart[((size_t)s * NP + col) * kF + row0];
  f32x4 bv = *(const f32x4*)&bias[row0];
  ushort4 o;
  o.x = f2bf(leaky(a[0] + bv[0]));
  o.y = f2bf(leaky(a[1] + bv[1]));
  o.z = f2bf(leaky(a[2] + bv[2]));
  o.w = f2bf(leaky(a[3] + bv[3]));
  *(ushort4*)&Y[(size_t)col * kF + row0] = o;
}

// ---------------------------------------------------------------------------
// seq[b][c][t] = sum_ci wcb[c][ci] * h2[(b*750+t)][ci]; fused wa = sigmoid(...)
// ---------------------------------------------------------------------------
__global__ __launch_bounds__(256) void seqcas_kernel(
    const ushort* __restrict__ h2, const ushort* __restrict__ wcb,
    const float* __restrict__ watt, const float* __restrict__ batt,
    float* __restrict__ seq, float* __restrict__ wa) {
  const int w = threadIdx.x >> 6, lane = threadIdx.x & 63;
  const int idx = blockIdx.x * 4 + w;
  if (idx >= 2 * kT) return;
  const ushort* hr = h2 + (size_t)idx * kF;
  float acc[kC];
#pragma unroll
  for (int c = 0; c < kC; ++c) acc[c] = 0.f;
#pragma unroll
  for (int ch = 0; ch < 4; ++ch) {
    const int ci0 = ch * 512 + lane * 8;
    ushort4 ha = *(const ushort4*)(hr + ci0);
    ushort4 hb = *(const ushort4*)(hr + ci0 + 4);
    float hx[8] = {bf2f(ha.x), bf2f(ha.y), bf2f(ha.z), bf2f(ha.w),
                   bf2f(hb.x), bf2f(hb.y), bf2f(hb.z), bf2f(hb.w)};
#pragma unroll
    for (int c = 0; c < kC; ++c) {
      const ushort* wr = wcb + c * kF + ci0;
      ushort4 wa4 = *(const ushort4*)wr;
      ushort4 wb4 = *(const ushort4*)(wr + 4);
      acc[c] += bf2f(wa4.x) * hx[0] + bf2f(wa4.y) * hx[1] +
                bf2f(wa4.z) * hx[2] + bf2f(wa4.w) * hx[3] +
                bf2f(wb4.x) * hx[4] + bf2f(wb4.y) * hx[5] +
                bf2f(wb4.z) * hx[6] + bf2f(wb4.w) * hx[7];
    }
  }
#pragma unroll
  for (int off = 32; off; off >>= 1)
#pragma unroll
    for (int c = 0; c < kC; ++c) acc[c] += __shfl_xor(acc[c], off);
  if (lane == 0) {
    int b = idx / kT, t = idx % kT;
#pragma unroll
    for (int c = 0; c < kC; ++c) seq[(size_t)(b * kC + c) * kT + t] = acc[c];
#pragma unroll
    for (int c = 0; c < kC; ++c) {
      float z = batt[c];
#pragma unroll
      for (int a = 0; a < kC; ++a) z += watt[c * kC + a] * acc[a];
      wa[(size_t)(b * kC + c) * kT + t] = 1.f / (1.f + expf(-z));
    }
  }
}

// top-93 mean over T per (b,c) row — one wave per row, barrier-free
__global__ __launch_bounds__(64) void score_pre_kernel(
    const float* __restrict__ seq, float* __restrict__ out) {
  const int n = blockIdx.x;
  const int lane = threadIdx.x;
  float v[12];
#pragma unroll
  for (int i = 0; i < 12; ++i) {
    int idx = lane + i * 64;
    v[i] = (idx < kT) ? seq[(size_t)n * kT + idx] : -1e30f;
  }
  float sum = 0.f;
  for (int it = 0; it < kTop; ++it) {
    float lm = v[0];
#pragma unroll
    for (int i = 1; i < 12; ++i) lm = fmaxf(lm, v[i]);
    float wm = lm;
#pragma unroll
    for (int off = 32; off; off >>= 1) wm = fmaxf(wm, __shfl_xor(wm, off));
    sum += wm;
    unsigned long long ball = __ballot(lm == wm);
    int first = __ffsll(ball) - 1;
    bool own = (lane == first);
    bool done = false;
#pragma unroll
    for (int i = 0; i < 12; ++i) {
      bool hit = own && !done && (v[i] == wm);
      if (hit) { v[i] = -1e30f; done = true; }
    }
  }
  if (lane == 0) out[n] = sum / (float)kTop;
}

// score[n] = (1/3) sum_g sum_co h[(n*3+g)][co] * wc[class(n)][co]
__global__ __launch_bounds__(256) void cls_kernel(
    const ushort* __restrict__ h, const float* __restrict__ wc,
    float* __restrict__ out40, float* __restrict__ scb) {
  __shared__ float red[256];
  const int n = blockIdx.x;
  const int tid = threadIdx.x;
  const int cls = (n < 40) ? (n % kC) : ((n - 40) % kC);
  const int co0 = tid * 8;
  const float4 w0 = *(const float4*)(wc + (size_t)cls * kF + co0);
  const float4 w1 = *(const float4*)(wc + (size_t)cls * kF + co0 + 4);
  float acc = 0.f;
#pragma unroll
  for (int g = 0; g < 3; ++g) {
    const ushort* hr = h + (size_t)(n * 3 + g) * kF + co0;
    ushort4 a = *(const ushort4*)hr;
    ushort4 b4 = *(const ushort4*)(hr + 4);
    acc += bf2f(a.x) * w0.x + bf2f(a.y) * w0.y + bf2f(a.z) * w0.z + bf2f(a.w) * w0.w +
           bf2f(b4.x) * w1.x + bf2f(b4.y) * w1.y + bf2f(b4.z) * w1.z + bf2f(b4.w) * w1.w;
  }
  red[tid] = acc;
  __syncthreads();
  for (int s = 128; s > 0; s >>= 1) {
    if (tid < s) red[tid] += red[tid + s];
    __syncthreads();
  }
  if (tid == 0) {
    float v = red[0] * (1.f / 3.f);
    if (n < 40) out40[n] = v; else scb[n - 40] = v;
  }
}

// collect + concat + softmax -> out[80 + b*40 + i]
__global__ void final_kernel(const float* __restrict__ score_post,
                             const float* __restrict__ sc_buf,
                             const int* __restrict__ label,
                             float* __restrict__ out) {
  __shared__ float z[2 * kC];
  __shared__ float collect[kC];
  const int b = blockIdx.x;
  const int tid = threadIdx.x;
  if (tid < kC) {
    int a = tid;
    float s = 0.f, ngt = 0.f;
    for (int c = 0; c < kC; ++c) {
      float m = label[b * kC + c] > 0 ? 1.f : 0.f;
      ngt += m;
      s += m * sc_buf[b * 400 + c * kC + a];
    }
    if (ngt < 1.f) ngt = 1.f;
    float col = s / ngt;
    if (label[b * kC + a] > 0) col = sc_buf[b * 400 + a * kC + a];
    collect[a] = col;
  }
  __syncthreads();
  if (tid < 2 * kC) z[tid] = (tid < kC) ? score_post[b * kC + tid] : collect[tid - kC];
  __syncthreads();
  if (tid == 0) {
    float mx = z[0];
    for (int i = 1; i < 2 * kC; ++i) mx = fmaxf(mx, z[i]);
    float s = 0.f;
    for (int i = 0; i < 2 * kC; ++i) { z[i] = expf(z[i] - mx); s += z[i]; }
    for (int i = 0; i < 2 * kC; ++i) out[80 + b * 2 * kC + i] = z[i] / s;
  }
}

extern "C" void kernel_launch(void* const* d_in, const int* in_sizes, int n_in,
                              void* d_out, int out_size, void* d_ws, size_t ws_size,
                              hipStream_t stream) {
  (void)in_sizes; (void)n_in; (void)out_size;
  const float* x    = (const float*)d_in[0];
  const float* w1   = (const float*)d_in[1];
  const float* b1   = (const float*)d_in[2];
  const float* w2   = (const float*)d_in[3];
  const float* b2   = (const float*)d_in[4];
  const float* wc   = (const float*)d_in[5];
  const float* watt = (const float*)d_in[6];
  const float* batt = (const float*)d_in[7];
  const int*   lbl  = (const int*)d_in[8];
  float* out = (float*)d_out;
  char*  wsb = (char*)d_ws;

  // workspace layout (bytes)
  ushort* Wt1   = (ushort*)(wsb + 0);           // 25,165,824  [3][2048][2048]
  ushort* Wt2   = (ushort*)(wsb + 25165824);    // 25,165,824
  ushort* wcb   = (ushort*)(wsb + 50331648);    // 81,920
  ushort* zpage = (ushort*)(wsb + 50413568);    // 4,096
  ushort* xTt   = (ushort*)(wsb + 50417664);    // 6,144,000
  ushort* xJ    = (ushort*)(wsb + 56561664);    // 6,291,456  [6][2048][256]
  ushort* W2b   = (ushort*)(wsb + 62853120);    // 1,572,864  [6][512][256]
  ushort* Ybuf  = (ushort*)(wsb + 64425984);    // 10,321,920 (Y1 / FeatY / Yp)
  ushort* h2    = (ushort*)(wsb + 74747904);    // 6,144,000
  ushort* hP2   = (ushort*)(wsb + 80891904);    // 10,321,920
  float*  seq   = (float*)(wsb + 91213824);     // 120,000
  float*  wab   = (float*)(wsb + 91333824);     // 120,000
  float*  scb   = (float*)(wsb + 91453824);     // 3,200
  const size_t ppart_off = 91457536;            // 16B aligned
  float*  Ppart = (float*)(wsb + ppart_off);

  // dynamic split-K: prefer S_main=8 (100.7 MB partials), S_post=4 (83.9 MB)
  const size_t avail = (ws_size > ppart_off) ? ws_size - ppart_off : 0;
  const int S_main = (avail >= (size_t)8 * 1536 * 2048 * 4) ? 8 : 4;
  const int S_post = (avail >= (size_t)4 * 2560 * 2048 * 4) ? 4 : 2;

  dim3 blk(256);
  convert_w_kernel<<<dim3(2048, 2), blk, 0, stream>>>(w1, w2, Wt1, Wt2, zpage);
  convert_kernel<<<dim3(40), blk, 0, stream>>>(wc, wcb, kC * kF);
  transpose_kernel<<<dim3(12, 32, 2), blk, 0, stream>>>(x, xTt);
  xj_kernel<<<dim3(4096), blk, 0, stream>>>(x, xJ);
  // main conv1
  gemm_conv_kernel<750><<<dim3(12, 16, S_main), blk, 0, stream>>>(
      Wt1, xTt, zpage, Ppart, 1500, 1536, 96 / S_main);
  reduce_kernel<<<dim3(1500, 2), blk, 0, stream>>>(Ppart, b1, Ybuf, 1536, S_main);
  // main conv2
  gemm_conv_kernel<750><<<dim3(12, 16, S_main), blk, 0, stream>>>(
      Wt2, Ybuf, zpage, Ppart, 1500, 1536, 96 / S_main);
  reduce_kernel<<<dim3(1500, 2), blk, 0, stream>>>(Ppart, b2, h2, 1536, S_main);
  // attention path (wa fused into seqcas)
  seqcas_kernel<<<dim3(375), blk, 0, stream>>>(h2, wcb, watt, batt, seq, wab);
  score_pre_kernel<<<dim3(40), dim3(64), 0, stream>>>(seq, out);  // out[0..39]
  // fg + bg aggregation as MFMA GEMM -> FeatY (Ybuf)
  ww_build_kernel<<<dim3(6, 16), blk, 0, stream>>>(wab, W2b);
  ww_gemm_kernel<<<dim3(4, 16, 6), blk, 0, stream>>>(xJ, W2b, Ybuf);
  // post conv1
  gemm_conv_kernel<3><<<dim3(20, 16, S_post), blk, 0, stream>>>(
      Wt1, Ybuf, zpage, Ppart, 2520, 2560, 96 / S_post);
  reduce_kernel<<<dim3(2520, 2), blk, 0, stream>>>(Ppart, b1, Ybuf, 2560, S_post);
  // post conv2
  gemm_conv_kernel<3><<<dim3(20, 16, S_post), blk, 0, stream>>>(
      Wt2, Ybuf, zpage, Ppart, 2520, 2560, S_post == 4 ? 24 : 48);
  reduce_kernel<<<dim3(2520, 2), blk, 0, stream>>>(Ppart, b2, hP2, 2560, S_post);
  // classifiers + final
  cls_kernel<<<dim3(840), blk, 0, stream>>>(hP2, wc, out + 40, scb);
  final_kernel<<<dim3(2), dim3(64), 0, stream>>>(out + 40, scb, lbl, out);
}

// Round 7
// 441.745 us; speedup vs baseline: 19.1463x; 1.1754x over previous
//
#include <hip/hip_runtime.h>
#include <math.h>

// ECMNet on gfx950 — 256x256 8-wave counted-vmcnt MFMA conv-GEMM (T2+T3+T4+T5),
// split-K; feat/agg folded into MFMA GEMM.
// B=2, F=2048, T=750, C=20, G=3, Tg=250, topK=93
namespace {
constexpr int kF = 2048;
constexpr int kT = 750;
constexpr int kC = 20;
constexpr int kTop = 93;
}

typedef __bf16 bf16x8 __attribute__((ext_vector_type(8)));
typedef float f32x4 __attribute__((ext_vector_type(4)));

__device__ __forceinline__ ushort f2bf(float f) {
  uint u = __builtin_bit_cast(uint, f);
  uint r = u + 0x7FFFu + ((u >> 16) & 1u);
  return (ushort)(r >> 16);
}
__device__ __forceinline__ float bf2f(ushort u) {
  return __builtin_bit_cast(float, ((uint)u) << 16);
}
__device__ __forceinline__ float leaky(float v) { return v > 0.f ? v : 0.01f * v; }

__device__ __forceinline__ void gload_lds16(const ushort* g, ushort* l) {
  __builtin_amdgcn_global_load_lds(
      (const __attribute__((address_space(1))) void*)g,
      (__attribute__((address_space(3))) void*)l, 16, 0, 0);
}

// ---------------------------------------------------------------------------
// weights [co][ci][3] fp32 -> Wt [tap][co][ci] bf16 (both w1,w2); zero page
// ---------------------------------------------------------------------------
__global__ __launch_bounds__(256) void convert_w_kernel(
    const float* __restrict__ w1, const float* __restrict__ w2,
    ushort* __restrict__ Wt1, ushort* __restrict__ Wt2,
    ushort* __restrict__ zpage) {
  const int co = blockIdx.x;
  const float* w = (blockIdx.y == 0) ? w1 : w2;
  ushort* Wt = (blockIdx.y == 0) ? Wt1 : Wt2;
  const int ci0 = threadIdx.x * 8;
  float v[24];
  const float4* p = (const float4*)(w + (size_t)co * 6144 + ci0 * 3);
#pragma unroll
  for (int s = 0; s < 6; ++s) {
    float4 f = p[s];
    v[s * 4 + 0] = f.x; v[s * 4 + 1] = f.y; v[s * 4 + 2] = f.z; v[s * 4 + 3] = f.w;
  }
#pragma unroll
  for (int tap = 0; tap < 3; ++tap) {
    ushort o[8];
#pragma unroll
    for (int j = 0; j < 8; ++j) o[j] = f2bf(v[j * 3 + tap]);
    ushort4 a = {o[0], o[1], o[2], o[3]}, b = {o[4], o[5], o[6], o[7]};
    ushort4* q = (ushort4*)(Wt + (size_t)tap * kF * kF + (size_t)co * kF + ci0);
    q[0] = a; q[1] = b;
  }
  if (blockIdx.x == 0 && blockIdx.y == 0) {
    ((float4*)zpage)[threadIdx.x] = (float4){0.f, 0.f, 0.f, 0.f};  // 4 KB zeros
  }
}

// fp32 -> bf16 plain (for wc)
__global__ __launch_bounds__(256) void convert_kernel(
    const float* __restrict__ src, ushort* __restrict__ dst, int n) {
  int i = (blockIdx.x * 256 + threadIdx.x) * 4;
  if (i + 3 < n) {
    float4 f = *(const float4*)(src + i);
    ushort4 o;
    o.x = f2bf(f.x); o.y = f2bf(f.y); o.z = f2bf(f.z); o.w = f2bf(f.w);
    *(ushort4*)(dst + i) = o;
  } else {
    for (; i < n; ++i) dst[i] = f2bf(src[i]);
  }
}

// ---------------------------------------------------------------------------
// x [2][2048][750] fp32 -> xTt [(b*750+t)][2048] bf16
// ---------------------------------------------------------------------------
__global__ __launch_bounds__(256) void transpose_kernel(
    const float* __restrict__ x, ushort* __restrict__ xTt) {
  __shared__ float tile[64][65];
  const int b = blockIdx.z;
  const int t0 = blockIdx.x * 64, f0 = blockIdx.y * 64;
  const int tx = threadIdx.x & 63, ty4 = threadIdx.x >> 6;
#pragma unroll
  for (int i = 0; i < 16; ++i) {
    int lf = ty4 + i * 4;
    int t = t0 + tx;
    tile[lf][tx] = (t < kT) ? x[((size_t)b * kF + f0 + lf) * kT + t] : 0.f;
  }
  __syncthreads();
#pragma unroll
  for (int i = 0; i < 16; ++i) {
    int lt = ty4 + i * 4;
    int t = t0 + lt;
    if (t < kT)
      xTt[(size_t)(b * kT + t) * kF + f0 + tx] = f2bf(tile[tx][lt]);
  }
}

// ---------------------------------------------------------------------------
// xJ[((b*3+g)*2048+f)][j] = x[b][f][j*3+g] bf16, j in [0,256), pad 0
// ---------------------------------------------------------------------------
__global__ __launch_bounds__(256) void xj_kernel(
    const float* __restrict__ x, ushort* __restrict__ xJ) {
  const int bid = blockIdx.x;           // 0..4095
  const int b = bid >> 11, f = bid & 2047;
  __shared__ float buf[768];
  const float* xr = x + ((size_t)b * kF + f) * kT;
  for (int t = threadIdx.x; t < kT; t += 256) buf[t] = xr[t];
  __syncthreads();
  const int j = threadIdx.x;
#pragma unroll
  for (int g = 0; g < 3; ++g) {
    float v = (j < 250) ? buf[j * 3 + g] : 0.f;
    xJ[(((size_t)(b * 3 + g) * kF + f) << 8) + j] = f2bf(v);
  }
}

// ---------------------------------------------------------------------------
// W2[bg][r][j] bf16: r<20 fg rows wa[c=r]; 20<=r<420 bg rows wa[a]*(1-wa[c])
// ---------------------------------------------------------------------------
__global__ __launch_bounds__(256) void ww_build_kernel(
    const float* __restrict__ wab, ushort* __restrict__ W2) {
  const int bg = blockIdx.x;
  const int b = bg / 3, g = bg % 3;
  const int r0 = blockIdx.y * 32;
  __shared__ float ws[kC][256];
  for (int i = threadIdx.x; i < kC * 250; i += 256) {
    int c = i / 250, j = i % 250;
    ws[c][j] = wab[(size_t)(b * kC + c) * kT + j * 3 + g];
  }
  __syncthreads();
  ushort* Wb = W2 + (size_t)bg * 512 * 256;
  const int j = threadIdx.x;
#pragma unroll 4
  for (int rr = 0; rr < 32; ++rr) {
    int r = r0 + rr;
    float v = 0.f;
    if (j < 250 && r < 420) {
      if (r < kC) {
        v = ws[r][j];
      } else {
        int idx = r - kC;
        int c = idx / kC, a = idx % kC;
        v = ws[a][j] * (1.f - ws[c][j]);
      }
    }
    Wb[(size_t)r * 256 + j] = f2bf(v);
  }
}

// ---------------------------------------------------------------------------
// ww GEMM (128x128, 2-phase; small, unchanged from R6)
// ---------------------------------------------------------------------------
__global__ __launch_bounds__(256) void ww_gemm_kernel(
    const ushort* __restrict__ xJ, const ushort* __restrict__ W2,
    ushort* __restrict__ FeatY) {
  __shared__ ushort sA[2][128 * 64];
  __shared__ ushort sB[2][128 * 64];
  const int tid = threadIdx.x;
  const int w = tid >> 6, lane = tid & 63;
  const int wm = w >> 1, wn = w & 1;
  const int bg = blockIdx.z;
  const int f0 = blockIdx.y * 128;
  const int s0 = blockIdx.x * 128;
  const ushort* A = xJ + ((size_t)bg * kF << 8);
  const ushort* Bp = W2 + (size_t)bg * 512 * 256;
  const int srow = lane >> 3;
  const int selem = ((lane & 7) ^ srow) * 8;
  f32x4 acc[4][4];
#pragma unroll
  for (int i = 0; i < 4; ++i)
#pragma unroll
    for (int j = 0; j < 4; ++j) acc[i][j] = (f32x4){0.f, 0.f, 0.f, 0.f};

  auto STAGE = [&](int buf, int kt) {
    const int kin = kt * 64;
#pragma unroll
    for (int i = 0; i < 4; ++i) {
      int r = (w * 4 + i) * 8 + srow;
      gload_lds16(A + (size_t)(f0 + r) * 256 + kin + selem,
                  &sA[buf][(w * 4 + i) * 512]);
    }
#pragma unroll
    for (int i = 0; i < 4; ++i) {
      int r = (w * 4 + i) * 8 + srow;
      gload_lds16(Bp + (size_t)(s0 + r) * 256 + kin + selem,
                  &sB[buf][(w * 4 + i) * 512]);
    }
  };

  STAGE(0, 0);
  asm volatile("s_waitcnt vmcnt(0)" ::: "memory");
  __builtin_amdgcn_s_barrier();

  int cur = 0;
  for (int kt = 0; kt < 4; ++kt) {
    if (kt + 1 < 4) STAGE(cur ^ 1, kt + 1);
#pragma unroll
    for (int ksub = 0; ksub < 2; ++ksub) {
      bf16x8 af[4], bfv[4];
      const int rlow = lane & 7;
#pragma unroll
      for (int fm = 0; fm < 4; ++fm) {
        int row = wm * 64 + fm * 16 + (lane & 15);
        int c16 = (ksub * 4 + (lane >> 4)) ^ rlow;
        af[fm] = *(const bf16x8*)&sA[cur][row * 64 + c16 * 8];
      }
#pragma unroll
      for (int fn = 0; fn < 4; ++fn) {
        int row = wn * 64 + fn * 16 + (lane & 15);
        int c16 = (ksub * 4 + (lane >> 4)) ^ rlow;
        bfv[fn] = *(const bf16x8*)&sB[cur][row * 64 + c16 * 8];
      }
#pragma unroll
      for (int fm = 0; fm < 4; ++fm)
#pragma unroll
        for (int fn = 0; fn < 4; ++fn)
          acc[fm][fn] = __builtin_amdgcn_mfma_f32_16x16x32_bf16(
              af[fm], bfv[fn], acc[fm][fn], 0, 0, 0);
    }
    asm volatile("s_waitcnt vmcnt(0)" ::: "memory");
    __builtin_amdgcn_s_barrier();
    cur ^= 1;
  }

  const int b = bg / 3, g = bg % 3;
#pragma unroll
  for (int fm = 0; fm < 4; ++fm) {
#pragma unroll
    for (int fn = 0; fn < 4; ++fn) {
      int s = s0 + wn * 64 + fn * 16 + (lane & 15);
      if (s >= 420) continue;
      int sampleg = (s < kC) ? (b * kC + s) : (40 + b * 400 + (s - kC));
      int row = f0 + wm * 64 + fm * 16 + ((lane >> 4) << 2);
      ushort4 o;
      o.x = f2bf(acc[fm][fn][0]);
      o.y = f2bf(acc[fm][fn][1]);
      o.z = f2bf(acc[fm][fn][2]);
      o.w = f2bf(acc[fm][fn][3]);
      *(ushort4*)&FeatY[(size_t)(sampleg * 3 + g) * kF + row] = o;
    }
  }
}

// ---------------------------------------------------------------------------
// Direct-conv GEMM, split-K, 256x256 tile, 8 waves (2Mx4N), BK=64.
// Counted-vmcnt 2-deep prefetch: COMPUTE(cur) -> barrier -> STAGE(cur,t+2)
// -> vmcnt(8) [t+1 drained, t+2 in flight] -> barrier -> swap.
// LDS 128 KB dynamic (2 dbuf x (A 32K + B 32K)), XOR-swizzled both sides.
// ---------------------------------------------------------------------------
template <int L>
__global__ __launch_bounds__(512, 1) void gemm_conv_kernel(
    const ushort* __restrict__ A, const ushort* __restrict__ B,
    const ushort* __restrict__ zpage, float* __restrict__ Cpart,
    int ncols, int NP, int ktn_base, int ktrem) {
  extern __shared__ ushort lds[];
  ushort* sAl = lds;            // [2][256*64]
  ushort* sBl = lds + 32768;    // [2][256*64]
  const int tid = threadIdx.x;
  const int wid = tid >> 6, lane = tid & 63;
  const int wr = wid >> 2, wc = wid & 3;          // wave -> (M half, N quarter)
  const int co0 = blockIdx.y * 256;
  const int col0 = blockIdx.x * 256;
  const int z = blockIdx.z;
  const int kt0 = z * ktn_base + (z < ktrem ? z : ktrem);
  const int ktn = ktn_base + (z < ktrem ? 1 : 0);
  const int srow = lane >> 3;                     // 0..7
  const int selem = ((lane & 7) ^ srow) * 8;      // swizzled k-chunk (involution)
  f32x4 acc[8][4];
#pragma unroll
  for (int i = 0; i < 8; ++i)
#pragma unroll
    for (int j = 0; j < 4; ++j) acc[i][j] = (f32x4){0.f, 0.f, 0.f, 0.f};

  auto STAGE = [&](int buf, int kt) {
    const int tap = kt >> 5;          // 32 K-steps per tap (2048/64)
    const int kin = (kt & 31) * 64;
    const size_t aoff = (size_t)tap * kF * kF + kin + selem;
#pragma unroll
    for (int i = 0; i < 4; ++i) {
      int rb = i * 64 + wid * 8;                  // wave's 8-row group
      gload_lds16(A + aoff + (size_t)(co0 + rb + srow) * kF,
                  &sAl[buf * 16384 + rb * 64]);
    }
#pragma unroll
    for (int i = 0; i < 4; ++i) {
      int rb = i * 64 + wid * 8;
      int col = col0 + rb + srow;
      int t = col - (col / L) * L;
      int tt = t + tap - 1;
      const ushort* src = (col < ncols && tt >= 0 && tt < L)
          ? B + (size_t)(col + tap - 1) * kF + kin + selem
          : zpage + selem;
      gload_lds16(src, &sBl[buf * 16384 + rb * 64]);
    }
  };

  auto COMPUTE = [&](int buf) {
    const int rlow = lane & 7;
    const ushort* sAb = &sAl[buf * 16384];
    const ushort* sBb = &sBl[buf * 16384];
#pragma unroll
    for (int ksub = 0; ksub < 2; ++ksub) {
      const int c16 = (ksub * 4 + (lane >> 4)) ^ rlow;
      bf16x8 bfv[4], af[8];
#pragma unroll
      for (int fn = 0; fn < 4; ++fn) {
        int row = wc * 64 + fn * 16 + (lane & 15);
        bfv[fn] = *(const bf16x8*)&sBb[row * 64 + c16 * 8];
      }
#pragma unroll
      for (int fm = 0; fm < 8; ++fm) {
        int row = wr * 128 + fm * 16 + (lane & 15);
        af[fm] = *(const bf16x8*)&sAb[row * 64 + c16 * 8];
      }
      __builtin_amdgcn_s_setprio(1);
#pragma unroll
      for (int fm = 0; fm < 8; ++fm)
#pragma unroll
        for (int fn = 0; fn < 4; ++fn)
          acc[fm][fn] = __builtin_amdgcn_mfma_f32_16x16x32_bf16(
              af[fm], bfv[fn], acc[fm][fn], 0, 0, 0);
      __builtin_amdgcn_s_setprio(0);
    }
  };

  // prologue: stage tiles t0, t0+1 (ktn >= 16 always)
  STAGE(0, kt0);
  STAGE(1, kt0 + 1);
  asm volatile("s_waitcnt vmcnt(8)" ::: "memory");  // t0 landed; t0+1 flying
  __builtin_amdgcn_s_barrier();
  __builtin_amdgcn_sched_barrier(0);

  int cur = 0;
  for (int kt = kt0; kt < kt0 + ktn; ++kt) {
    COMPUTE(cur);
    __builtin_amdgcn_s_barrier();                 // all waves done with buf[cur]
    __builtin_amdgcn_sched_barrier(0);
    if (kt + 2 < kt0 + ktn) {
      STAGE(cur, kt + 2);                         // refill freed buffer
      asm volatile("s_waitcnt vmcnt(8)" ::: "memory");  // drain t+1 only
    } else {
      asm volatile("s_waitcnt vmcnt(0)" ::: "memory");
    }
    __builtin_amdgcn_s_barrier();
    __builtin_amdgcn_sched_barrier(0);
    cur ^= 1;
  }

  float* Cz = Cpart + (size_t)z * NP * kF;
#pragma unroll
  for (int fm = 0; fm < 8; ++fm) {
#pragma unroll
    for (int fn = 0; fn < 4; ++fn) {
      int col = col0 + wc * 64 + fn * 16 + (lane & 15);
      int row = co0 + wr * 128 + fm * 16 + ((lane >> 4) << 2);
      *(f32x4*)&Cz[(size_t)col * kF + row] = acc[fm][fn];
    }
  }
}

// ---------------------------------------------------------------------------
// reduce partials over S + bias + leaky -> bf16 [col][2048]
// ---------------------------------------------------------------------------
__global__ __launch_bounds__(256) void reduce_kernel(
    const float* __restrict__ Cpart, const float* __restrict__ bias,
    ushort* __restrict__ Y, int NP, int S) {
  const int col = blockIdx.x;
  const int row0 = (blockIdx.y * 256 + threadIdx.x) * 4;
  f32x4 a = *(const f32x4*)&Cpart[(size_t)col * kF + row0];
  for (int s = 1; s < S; ++s)
    a += *(const f32x4*)&Cpart[((size_t)s * NP + col) * kF + row0];
  f32x4 bv = *(const f32x4*)&bias[row0];
  ushort4 o;
  o.x = f2bf(leaky(a[0] + bv[0]));
  o.y = f2bf(leaky(a[1] + bv[1]));
  o.z = f2bf(leaky(a[2] + bv[2]));
  o.w = f2bf(leaky(a[3] + bv[3]));
  *(ushort4*)&Y[(size_t)col * kF + row0] = o;
}

// ---------------------------------------------------------------------------
// seq[b][c][t] = sum_ci wcb[c][ci] * h2[(b*750+t)][ci]; fused wa = sigmoid(...)
// ---------------------------------------------------------------------------
__global__ __launch_bounds__(256) void seqcas_kernel(
    const ushort* __restrict__ h2, const ushort* __restrict__ wcb,
    const float* __restrict__ watt, const float* __restrict__ batt,
    float* __restrict__ seq, float* __restrict__ wa) {
  const int w = threadIdx.x >> 6, lane = threadIdx.x & 63;
  const int idx = blockIdx.x * 4 + w;
  if (idx >= 2 * kT) return;
  const ushort* hr = h2 + (size_t)idx * kF;
  float acc[kC];
#pragma unroll
  for (int c = 0; c < kC; ++c) acc[c] = 0.f;
#pragma unroll
  for (int ch = 0; ch < 4; ++ch) {
    const int ci0 = ch * 512 + lane * 8;
    ushort4 ha = *(const ushort4*)(hr + ci0);
    ushort4 hb = *(const ushort4*)(hr + ci0 + 4);
    float hx[8] = {bf2f(ha.x), bf2f(ha.y), bf2f(ha.z), bf2f(ha.w),
                   bf2f(hb.x), bf2f(hb.y), bf2f(hb.z), bf2f(hb.w)};
#pragma unroll
    for (int c = 0; c < kC; ++c) {
      const ushort* wr = wcb + c * kF + ci0;
      ushort4 wa4 = *(const ushort4*)wr;
      ushort4 wb4 = *(const ushort4*)(wr + 4);
      acc[c] += bf2f(wa4.x) * hx[0] + bf2f(wa4.y) * hx[1] +
                bf2f(wa4.z) * hx[2] + bf2f(wa4.w) * hx[3] +
                bf2f(wb4.x) * hx[4] + bf2f(wb4.y) * hx[5] +
                bf2f(wb4.z) * hx[6] + bf2f(wb4.w) * hx[7];
    }
  }
#pragma unroll
  for (int off = 32; off; off >>= 1)
#pragma unroll
    for (int c = 0; c < kC; ++c) acc[c] += __shfl_xor(acc[c], off);
  if (lane == 0) {
    int b = idx / kT, t = idx % kT;
#pragma unroll
    for (int c = 0; c < kC; ++c) seq[(size_t)(b * kC + c) * kT + t] = acc[c];
#pragma unroll
    for (int c = 0; c < kC; ++c) {
      float z = batt[c];
#pragma unroll
      for (int a = 0; a < kC; ++a) z += watt[c * kC + a] * acc[a];
      wa[(size_t)(b * kC + c) * kT + t] = 1.f / (1.f + expf(-z));
    }
  }
}

// top-93 mean over T per (b,c) row — one wave per row, barrier-free
__global__ __launch_bounds__(64) void score_pre_kernel(
    const float* __restrict__ seq, float* __restrict__ out) {
  const int n = blockIdx.x;
  const int lane = threadIdx.x;
  float v[12];
#pragma unroll
  for (int i = 0; i < 12; ++i) {
    int idx = lane + i * 64;
    v[i] = (idx < kT) ? seq[(size_t)n * kT + idx] : -1e30f;
  }
  float sum = 0.f;
  for (int it = 0; it < kTop; ++it) {
    float lm = v[0];
#pragma unroll
    for (int i = 1; i < 12; ++i) lm = fmaxf(lm, v[i]);
    float wm = lm;
#pragma unroll
    for (int off = 32; off; off >>= 1) wm = fmaxf(wm, __shfl_xor(wm, off));
    sum += wm;
    unsigned long long ball = __ballot(lm == wm);
    int first = __ffsll(ball) - 1;
    bool own = (lane == first);
    bool done = false;
#pragma unroll
    for (int i = 0; i < 12; ++i) {
      bool hit = own && !done && (v[i] == wm);
      if (hit) { v[i] = -1e30f; done = true; }
    }
  }
  if (lane == 0) out[n] = sum / (float)kTop;
}

// score[n] = (1/3) sum_g sum_co h[(n*3+g)][co] * wc[class(n)][co]
__global__ __launch_bounds__(256) void cls_kernel(
    const ushort* __restrict__ h, const float* __restrict__ wc,
    float* __restrict__ out40, float* __restrict__ scb) {
  __shared__ float red[256];
  const int n = blockIdx.x;
  const int tid = threadIdx.x;
  const int cls = (n < 40) ? (n % kC) : ((n - 40) % kC);
  const int co0 = tid * 8;
  const float4 w0 = *(const float4*)(wc + (size_t)cls * kF + co0);
  const float4 w1 = *(const float4*)(wc + (size_t)cls * kF + co0 + 4);
  float acc = 0.f;
#pragma unroll
  for (int g = 0; g < 3; ++g) {
    const ushort* hr = h + (size_t)(n * 3 + g) * kF + co0;
    ushort4 a = *(const ushort4*)hr;
    ushort4 b4 = *(const ushort4*)(hr + 4);
    acc += bf2f(a.x) * w0.x + bf2f(a.y) * w0.y + bf2f(a.z) * w0.z + bf2f(a.w) * w0.w +
           bf2f(b4.x) * w1.x + bf2f(b4.y) * w1.y + bf2f(b4.z) * w1.z + bf2f(b4.w) * w1.w;
  }
  red[tid] = acc;
  __syncthreads();
  for (int s = 128; s > 0; s >>= 1) {
    if (tid < s) red[tid] += red[tid + s];
    __syncthreads();
  }
  if (tid == 0) {
    float v = red[0] * (1.f / 3.f);
    if (n < 40) out40[n] = v; else scb[n - 40] = v;
  }
}

// collect + concat + softmax -> out[80 + b*40 + i]
__global__ void final_kernel(const float* __restrict__ score_post,
                             const float* __restrict__ sc_buf,
                             const int* __restrict__ label,
                             float* __restrict__ out) {
  __shared__ float z[2 * kC];
  __shared__ float collect[kC];
  const int b = blockIdx.x;
  const int tid = threadIdx.x;
  if (tid < kC) {
    int a = tid;
    float s = 0.f, ngt = 0.f;
    for (int c = 0; c < kC; ++c) {
      float m = label[b * kC + c] > 0 ? 1.f : 0.f;
      ngt += m;
      s += m * sc_buf[b * 400 + c * kC + a];
    }
    if (ngt < 1.f) ngt = 1.f;
    float col = s / ngt;
    if (label[b * kC + a] > 0) col = sc_buf[b * 400 + a * kC + a];
    collect[a] = col;
  }
  __syncthreads();
  if (tid < 2 * kC) z[tid] = (tid < kC) ? score_post[b * kC + tid] : collect[tid - kC];
  __syncthreads();
  if (tid == 0) {
    float mx = z[0];
    for (int i = 1; i < 2 * kC; ++i) mx = fmaxf(mx, z[i]);
    float s = 0.f;
    for (int i = 0; i < 2 * kC; ++i) { z[i] = expf(z[i] - mx); s += z[i]; }
    for (int i = 0; i < 2 * kC; ++i) out[80 + b * 2 * kC + i] = z[i] / s;
  }
}

extern "C" void kernel_launch(void* const* d_in, const int* in_sizes, int n_in,
                              void* d_out, int out_size, void* d_ws, size_t ws_size,
                              hipStream_t stream) {
  (void)in_sizes; (void)n_in; (void)out_size; (void)ws_size;
  const float* x    = (const float*)d_in[0];
  const float* w1   = (const float*)d_in[1];
  const float* b1   = (const float*)d_in[2];
  const float* w2   = (const float*)d_in[3];
  const float* b2   = (const float*)d_in[4];
  const float* wc   = (const float*)d_in[5];
  const float* watt = (const float*)d_in[6];
  const float* batt = (const float*)d_in[7];
  const int*   lbl  = (const int*)d_in[8];
  float* out = (float*)d_out;
  char*  wsb = (char*)d_ws;

  // enable 128 KB dynamic LDS for the big GEMM (deterministic, capture-safe)
  hipFuncSetAttribute(reinterpret_cast<const void*>(&gemm_conv_kernel<750>),
                      hipFuncAttributeMaxDynamicSharedMemorySize, 131072);
  hipFuncSetAttribute(reinterpret_cast<const void*>(&gemm_conv_kernel<3>),
                      hipFuncAttributeMaxDynamicSharedMemorySize, 131072);

  // workspace layout (bytes)
  ushort* Wt1   = (ushort*)(wsb + 0);           // 25,165,824  [3][2048][2048]
  ushort* Wt2   = (ushort*)(wsb + 25165824);    // 25,165,824
  ushort* wcb   = (ushort*)(wsb + 50331648);    // 81,920
  ushort* zpage = (ushort*)(wsb + 50413568);    // 4,096
  ushort* xTt   = (ushort*)(wsb + 50417664);    // 6,144,000
  ushort* xJ    = (ushort*)(wsb + 56561664);    // 6,291,456  [6][2048][256]
  ushort* W2b   = (ushort*)(wsb + 62853120);    // 1,572,864  [6][512][256]
  ushort* Ybuf  = (ushort*)(wsb + 64425984);    // 10,321,920 (Y1 / FeatY / Yp)
  ushort* h2    = (ushort*)(wsb + 74747904);    // 6,144,000
  ushort* hP2   = (ushort*)(wsb + 80891904);    // 10,321,920
  float*  seq   = (float*)(wsb + 91213824);     // 120,000
  float*  wab   = (float*)(wsb + 91333824);     // 120,000
  float*  scb   = (float*)(wsb + 91453824);     // 3,200
  float*  Ppart = (float*)(wsb + 91457536);     // <= 62.9 MB -> peak ~154.4 MB

  const int S_main = 5;  // 6x8x5 = 240 blocks, ktn 20/19 (96 = 5*19+1)
  const int S_post = 3;  // 10x8x3 = 240 blocks, ktn 32

  dim3 blk(256);
  convert_w_kernel<<<dim3(2048, 2), blk, 0, stream>>>(w1, w2, Wt1, Wt2, zpage);
  convert_kernel<<<dim3(40), blk, 0, stream>>>(wc, wcb, kC * kF);
  transpose_kernel<<<dim3(12, 32, 2), blk, 0, stream>>>(x, xTt);
  xj_kernel<<<dim3(4096), blk, 0, stream>>>(x, xJ);
  // main conv1
  gemm_conv_kernel<750><<<dim3(6, 8, S_main), dim3(512), 131072, stream>>>(
      Wt1, xTt, zpage, Ppart, 1500, 1536, 19, 1);
  reduce_kernel<<<dim3(1500, 2), blk, 0, stream>>>(Ppart, b1, Ybuf, 1536, S_main);
  // main conv2
  gemm_conv_kernel<750><<<dim3(6, 8, S_main), dim3(512), 131072, stream>>>(
      Wt2, Ybuf, zpage, Ppart, 1500, 1536, 19, 1);
  reduce_kernel<<<dim3(1500, 2), blk, 0, stream>>>(Ppart, b2, h2, 1536, S_main);
  // attention path (wa fused into seqcas)
  seqcas_kernel<<<dim3(375), blk, 0, stream>>>(h2, wcb, watt, batt, seq, wab);
  score_pre_kernel<<<dim3(40), dim3(64), 0, stream>>>(seq, out);  // out[0..39]
  // fg + bg aggregation as MFMA GEMM -> FeatY (Ybuf)
  ww_build_kernel<<<dim3(6, 16), blk, 0, stream>>>(wab, W2b);
  ww_gemm_kernel<<<dim3(4, 16, 6), blk, 0, stream>>>(xJ, W2b, Ybuf);
  // post conv1
  gemm_conv_kernel<3><<<dim3(10, 8, S_post), dim3(512), 131072, stream>>>(
      Wt1, Ybuf, zpage, Ppart, 2520, 2560, 32, 0);
  reduce_kernel<<<dim3(2520, 2), blk, 0, stream>>>(Ppart, b1, Ybuf, 2560, S_post);
  // post conv2
  gemm_conv_kernel<3><<<dim3(10, 8, S_post), dim3(512), 131072, stream>>>(
      Wt2, Ybuf, zpage, Ppart, 2520, 2560, 32, 0);
  reduce_kernel<<<dim3(2520, 2), blk, 0, stream>>>(Ppart, b2, hP2, 2560, S_post);
  // classifiers + final
  cls_kernel<<<dim3(840), blk, 0, stream>>>(hP2, wc, out + 40, scb);
  final_kernel<<<dim3(2), dim3(64), 0, stream>>>(out + 40, scb, lbl, out);
}

// Round 8
// 428.247 us; speedup vs baseline: 19.7498x; 1.0315x over previous
//
#include <hip/hip_runtime.h>
#include <math.h>

// ECMNet on gfx950 — 256x256 8-wave conv-GEMM, BK=32, 4-slot LDS ring,
// 3-deep counted-vmcnt prefetch, fine phase interleave (T2+T3+T4+T5).
// B=2, F=2048, T=750, C=20, G=3, Tg=250, topK=93
namespace {
constexpr int kF = 2048;
constexpr int kT = 750;
constexpr int kC = 20;
constexpr int kTop = 93;
}

typedef __bf16 bf16x8 __attribute__((ext_vector_type(8)));
typedef float f32x4 __attribute__((ext_vector_type(4)));

__device__ __forceinline__ ushort f2bf(float f) {
  uint u = __builtin_bit_cast(uint, f);
  uint r = u + 0x7FFFu + ((u >> 16) & 1u);
  return (ushort)(r >> 16);
}
__device__ __forceinline__ float bf2f(ushort u) {
  return __builtin_bit_cast(float, ((uint)u) << 16);
}
__device__ __forceinline__ float leaky(float v) { return v > 0.f ? v : 0.01f * v; }

__device__ __forceinline__ void gload_lds16(const ushort* g, ushort* l) {
  __builtin_amdgcn_global_load_lds(
      (const __attribute__((address_space(1))) void*)g,
      (__attribute__((address_space(3))) void*)l, 16, 0, 0);
}

// ---------------------------------------------------------------------------
// weights [co][ci][3] fp32 -> Wt [tap][co][ci] bf16 (both w1,w2); zero page
// ---------------------------------------------------------------------------
__global__ __launch_bounds__(256) void convert_w_kernel(
    const float* __restrict__ w1, const float* __restrict__ w2,
    ushort* __restrict__ Wt1, ushort* __restrict__ Wt2,
    ushort* __restrict__ zpage) {
  const int co = blockIdx.x;
  const float* w = (blockIdx.y == 0) ? w1 : w2;
  ushort* Wt = (blockIdx.y == 0) ? Wt1 : Wt2;
  const int ci0 = threadIdx.x * 8;
  float v[24];
  const float4* p = (const float4*)(w + (size_t)co * 6144 + ci0 * 3);
#pragma unroll
  for (int s = 0; s < 6; ++s) {
    float4 f = p[s];
    v[s * 4 + 0] = f.x; v[s * 4 + 1] = f.y; v[s * 4 + 2] = f.z; v[s * 4 + 3] = f.w;
  }
#pragma unroll
  for (int tap = 0; tap < 3; ++tap) {
    ushort o[8];
#pragma unroll
    for (int j = 0; j < 8; ++j) o[j] = f2bf(v[j * 3 + tap]);
    ushort4 a = {o[0], o[1], o[2], o[3]}, b = {o[4], o[5], o[6], o[7]};
    ushort4* q = (ushort4*)(Wt + (size_t)tap * kF * kF + (size_t)co * kF + ci0);
    q[0] = a; q[1] = b;
  }
  if (blockIdx.x == 0 && blockIdx.y == 0) {
    ((float4*)zpage)[threadIdx.x] = (float4){0.f, 0.f, 0.f, 0.f};  // 4 KB zeros
  }
}

// fp32 -> bf16 plain (for wc)
__global__ __launch_bounds__(256) void convert_kernel(
    const float* __restrict__ src, ushort* __restrict__ dst, int n) {
  int i = (blockIdx.x * 256 + threadIdx.x) * 4;
  if (i + 3 < n) {
    float4 f = *(const float4*)(src + i);
    ushort4 o;
    o.x = f2bf(f.x); o.y = f2bf(f.y); o.z = f2bf(f.z); o.w = f2bf(f.w);
    *(ushort4*)(dst + i) = o;
  } else {
    for (; i < n; ++i) dst[i] = f2bf(src[i]);
  }
}

// ---------------------------------------------------------------------------
// x [2][2048][750] fp32 -> xTt [(b*750+t)][2048] bf16
// ---------------------------------------------------------------------------
__global__ __launch_bounds__(256) void transpose_kernel(
    const float* __restrict__ x, ushort* __restrict__ xTt) {
  __shared__ float tile[64][65];
  const int b = blockIdx.z;
  const int t0 = blockIdx.x * 64, f0 = blockIdx.y * 64;
  const int tx = threadIdx.x & 63, ty4 = threadIdx.x >> 6;
#pragma unroll
  for (int i = 0; i < 16; ++i) {
    int lf = ty4 + i * 4;
    int t = t0 + tx;
    tile[lf][tx] = (t < kT) ? x[((size_t)b * kF + f0 + lf) * kT + t] : 0.f;
  }
  __syncthreads();
#pragma unroll
  for (int i = 0; i < 16; ++i) {
    int lt = ty4 + i * 4;
    int t = t0 + lt;
    if (t < kT)
      xTt[(size_t)(b * kT + t) * kF + f0 + tx] = f2bf(tile[tx][lt]);
  }
}

// ---------------------------------------------------------------------------
// xJ[((b*3+g)*2048+f)][j] = x[b][f][j*3+g] bf16, j in [0,256), pad 0
// ---------------------------------------------------------------------------
__global__ __launch_bounds__(256) void xj_kernel(
    const float* __restrict__ x, ushort* __restrict__ xJ) {
  const int bid = blockIdx.x;           // 0..4095
  const int b = bid >> 11, f = bid & 2047;
  __shared__ float buf[768];
  const float* xr = x + ((size_t)b * kF + f) * kT;
  for (int t = threadIdx.x; t < kT; t += 256) buf[t] = xr[t];
  __syncthreads();
  const int j = threadIdx.x;
#pragma unroll
  for (int g = 0; g < 3; ++g) {
    float v = (j < 250) ? buf[j * 3 + g] : 0.f;
    xJ[(((size_t)(b * 3 + g) * kF + f) << 8) + j] = f2bf(v);
  }
}

// ---------------------------------------------------------------------------
// W2[bg][r][j] bf16: r<20 fg rows wa[c=r]; 20<=r<420 bg rows wa[a]*(1-wa[c])
// ---------------------------------------------------------------------------
__global__ __launch_bounds__(256) void ww_build_kernel(
    const float* __restrict__ wab, ushort* __restrict__ W2) {
  const int bg = blockIdx.x;
  const int b = bg / 3, g = bg % 3;
  const int r0 = blockIdx.y * 32;
  __shared__ float ws[kC][256];
  for (int i = threadIdx.x; i < kC * 250; i += 256) {
    int c = i / 250, j = i % 250;
    ws[c][j] = wab[(size_t)(b * kC + c) * kT + j * 3 + g];
  }
  __syncthreads();
  ushort* Wb = W2 + (size_t)bg * 512 * 256;
  const int j = threadIdx.x;
#pragma unroll 4
  for (int rr = 0; rr < 32; ++rr) {
    int r = r0 + rr;
    float v = 0.f;
    if (j < 250 && r < 420) {
      if (r < kC) {
        v = ws[r][j];
      } else {
        int idx = r - kC;
        int c = idx / kC, a = idx % kC;
        v = ws[a][j] * (1.f - ws[c][j]);
      }
    }
    Wb[(size_t)r * 256 + j] = f2bf(v);
  }
}

// ---------------------------------------------------------------------------
// ww GEMM (128x128, 2-phase; small; unchanged)
// ---------------------------------------------------------------------------
__global__ __launch_bounds__(256) void ww_gemm_kernel(
    const ushort* __restrict__ xJ, const ushort* __restrict__ W2,
    ushort* __restrict__ FeatY) {
  __shared__ ushort sA[2][128 * 64];
  __shared__ ushort sB[2][128 * 64];
  const int tid = threadIdx.x;
  const int w = tid >> 6, lane = tid & 63;
  const int wm = w >> 1, wn = w & 1;
  const int bg = blockIdx.z;
  const int f0 = blockIdx.y * 128;
  const int s0 = blockIdx.x * 128;
  const ushort* A = xJ + ((size_t)bg * kF << 8);
  const ushort* Bp = W2 + (size_t)bg * 512 * 256;
  const int srow = lane >> 3;
  const int selem = ((lane & 7) ^ srow) * 8;
  f32x4 acc[4][4];
#pragma unroll
  for (int i = 0; i < 4; ++i)
#pragma unroll
    for (int j = 0; j < 4; ++j) acc[i][j] = (f32x4){0.f, 0.f, 0.f, 0.f};

  auto STAGE = [&](int buf, int kt) {
    const int kin = kt * 64;
#pragma unroll
    for (int i = 0; i < 4; ++i) {
      int r = (w * 4 + i) * 8 + srow;
      gload_lds16(A + (size_t)(f0 + r) * 256 + kin + selem,
                  &sA[buf][(w * 4 + i) * 512]);
    }
#pragma unroll
    for (int i = 0; i < 4; ++i) {
      int r = (w * 4 + i) * 8 + srow;
      gload_lds16(Bp + (size_t)(s0 + r) * 256 + kin + selem,
                  &sB[buf][(w * 4 + i) * 512]);
    }
  };

  STAGE(0, 0);
  asm volatile("s_waitcnt vmcnt(0)" ::: "memory");
  __builtin_amdgcn_s_barrier();

  int cur = 0;
  for (int kt = 0; kt < 4; ++kt) {
    if (kt + 1 < 4) STAGE(cur ^ 1, kt + 1);
#pragma unroll
    for (int ksub = 0; ksub < 2; ++ksub) {
      bf16x8 af[4], bfv[4];
      const int rlow = lane & 7;
#pragma unroll
      for (int fm = 0; fm < 4; ++fm) {
        int row = wm * 64 + fm * 16 + (lane & 15);
        int c16 = (ksub * 4 + (lane >> 4)) ^ rlow;
        af[fm] = *(const bf16x8*)&sA[cur][row * 64 + c16 * 8];
      }
#pragma unroll
      for (int fn = 0; fn < 4; ++fn) {
        int row = wn * 64 + fn * 16 + (lane & 15);
        int c16 = (ksub * 4 + (lane >> 4)) ^ rlow;
        bfv[fn] = *(const bf16x8*)&sB[cur][row * 64 + c16 * 8];
      }
#pragma unroll
      for (int fm = 0; fm < 4; ++fm)
#pragma unroll
        for (int fn = 0; fn < 4; ++fn)
          acc[fm][fn] = __builtin_amdgcn_mfma_f32_16x16x32_bf16(
              af[fm], bfv[fn], acc[fm][fn], 0, 0, 0);
    }
    asm volatile("s_waitcnt vmcnt(0)" ::: "memory");
    __builtin_amdgcn_s_barrier();
    cur ^= 1;
  }

  const int b = bg / 3, g = bg % 3;
#pragma unroll
  for (int fm = 0; fm < 4; ++fm) {
#pragma unroll
    for (int fn = 0; fn < 4; ++fn) {
      int s = s0 + wn * 64 + fn * 16 + (lane & 15);
      if (s >= 420) continue;
      int sampleg = (s < kC) ? (b * kC + s) : (40 + b * 400 + (s - kC));
      int row = f0 + wm * 64 + fm * 16 + ((lane >> 4) << 2);
      ushort4 o;
      o.x = f2bf(acc[fm][fn][0]);
      o.y = f2bf(acc[fm][fn][1]);
      o.z = f2bf(acc[fm][fn][2]);
      o.w = f2bf(acc[fm][fn][3]);
      *(ushort4*)&FeatY[(size_t)(sampleg * 3 + g) * kF + row] = o;
    }
  }
}

// ---------------------------------------------------------------------------
// Direct-conv GEMM, split-K, 256x256 tile, 8 waves (2Mx4N), BK=32.
// 4-slot LDS ring (4 x 32 KB), 3-deep prefetch, counted vmcnt(8), one
// s_barrier per K-step. Two fine phases per step:
//   A: stage-issue A(t+3) || ds_read bfv+af[0..3] -> lgkm(0) -> 16 MFMA
//   B: stage-issue B(t+3) || ds_read af[4..7]     -> lgkm(0) -> 16 MFMA
// Swizzle: seg ^= (row&3)^((row>>2)&3), applied on stage SOURCE and read.
// ---------------------------------------------------------------------------
template <int L>
__global__ __launch_bounds__(512, 1) void gemm_conv_kernel(
    const ushort* __restrict__ A, const ushort* __restrict__ B,
    const ushort* __restrict__ zpage, float* __restrict__ Cpart,
    int ncols, int NP, int ktn_base, int ktrem) {
  extern __shared__ ushort lds[];   // 4 slots x (A 8192 + B 8192) ushorts
  const int tid = threadIdx.x;
  const int wid = tid >> 6, lane = tid & 63;
  const int wr = wid >> 2, wc = wid & 3;
  const int co0 = blockIdx.y * 256;
  const int col0 = blockIdx.x * 256;
  const int z = blockIdx.z;
  const int kt0 = z * ktn_base + (z < ktrem ? z : ktrem);
  const int ktn = ktn_base + (z < ktrem ? 1 : 0);
  const int ktend = kt0 + ktn;
  const int srow_lo = lane >> 2;       // 0..15 row-in-group for staging
  const int sseg = lane & 3;           // 16B seg for staging
  // read-side swizzled seg (lane-only; fm/fn-independent)
  const int seg2 = (((lane >> 4) ^ (lane & 3) ^ ((lane >> 2) & 3))) * 8;
  const int l15 = lane & 15;

  f32x4 acc[8][4];
#pragma unroll
  for (int i = 0; i < 8; ++i)
#pragma unroll
    for (int j = 0; j < 4; ++j) acc[i][j] = (f32x4){0.f, 0.f, 0.f, 0.f};

  auto STAGE_A = [&](int buf, int kt) {
    const int tap = kt >> 6;                 // 64 K-steps of 32 per tap
    const int kin = (kt & 63) * 32;
    const size_t abase = (size_t)tap * kF * kF + kin;
#pragma unroll
    for (int l = 0; l < 2; ++l) {
      int r = l * 128 + wid * 16 + srow_lo;
      int ssrc = ((sseg ^ (r & 3) ^ ((r >> 2) & 3))) * 8;
      gload_lds16(A + abase + (size_t)(co0 + r) * kF + ssrc,
                  &lds[buf * 16384 + l * 4096 + wid * 512]);
    }
  };
  auto STAGE_B = [&](int buf, int kt) {
    const int tap = kt >> 6;
    const int kin = (kt & 63) * 32;
#pragma unroll
    for (int l = 0; l < 2; ++l) {
      int r = l * 128 + wid * 16 + srow_lo;
      int col = col0 + r;
      int t = col - (col / L) * L;
      int tt = t + tap - 1;
      int ssrc = ((sseg ^ (r & 3) ^ ((r >> 2) & 3))) * 8;
      const ushort* src = (col < ncols && tt >= 0 && tt < L)
          ? B + (size_t)(col + tap - 1) * kF + kin + ssrc
          : zpage + ssrc;
      gload_lds16(src, &lds[buf * 16384 + 8192 + l * 4096 + wid * 512]);
    }
  };

  // prologue: stage tiles kt0, kt0+1, kt0+2 (ktn >= 32 always)
  STAGE_A(kt0 & 3, kt0);       STAGE_B(kt0 & 3, kt0);
  STAGE_A((kt0 + 1) & 3, kt0 + 1); STAGE_B((kt0 + 1) & 3, kt0 + 1);
  STAGE_A((kt0 + 2) & 3, kt0 + 2); STAGE_B((kt0 + 2) & 3, kt0 + 2);
  asm volatile("s_waitcnt vmcnt(8)" ::: "memory");   // kt0 landed
  __builtin_amdgcn_s_barrier();
  __builtin_amdgcn_sched_barrier(0);

  for (int kt = kt0; kt < ktend; ++kt) {
    const int buf = kt & 3;
    const int ts = (kt + 3 < ktend) ? kt + 3 : ktend - 1;  // clamped re-stage
    const int bufs = ts & 3;
    const ushort* bb = &lds[buf * 16384];
    bf16x8 bfv[4], af[4];
    // ---- phase A ----
    STAGE_A(bufs, ts);
#pragma unroll
    for (int fn = 0; fn < 4; ++fn)
      bfv[fn] = *(const bf16x8*)&bb[8192 + (wc * 64 + fn * 16 + l15) * 32 + seg2];
#pragma unroll
    for (int fm = 0; fm < 4; ++fm)
      af[fm] = *(const bf16x8*)&bb[(wr * 128 + fm * 16 + l15) * 32 + seg2];
    asm volatile("s_waitcnt lgkmcnt(0)" ::: "memory");
    __builtin_amdgcn_sched_barrier(0);
    __builtin_amdgcn_s_setprio(1);
#pragma unroll
    for (int fm = 0; fm < 4; ++fm)
#pragma unroll
      for (int fn = 0; fn < 4; ++fn)
        acc[fm][fn] = __builtin_amdgcn_mfma_f32_16x16x32_bf16(
            af[fm], bfv[fn], acc[fm][fn], 0, 0, 0);
    __builtin_amdgcn_s_setprio(0);
    // ---- phase B ----
    STAGE_B(bufs, ts);
#pragma unroll
    for (int fm = 0; fm < 4; ++fm)
      af[fm] = *(const bf16x8*)&bb[(wr * 128 + (fm + 4) * 16 + l15) * 32 + seg2];
    asm volatile("s_waitcnt lgkmcnt(0)" ::: "memory");
    __builtin_amdgcn_sched_barrier(0);
    __builtin_amdgcn_s_setprio(1);
#pragma unroll
    for (int fm = 0; fm < 4; ++fm)
#pragma unroll
      for (int fn = 0; fn < 4; ++fn)
        acc[fm + 4][fn] = __builtin_amdgcn_mfma_f32_16x16x32_bf16(
            af[fm], bfv[fn], acc[fm + 4][fn], 0, 0, 0);
    __builtin_amdgcn_s_setprio(0);
    // ---- step boundary: counted drain (t+1 landed), one barrier ----
    asm volatile("s_waitcnt vmcnt(8)" ::: "memory");
    __builtin_amdgcn_s_barrier();
    __builtin_amdgcn_sched_barrier(0);
  }

  float* Cz = Cpart + (size_t)z * NP * kF;
#pragma unroll
  for (int fm = 0; fm < 8; ++fm) {
#pragma unroll
    for (int fn = 0; fn < 4; ++fn) {
      int col = col0 + wc * 64 + fn * 16 + l15;
      int row = co0 + wr * 128 + fm * 16 + ((lane >> 4) << 2);
      *(f32x4*)&Cz[(size_t)col * kF + row] = acc[fm][fn];
    }
  }
}

// ---------------------------------------------------------------------------
// reduce partials over S + bias + leaky -> bf16 [col][2048]
// ---------------------------------------------------------------------------
__global__ __launch_bounds__(256) void reduce_kernel(
    const float* __restrict__ Cpart, const float* __restrict__ bias,
    ushort* __restrict__ Y, int NP, int S) {
  const int col = blockIdx.x;
  const int row0 = (blockIdx.y * 256 + threadIdx.x) * 4;
  f32x4 a = *(const f32x4*)&Cpart[(size_t)col * kF + row0];
  for (int s = 1; s < S; ++s)
    a += *(const f32x4*)&Cpart[((size_t)s * NP + col) * kF + row0];
  f32x4 bv = *(const f32x4*)&bias[row0];
  ushort4 o;
  o.x = f2bf(leaky(a[0] + bv[0]));
  o.y = f2bf(leaky(a[1] + bv[1]));
  o.z = f2bf(leaky(a[2] + bv[2]));
  o.w = f2bf(leaky(a[3] + bv[3]));
  *(ushort4*)&Y[(size_t)col * kF + row0] = o;
}

// ---------------------------------------------------------------------------
// seq[b][c][t] = sum_ci wcb[c][ci] * h2[(b*750+t)][ci]; fused wa = sigmoid(...)
// ---------------------------------------------------------------------------
__global__ __launch_bounds__(256) void seqcas_kernel(
    const ushort* __restrict__ h2, const ushort* __restrict__ wcb,
    const float* __restrict__ watt, const float* __restrict__ batt,
    float* __restrict__ seq, float* __restrict__ wa) {
  const int w = threadIdx.x >> 6, lane = threadIdx.x & 63;
  const int idx = blockIdx.x * 4 + w;
  if (idx >= 2 * kT) return;
  const ushort* hr = h2 + (size_t)idx * kF;
  float acc[kC];
#pragma unroll
  for (int c = 0; c < kC; ++c) acc[c] = 0.f;
#pragma unroll
  for (int ch = 0; ch < 4; ++ch) {
    const int ci0 = ch * 512 + lane * 8;
    ushort4 ha = *(const ushort4*)(hr + ci0);
    ushort4 hb = *(const ushort4*)(hr + ci0 + 4);
    float hx[8] = {bf2f(ha.x), bf2f(ha.y), bf2f(ha.z), bf2f(ha.w),
                   bf2f(hb.x), bf2f(hb.y), bf2f(hb.z), bf2f(hb.w)};
#pragma unroll
    for (int c = 0; c < kC; ++c) {
      const ushort* wr = wcb + c * kF + ci0;
      ushort4 wa4 = *(const ushort4*)wr;
      ushort4 wb4 = *(const ushort4*)(wr + 4);
      acc[c] += bf2f(wa4.x) * hx[0] + bf2f(wa4.y) * hx[1] +
                bf2f(wa4.z) * hx[2] + bf2f(wa4.w) * hx[3] +
                bf2f(wb4.x) * hx[4] + bf2f(wb4.y) * hx[5] +
                bf2f(wb4.z) * hx[6] + bf2f(wb4.w) * hx[7];
    }
  }
#pragma unroll
  for (int off = 32; off; off >>= 1)
#pragma unroll
    for (int c = 0; c < kC; ++c) acc[c] += __shfl_xor(acc[c], off);
  if (lane == 0) {
    int b = idx / kT, t = idx % kT;
#pragma unroll
    for (int c = 0; c < kC; ++c) seq[(size_t)(b * kC + c) * kT + t] = acc[c];
#pragma unroll
    for (int c = 0; c < kC; ++c) {
      float z = batt[c];
#pragma unroll
      for (int a = 0; a < kC; ++a) z += watt[c * kC + a] * acc[a];
      wa[(size_t)(b * kC + c) * kT + t] = 1.f / (1.f + expf(-z));
    }
  }
}

// top-93 mean over T per (b,c) row — one wave per row, barrier-free
__global__ __launch_bounds__(64) void score_pre_kernel(
    const float* __restrict__ seq, float* __restrict__ out) {
  const int n = blockIdx.x;
  const int lane = threadIdx.x;
  float v[12];
#pragma unroll
  for (int i = 0; i < 12; ++i) {
    int idx = lane + i * 64;
    v[i] = (idx < kT) ? seq[(size_t)n * kT + idx] : -1e30f;
  }
  float sum = 0.f;
  for (int it = 0; it < kTop; ++it) {
    float lm = v[0];
#pragma unroll
    for (int i = 1; i < 12; ++i) lm = fmaxf(lm, v[i]);
    float wm = lm;
#pragma unroll
    for (int off = 32; off; off >>= 1) wm = fmaxf(wm, __shfl_xor(wm, off));
    sum += wm;
    unsigned long long ball = __ballot(lm == wm);
    int first = __ffsll(ball) - 1;
    bool own = (lane == first);
    bool done = false;
#pragma unroll
    for (int i = 0; i < 12; ++i) {
      bool hit = own && !done && (v[i] == wm);
      if (hit) { v[i] = -1e30f; done = true; }
    }
  }
  if (lane == 0) out[n] = sum / (float)kTop;
}

// score[n] = (1/3) sum_g sum_co h[(n*3+g)][co] * wc[class(n)][co]
__global__ __launch_bounds__(256) void cls_kernel(
    const ushort* __restrict__ h, const float* __restrict__ wc,
    float* __restrict__ out40, float* __restrict__ scb) {
  __shared__ float red[256];
  const int n = blockIdx.x;
  const int tid = threadIdx.x;
  const int cls = (n < 40) ? (n % kC) : ((n - 40) % kC);
  const int co0 = tid * 8;
  const float4 w0 = *(const float4*)(wc + (size_t)cls * kF + co0);
  const float4 w1 = *(const float4*)(wc + (size_t)cls * kF + co0 + 4);
  float acc = 0.f;
#pragma unroll
  for (int g = 0; g < 3; ++g) {
    const ushort* hr = h + (size_t)(n * 3 + g) * kF + co0;
    ushort4 a = *(const ushort4*)hr;
    ushort4 b4 = *(const ushort4*)(hr + 4);
    acc += bf2f(a.x) * w0.x + bf2f(a.y) * w0.y + bf2f(a.z) * w0.z + bf2f(a.w) * w0.w +
           bf2f(b4.x) * w1.x + bf2f(b4.y) * w1.y + bf2f(b4.z) * w1.z + bf2f(b4.w) * w1.w;
  }
  red[tid] = acc;
  __syncthreads();
  for (int s = 128; s > 0; s >>= 1) {
    if (tid < s) red[tid] += red[tid + s];
    __syncthreads();
  }
  if (tid == 0) {
    float v = red[0] * (1.f / 3.f);
    if (n < 40) out40[n] = v; else scb[n - 40] = v;
  }
}

// collect + concat + softmax -> out[80 + b*40 + i]
__global__ void final_kernel(const float* __restrict__ score_post,
                             const float* __restrict__ sc_buf,
                             const int* __restrict__ label,
                             float* __restrict__ out) {
  __shared__ float z[2 * kC];
  __shared__ float collect[kC];
  const int b = blockIdx.x;
  const int tid = threadIdx.x;
  if (tid < kC) {
    int a = tid;
    float s = 0.f, ngt = 0.f;
    for (int c = 0; c < kC; ++c) {
      float m = label[b * kC + c] > 0 ? 1.f : 0.f;
      ngt += m;
      s += m * sc_buf[b * 400 + c * kC + a];
    }
    if (ngt < 1.f) ngt = 1.f;
    float col = s / ngt;
    if (label[b * kC + a] > 0) col = sc_buf[b * 400 + a * kC + a];
    collect[a] = col;
  }
  __syncthreads();
  if (tid < 2 * kC) z[tid] = (tid < kC) ? score_post[b * kC + tid] : collect[tid - kC];
  __syncthreads();
  if (tid == 0) {
    float mx = z[0];
    for (int i = 1; i < 2 * kC; ++i) mx = fmaxf(mx, z[i]);
    float s = 0.f;
    for (int i = 0; i < 2 * kC; ++i) { z[i] = expf(z[i] - mx); s += z[i]; }
    for (int i = 0; i < 2 * kC; ++i) out[80 + b * 2 * kC + i] = z[i] / s;
  }
}

extern "C" void kernel_launch(void* const* d_in, const int* in_sizes, int n_in,
                              void* d_out, int out_size, void* d_ws, size_t ws_size,
                              hipStream_t stream) {
  (void)in_sizes; (void)n_in; (void)out_size; (void)ws_size;
  const float* x    = (const float*)d_in[0];
  const float* w1   = (const float*)d_in[1];
  const float* b1   = (const float*)d_in[2];
  const float* w2   = (const float*)d_in[3];
  const float* b2   = (const float*)d_in[4];
  const float* wc   = (const float*)d_in[5];
  const float* watt = (const float*)d_in[6];
  const float* batt = (const float*)d_in[7];
  const int*   lbl  = (const int*)d_in[8];
  float* out = (float*)d_out;
  char*  wsb = (char*)d_ws;

  // enable 128 KB dynamic LDS for the big GEMM
  hipFuncSetAttribute(reinterpret_cast<const void*>(&gemm_conv_kernel<750>),
                      hipFuncAttributeMaxDynamicSharedMemorySize, 131072);
  hipFuncSetAttribute(reinterpret_cast<const void*>(&gemm_conv_kernel<3>),
                      hipFuncAttributeMaxDynamicSharedMemorySize, 131072);

  // workspace layout (bytes)
  ushort* Wt1   = (ushort*)(wsb + 0);           // 25,165,824  [3][2048][2048]
  ushort* Wt2   = (ushort*)(wsb + 25165824);    // 25,165,824
  ushort* wcb   = (ushort*)(wsb + 50331648);    // 81,920
  ushort* zpage = (ushort*)(wsb + 50413568);    // 4,096
  ushort* xTt   = (ushort*)(wsb + 50417664);    // 6,144,000
  ushort* xJ    = (ushort*)(wsb + 56561664);    // 6,291,456  [6][2048][256]
  ushort* W2b   = (ushort*)(wsb + 62853120);    // 1,572,864  [6][512][256]
  ushort* Ybuf  = (ushort*)(wsb + 64425984);    // 10,321,920 (Y1 / FeatY / Yp)
  ushort* h2    = (ushort*)(wsb + 74747904);    // 6,144,000
  ushort* hP2   = (ushort*)(wsb + 80891904);    // 10,321,920
  float*  seq   = (float*)(wsb + 91213824);     // 120,000
  float*  wab   = (float*)(wsb + 91333824);     // 120,000
  float*  scb   = (float*)(wsb + 91453824);     // 3,200
  float*  Ppart = (float*)(wsb + 91457536);     // <= 62.9 MB

  const int S_main = 5;  // 240 blocks; 192 K-steps of 32: ktn 39/38 (192=5*38+2)
  const int S_post = 3;  // 240 blocks; ktn 64

  dim3 blk(256);
  convert_w_kernel<<<dim3(2048, 2), blk, 0, stream>>>(w1, w2, Wt1, Wt2, zpage);
  convert_kernel<<<dim3(40), blk, 0, stream>>>(wc, wcb, kC * kF);
  transpose_kernel<<<dim3(12, 32, 2), blk, 0, stream>>>(x, xTt);
  xj_kernel<<<dim3(4096), blk, 0, stream>>>(x, xJ);
  // main conv1
  gemm_conv_kernel<750><<<dim3(6, 8, S_main), dim3(512), 131072, stream>>>(
      Wt1, xTt, zpage, Ppart, 1500, 1536, 38, 2);
  reduce_kernel<<<dim3(1500, 2), blk, 0, stream>>>(Ppart, b1, Ybuf, 1536, S_main);
  // main conv2
  gemm_conv_kernel<750><<<dim3(6, 8, S_main), dim3(512), 131072, stream>>>(
      Wt2, Ybuf, zpage, Ppart, 1500, 1536, 38, 2);
  reduce_kernel<<<dim3(1500, 2), blk, 0, stream>>>(Ppart, b2, h2, 1536, S_main);
  // attention path (wa fused into seqcas)
  seqcas_kernel<<<dim3(375), blk, 0, stream>>>(h2, wcb, watt, batt, seq, wab);
  score_pre_kernel<<<dim3(40), dim3(64), 0, stream>>>(seq, out);  // out[0..39]
  // fg + bg aggregation as MFMA GEMM -> FeatY (Ybuf)
  ww_build_kernel<<<dim3(6, 16), blk, 0, stream>>>(wab, W2b);
  ww_gemm_kernel<<<dim3(4, 16, 6), blk, 0, stream>>>(xJ, W2b, Ybuf);
  // post conv1
  gemm_conv_kernel<3><<<dim3(10, 8, S_post), dim3(512), 131072, stream>>>(
      Wt1, Ybuf, zpage, Ppart, 2520, 2560, 64, 0);
  reduce_kernel<<<dim3(2520, 2), blk, 0, stream>>>(Ppart, b1, Ybuf, 2560, S_post);
  // post conv2
  gemm_conv_kernel<3><<<dim3(10, 8, S_post), dim3(512), 131072, stream>>>(
      Wt2, Ybuf, zpage, Ppart, 2520, 2560, 64, 0);
  reduce_kernel<<<dim3(2520, 2), blk, 0, stream>>>(Ppart, b2, hP2, 2560, S_post);
  // classifiers + final
  cls_kernel<<<dim3(840), blk, 0, stream>>>(hP2, wc, out + 40, scb);
  final_kernel<<<dim3(2), dim3(64), 0, stream>>>(out + 40, scb, lbl, out);
}

// Round 9
// 412.773 us; speedup vs baseline: 20.4901x; 1.0375x over previous
//
#include <hip/hip_runtime.h>
#include <math.h>

// ECMNet on gfx950 — 256x256 8-wave conv-GEMM, BK=32, 4-slot LDS ring,
// 3-deep counted-vmcnt prefetch, paired-row 128B swizzle (R7-proven), XCD remap.
// B=2, F=2048, T=750, C=20, G=3, Tg=250, topK=93
namespace {
constexpr int kF = 2048;
constexpr int kT = 750;
constexpr int kC = 20;
constexpr int kTop = 93;
}

typedef __bf16 bf16x8 __attribute__((ext_vector_type(8)));
typedef float f32x4 __attribute__((ext_vector_type(4)));

__device__ __forceinline__ ushort f2bf(float f) {
  uint u = __builtin_bit_cast(uint, f);
  uint r = u + 0x7FFFu + ((u >> 16) & 1u);
  return (ushort)(r >> 16);
}
__device__ __forceinline__ float bf2f(ushort u) {
  return __builtin_bit_cast(float, ((uint)u) << 16);
}
__device__ __forceinline__ float leaky(float v) { return v > 0.f ? v : 0.01f * v; }

__device__ __forceinline__ void gload_lds16(const ushort* g, ushort* l) {
  __builtin_amdgcn_global_load_lds(
      (const __attribute__((address_space(1))) void*)g,
      (__attribute__((address_space(3))) void*)l, 16, 0, 0);
}

// ---------------------------------------------------------------------------
// weights [co][ci][3] fp32 -> Wt [tap][co][ci] bf16 (both w1,w2); zero page
// ---------------------------------------------------------------------------
__global__ __launch_bounds__(256) void convert_w_kernel(
    const float* __restrict__ w1, const float* __restrict__ w2,
    ushort* __restrict__ Wt1, ushort* __restrict__ Wt2,
    ushort* __restrict__ zpage) {
  const int co = blockIdx.x;
  const float* w = (blockIdx.y == 0) ? w1 : w2;
  ushort* Wt = (blockIdx.y == 0) ? Wt1 : Wt2;
  const int ci0 = threadIdx.x * 8;
  float v[24];
  const float4* p = (const float4*)(w + (size_t)co * 6144 + ci0 * 3);
#pragma unroll
  for (int s = 0; s < 6; ++s) {
    float4 f = p[s];
    v[s * 4 + 0] = f.x; v[s * 4 + 1] = f.y; v[s * 4 + 2] = f.z; v[s * 4 + 3] = f.w;
  }
#pragma unroll
  for (int tap = 0; tap < 3; ++tap) {
    ushort o[8];
#pragma unroll
    for (int j = 0; j < 8; ++j) o[j] = f2bf(v[j * 3 + tap]);
    ushort4 a = {o[0], o[1], o[2], o[3]}, b = {o[4], o[5], o[6], o[7]};
    ushort4* q = (ushort4*)(Wt + (size_t)tap * kF * kF + (size_t)co * kF + ci0);
    q[0] = a; q[1] = b;
  }
  if (blockIdx.x == 0 && blockIdx.y == 0) {
    ((float4*)zpage)[threadIdx.x] = (float4){0.f, 0.f, 0.f, 0.f};  // 4 KB zeros
  }
}

// fp32 -> bf16 plain (for wc)
__global__ __launch_bounds__(256) void convert_kernel(
    const float* __restrict__ src, ushort* __restrict__ dst, int n) {
  int i = (blockIdx.x * 256 + threadIdx.x) * 4;
  if (i + 3 < n) {
    float4 f = *(const float4*)(src + i);
    ushort4 o;
    o.x = f2bf(f.x); o.y = f2bf(f.y); o.z = f2bf(f.z); o.w = f2bf(f.w);
    *(ushort4*)(dst + i) = o;
  } else {
    for (; i < n; ++i) dst[i] = f2bf(src[i]);
  }
}

// ---------------------------------------------------------------------------
// x [2][2048][750] fp32 -> xTt [(b*750+t)][2048] bf16
// ---------------------------------------------------------------------------
__global__ __launch_bounds__(256) void transpose_kernel(
    const float* __restrict__ x, ushort* __restrict__ xTt) {
  __shared__ float tile[64][65];
  const int b = blockIdx.z;
  const int t0 = blockIdx.x * 64, f0 = blockIdx.y * 64;
  const int tx = threadIdx.x & 63, ty4 = threadIdx.x >> 6;
#pragma unroll
  for (int i = 0; i < 16; ++i) {
    int lf = ty4 + i * 4;
    int t = t0 + tx;
    tile[lf][tx] = (t < kT) ? x[((size_t)b * kF + f0 + lf) * kT + t] : 0.f;
  }
  __syncthreads();
#pragma unroll
  for (int i = 0; i < 16; ++i) {
    int lt = ty4 + i * 4;
    int t = t0 + lt;
    if (t < kT)
      xTt[(size_t)(b * kT + t) * kF + f0 + tx] = f2bf(tile[tx][lt]);
  }
}

// ---------------------------------------------------------------------------
// xJ[((b*3+g)*2048+f)][j] = x[b][f][j*3+g] bf16, j in [0,256), pad 0
// ---------------------------------------------------------------------------
__global__ __launch_bounds__(256) void xj_kernel(
    const float* __restrict__ x, ushort* __restrict__ xJ) {
  const int bid = blockIdx.x;           // 0..4095
  const int b = bid >> 11, f = bid & 2047;
  __shared__ float buf[768];
  const float* xr = x + ((size_t)b * kF + f) * kT;
  for (int t = threadIdx.x; t < kT; t += 256) buf[t] = xr[t];
  __syncthreads();
  const int j = threadIdx.x;
#pragma unroll
  for (int g = 0; g < 3; ++g) {
    float v = (j < 250) ? buf[j * 3 + g] : 0.f;
    xJ[(((size_t)(b * 3 + g) * kF + f) << 8) + j] = f2bf(v);
  }
}

// ---------------------------------------------------------------------------
// W2[bg][r][j] bf16: r<20 fg rows wa[c=r]; 20<=r<420 bg rows wa[a]*(1-wa[c])
// ---------------------------------------------------------------------------
__global__ __launch_bounds__(256) void ww_build_kernel(
    const float* __restrict__ wab, ushort* __restrict__ W2) {
  const int bg = blockIdx.x;
  const int b = bg / 3, g = bg % 3;
  const int r0 = blockIdx.y * 32;
  __shared__ float ws[kC][256];
  for (int i = threadIdx.x; i < kC * 250; i += 256) {
    int c = i / 250, j = i % 250;
    ws[c][j] = wab[(size_t)(b * kC + c) * kT + j * 3 + g];
  }
  __syncthreads();
  ushort* Wb = W2 + (size_t)bg * 512 * 256;
  const int j = threadIdx.x;
#pragma unroll 4
  for (int rr = 0; rr < 32; ++rr) {
    int r = r0 + rr;
    float v = 0.f;
    if (j < 250 && r < 420) {
      if (r < kC) {
        v = ws[r][j];
      } else {
        int idx = r - kC;
        int c = idx / kC, a = idx % kC;
        v = ws[a][j] * (1.f - ws[c][j]);
      }
    }
    Wb[(size_t)r * 256 + j] = f2bf(v);
  }
}

// ---------------------------------------------------------------------------
// ww GEMM (128x128, 2-phase; small; unchanged)
// ---------------------------------------------------------------------------
__global__ __launch_bounds__(256) void ww_gemm_kernel(
    const ushort* __restrict__ xJ, const ushort* __restrict__ W2,
    ushort* __restrict__ FeatY) {
  __shared__ ushort sA[2][128 * 64];
  __shared__ ushort sB[2][128 * 64];
  const int tid = threadIdx.x;
  const int w = tid >> 6, lane = tid & 63;
  const int wm = w >> 1, wn = w & 1;
  const int bg = blockIdx.z;
  const int f0 = blockIdx.y * 128;
  const int s0 = blockIdx.x * 128;
  const ushort* A = xJ + ((size_t)bg * kF << 8);
  const ushort* Bp = W2 + (size_t)bg * 512 * 256;
  const int srow = lane >> 3;
  const int selem = ((lane & 7) ^ srow) * 8;
  f32x4 acc[4][4];
#pragma unroll
  for (int i = 0; i < 4; ++i)
#pragma unroll
    for (int j = 0; j < 4; ++j) acc[i][j] = (f32x4){0.f, 0.f, 0.f, 0.f};

  auto STAGE = [&](int buf, int kt) {
    const int kin = kt * 64;
#pragma unroll
    for (int i = 0; i < 4; ++i) {
      int r = (w * 4 + i) * 8 + srow;
      gload_lds16(A + (size_t)(f0 + r) * 256 + kin + selem,
                  &sA[buf][(w * 4 + i) * 512]);
    }
#pragma unroll
    for (int i = 0; i < 4; ++i) {
      int r = (w * 4 + i) * 8 + srow;
      gload_lds16(Bp + (size_t)(s0 + r) * 256 + kin + selem,
                  &sB[buf][(w * 4 + i) * 512]);
    }
  };

  STAGE(0, 0);
  asm volatile("s_waitcnt vmcnt(0)" ::: "memory");
  __builtin_amdgcn_s_barrier();

  int cur = 0;
  for (int kt = 0; kt < 4; ++kt) {
    if (kt + 1 < 4) STAGE(cur ^ 1, kt + 1);
#pragma unroll
    for (int ksub = 0; ksub < 2; ++ksub) {
      bf16x8 af[4], bfv[4];
      const int rlow = lane & 7;
#pragma unroll
      for (int fm = 0; fm < 4; ++fm) {
        int row = wm * 64 + fm * 16 + (lane & 15);
        int c16 = (ksub * 4 + (lane >> 4)) ^ rlow;
        af[fm] = *(const bf16x8*)&sA[cur][row * 64 + c16 * 8];
      }
#pragma unroll
      for (int fn = 0; fn < 4; ++fn) {
        int row = wn * 64 + fn * 16 + (lane & 15);
        int c16 = (ksub * 4 + (lane >> 4)) ^ rlow;
        bfv[fn] = *(const bf16x8*)&sB[cur][row * 64 + c16 * 8];
      }
#pragma unroll
      for (int fm = 0; fm < 4; ++fm)
#pragma unroll
        for (int fn = 0; fn < 4; ++fn)
          acc[fm][fn] = __builtin_amdgcn_mfma_f32_16x16x32_bf16(
              af[fm], bfv[fn], acc[fm][fn], 0, 0, 0);
    }
    asm volatile("s_waitcnt vmcnt(0)" ::: "memory");
    __builtin_amdgcn_s_barrier();
    cur ^= 1;
  }

  const int b = bg / 3, g = bg % 3;
#pragma unroll
  for (int fm = 0; fm < 4; ++fm) {
#pragma unroll
    for (int fn = 0; fn < 4; ++fn) {
      int s = s0 + wn * 64 + fn * 16 + (lane & 15);
      if (s >= 420) continue;
      int sampleg = (s < kC) ? (b * kC + s) : (40 + b * 400 + (s - kC));
      int row = f0 + wm * 64 + fm * 16 + ((lane >> 4) << 2);
      ushort4 o;
      o.x = f2bf(acc[fm][fn][0]);
      o.y = f2bf(acc[fm][fn][1]);
      o.z = f2bf(acc[fm][fn][2]);
      o.w = f2bf(acc[fm][fn][3]);
      *(ushort4*)&FeatY[(size_t)(sampleg * 3 + g) * kF + row] = o;
    }
  }
}

// ---------------------------------------------------------------------------
// Direct-conv GEMM, split-K, 256x256 tile, 8 waves (2Mx4N), BK=32.
// 4-slot LDS ring, 3-deep prefetch, counted vmcnt(8), 1 barrier/K-step.
// LDS tile layout: 128 pseudo-rows x 128B; pseudo-row p = m>>1, inner code
// lin = (m&1)*4 + q (q = 16B k-seg), stored at seg8 = lin ^ (p&7)  — the
// R7-proven conflict-free geometry. Stage source decodes inverse permutation
// (linear gload_lds dest); read applies the same XOR. XCD-aware block remap.
// ---------------------------------------------------------------------------
template <int L>
__global__ __launch_bounds__(512, 1) void gemm_conv_kernel(
    const ushort* __restrict__ A, const ushort* __restrict__ B,
    const ushort* __restrict__ zpage, float* __restrict__ Cpart,
    int ncols, int NP, int ktn_base, int ktrem) {
  extern __shared__ ushort lds[];   // 4 slots x (A 8192 + B 8192 ushorts)
  const int tid = threadIdx.x;
  const int wid = tid >> 6, lane = tid & 63;
  const int wr = wid >> 2, wc = wid & 3;
  // XCD-aware bijective remap (nwg % 8 == 0 by launch config)
  const int gx = gridDim.x, gy = gridDim.y;
  const int nwg = gx * gy * gridDim.z;
  const int h = blockIdx.x + gx * (blockIdx.y + gy * blockIdx.z);
  const int lgc = (h & 7) * (nwg >> 3) + (h >> 3);
  const int bx = lgc % gx;
  const int byz = lgc / gx;
  const int co0 = (byz % gy) * 256;
  const int col0 = bx * 256;
  const int z = byz / gy;
  const int kt0 = z * ktn_base + (z < ktrem ? z : ktrem);
  const int ktn = ktn_base + (z < ktrem ? 1 : 0);
  const int ktend = kt0 + ktn;

  // stage-side inverse-permutation decode (lane constants)
  const int pofs = lane >> 3;                 // pseudo-row within wave-load
  const int lin_s = (lane & 7) ^ pofs;        // (m&1)*4 + q code
  const int mofs = 2 * pofs + (lin_s >> 2);   // m-row within wave-load (0..15)
  const int qseg = (lin_s & 3) * 8;           // k-elem offset (ushorts)
  // read-side swizzled offset (lane constant)
  const int l15 = lane & 15;
  const int seg8 = ((((l15 & 1) << 2) + (lane >> 4)) ^ (l15 >> 1)) * 8;
  const int off_rl = (l15 >> 1) * 64 + seg8;

  f32x4 acc[8][4];
#pragma unroll
  for (int i = 0; i < 8; ++i)
#pragma unroll
    for (int j = 0; j < 4; ++j) acc[i][j] = (f32x4){0.f, 0.f, 0.f, 0.f};

  auto STAGE_A = [&](int buf, int kt) {
    const int tap = kt >> 6;                 // 64 K-steps of 32 per tap
    const int kin = (kt & 63) * 32;
    const size_t abase = (size_t)tap * kF * kF + kin + qseg;
#pragma unroll
    for (int l = 0; l < 2; ++l) {
      int m = l * 128 + wid * 16 + mofs;
      gload_lds16(A + abase + (size_t)(co0 + m) * kF,
                  &lds[buf * 16384 + l * 4096 + wid * 512]);
    }
  };
  auto STAGE_B = [&](int buf, int kt) {
    const int tap = kt >> 6;
    const int kin = (kt & 63) * 32;
#pragma unroll
    for (int l = 0; l < 2; ++l) {
      int m = l * 128 + wid * 16 + mofs;
      int col = col0 + m;
      int t = col - (col / L) * L;
      int tt = t + tap - 1;
      const ushort* src = (col < ncols && tt >= 0 && tt < L)
          ? B + (size_t)(col + tap - 1) * kF + kin + qseg
          : zpage + qseg;
      gload_lds16(src, &lds[buf * 16384 + 8192 + l * 4096 + wid * 512]);
    }
  };

  // prologue: stage tiles kt0, kt0+1, kt0+2 (ktn >= 4 always)
  STAGE_A(kt0 & 3, kt0);           STAGE_B(kt0 & 3, kt0);
  STAGE_A((kt0 + 1) & 3, kt0 + 1); STAGE_B((kt0 + 1) & 3, kt0 + 1);
  STAGE_A((kt0 + 2) & 3, kt0 + 2); STAGE_B((kt0 + 2) & 3, kt0 + 2);
  asm volatile("s_waitcnt vmcnt(8)" ::: "memory");   // kt0 landed
  __builtin_amdgcn_s_barrier();
  __builtin_amdgcn_sched_barrier(0);

  for (int kt = kt0; kt < ktend; ++kt) {
    const int buf = kt & 3;
    const int ts = (kt + 3 < ktend) ? kt + 3 : ktend - 1;  // clamped re-stage
    const int bufs = ts & 3;
    const ushort* bb = &lds[buf * 16384];
    bf16x8 bfv[4], af[4];
    // ---- phase A: issue A-stage || read B frags + A[0..3] -> 16 MFMA ----
    STAGE_A(bufs, ts);
#pragma unroll
    for (int fn = 0; fn < 4; ++fn)
      bfv[fn] = *(const bf16x8*)&bb[8192 + wc * 2048 + fn * 512 + off_rl];
#pragma unroll
    for (int fm = 0; fm < 4; ++fm)
      af[fm] = *(const bf16x8*)&bb[wr * 4096 + fm * 512 + off_rl];
    asm volatile("s_waitcnt lgkmcnt(0)" ::: "memory");
    __builtin_amdgcn_sched_barrier(0);
    __builtin_amdgcn_s_setprio(1);
#pragma unroll
    for (int fm = 0; fm < 4; ++fm)
#pragma unroll
      for (int fn = 0; fn < 4; ++fn)
        acc[fm][fn] = __builtin_amdgcn_mfma_f32_16x16x32_bf16(
            af[fm], bfv[fn], acc[fm][fn], 0, 0, 0);
    __builtin_amdgcn_s_setprio(0);
    // ---- phase B: issue B-stage || read A[4..7] -> 16 MFMA ----
    STAGE_B(bufs, ts);
#pragma unroll
    for (int fm = 0; fm < 4; ++fm)
      af[fm] = *(const bf16x8*)&bb[wr * 4096 + (fm + 4) * 512 + off_rl];
    asm volatile("s_waitcnt lgkmcnt(0)" ::: "memory");
    __builtin_amdgcn_sched_barrier(0);
    __builtin_amdgcn_s_setprio(1);
#pragma unroll
    for (int fm = 0; fm < 4; ++fm)
#pragma unroll
      for (int fn = 0; fn < 4; ++fn)
        acc[fm + 4][fn] = __builtin_amdgcn_mfma_f32_16x16x32_bf16(
            af[fm], bfv[fn], acc[fm + 4][fn], 0, 0, 0);
    __builtin_amdgcn_s_setprio(0);
    // ---- step boundary: counted drain (t+1 landed), one barrier ----
    asm volatile("s_waitcnt vmcnt(8)" ::: "memory");
    __builtin_amdgcn_s_barrier();
    __builtin_amdgcn_sched_barrier(0);
  }

  float* Cz = Cpart + (size_t)z * NP * kF;
#pragma unroll
  for (int fm = 0; fm < 8; ++fm) {
#pragma unroll
    for (int fn = 0; fn < 4; ++fn) {
      int col = col0 + wc * 64 + fn * 16 + l15;
      int row = co0 + wr * 128 + fm * 16 + ((lane >> 4) << 2);
      *(f32x4*)&Cz[(size_t)col * kF + row] = acc[fm][fn];
    }
  }
}

// ---------------------------------------------------------------------------
// reduce partials over S + bias + leaky -> bf16 [col][2048]
// ---------------------------------------------------------------------------
__global__ __launch_bounds__(256) void reduce_kernel(
    const float* __restrict__ Cpart, const float* __restrict__ bias,
    ushort* __restrict__ Y, int NP, int S) {
  const int col = blockIdx.x;
  const int row0 = (blockIdx.y * 256 + threadIdx.x) * 4;
  f32x4 a = *(const f32x4*)&Cpart[(size_t)col * kF + row0];
  for (int s = 1; s < S; ++s)
    a += *(const f32x4*)&Cpart[((size_t)s * NP + col) * kF + row0];
  f32x4 bv = *(const f32x4*)&bias[row0];
  ushort4 o;
  o.x = f2bf(leaky(a[0] + bv[0]));
  o.y = f2bf(leaky(a[1] + bv[1]));
  o.z = f2bf(leaky(a[2] + bv[2]));
  o.w = f2bf(leaky(a[3] + bv[3]));
  *(ushort4*)&Y[(size_t)col * kF + row0] = o;
}

// ---------------------------------------------------------------------------
// seq[b][c][t] = sum_ci wcb[c][ci] * h2[(b*750+t)][ci]; fused wa = sigmoid(...)
// ---------------------------------------------------------------------------
__global__ __launch_bounds__(256) void seqcas_kernel(
    const ushort* __restrict__ h2, const ushort* __restrict__ wcb,
    const float* __restrict__ watt, const float* __restrict__ batt,
    float* __restrict__ seq, float* __restrict__ wa) {
  const int w = threadIdx.x >> 6, lane = threadIdx.x & 63;
  const int idx = blockIdx.x * 4 + w;
  if (idx >= 2 * kT) return;
  const ushort* hr = h2 + (size_t)idx * kF;
  float acc[kC];
#pragma unroll
  for (int c = 0; c < kC; ++c) acc[c] = 0.f;
#pragma unroll
  for (int ch = 0; ch < 4; ++ch) {
    const int ci0 = ch * 512 + lane * 8;
    ushort4 ha = *(const ushort4*)(hr + ci0);
    ushort4 hb = *(const ushort4*)(hr + ci0 + 4);
    float hx[8] = {bf2f(ha.x), bf2f(ha.y), bf2f(ha.z), bf2f(ha.w),
                   bf2f(hb.x), bf2f(hb.y), bf2f(hb.z), bf2f(hb.w)};
#pragma unroll
    for (int c = 0; c < kC; ++c) {
      const ushort* wr = wcb + c * kF + ci0;
      ushort4 wa4 = *(const ushort4*)wr;
      ushort4 wb4 = *(const ushort4*)(wr + 4);
      acc[c] += bf2f(wa4.x) * hx[0] + bf2f(wa4.y) * hx[1] +
                bf2f(wa4.z) * hx[2] + bf2f(wa4.w) * hx[3] +
                bf2f(wb4.x) * hx[4] + bf2f(wb4.y) * hx[5] +
                bf2f(wb4.z) * hx[6] + bf2f(wb4.w) * hx[7];
    }
  }
#pragma unroll
  for (int off = 32; off; off >>= 1)
#pragma unroll
    for (int c = 0; c < kC; ++c) acc[c] += __shfl_xor(acc[c], off);
  if (lane == 0) {
    int b = idx / kT, t = idx % kT;
#pragma unroll
    for (int c = 0; c < kC; ++c) seq[(size_t)(b * kC + c) * kT + t] = acc[c];
#pragma unroll
    for (int c = 0; c < kC; ++c) {
      float z = batt[c];
#pragma unroll
      for (int a = 0; a < kC; ++a) z += watt[c * kC + a] * acc[a];
      wa[(size_t)(b * kC + c) * kT + t] = 1.f / (1.f + expf(-z));
    }
  }
}

// top-93 mean over T per (b,c) row — one wave per row, barrier-free
__global__ __launch_bounds__(64) void score_pre_kernel(
    const float* __restrict__ seq, float* __restrict__ out) {
  const int n = blockIdx.x;
  const int lane = threadIdx.x;
  float v[12];
#pragma unroll
  for (int i = 0; i < 12; ++i) {
    int idx = lane + i * 64;
    v[i] = (idx < kT) ? seq[(size_t)n * kT + idx] : -1e30f;
  }
  float sum = 0.f;
  for (int it = 0; it < kTop; ++it) {
    float lm = v[0];
#pragma unroll
    for (int i = 1; i < 12; ++i) lm = fmaxf(lm, v[i]);
    float wm = lm;
#pragma unroll
    for (int off = 32; off; off >>= 1) wm = fmaxf(wm, __shfl_xor(wm, off));
    sum += wm;
    unsigned long long ball = __ballot(lm == wm);
    int first = __ffsll(ball) - 1;
    bool own = (lane == first);
    bool done = false;
#pragma unroll
    for (int i = 0; i < 12; ++i) {
      bool hit = own && !done && (v[i] == wm);
      if (hit) { v[i] = -1e30f; done = true; }
    }
  }
  if (lane == 0) out[n] = sum / (float)kTop;
}

// score[n] = (1/3) sum_g sum_co h[(n*3+g)][co] * wc[class(n)][co]
__global__ __launch_bounds__(256) void cls_kernel(
    const ushort* __restrict__ h, const float* __restrict__ wc,
    float* __restrict__ out40, float* __restrict__ scb) {
  __shared__ float red[256];
  const int n = blockIdx.x;
  const int tid = threadIdx.x;
  const int cls = (n < 40) ? (n % kC) : ((n - 40) % kC);
  const int co0 = tid * 8;
  const float4 w0 = *(const float4*)(wc + (size_t)cls * kF + co0);
  const float4 w1 = *(const float4*)(wc + (size_t)cls * kF + co0 + 4);
  float acc = 0.f;
#pragma unroll
  for (int g = 0; g < 3; ++g) {
    const ushort* hr = h + (size_t)(n * 3 + g) * kF + co0;
    ushort4 a = *(const ushort4*)hr;
    ushort4 b4 = *(const ushort4*)(hr + 4);
    acc += bf2f(a.x) * w0.x + bf2f(a.y) * w0.y + bf2f(a.z) * w0.z + bf2f(a.w) * w0.w +
           bf2f(b4.x) * w1.x + bf2f(b4.y) * w1.y + bf2f(b4.z) * w1.z + bf2f(b4.w) * w1.w;
  }
  red[tid] = acc;
  __syncthreads();
  for (int s = 128; s > 0; s >>= 1) {
    if (tid < s) red[tid] += red[tid + s];
    __syncthreads();
  }
  if (tid == 0) {
    float v = red[0] * (1.f / 3.f);
    if (n < 40) out40[n] = v; else scb[n - 40] = v;
  }
}

// collect + concat + softmax -> out[80 + b*40 + i]
__global__ void final_kernel(const float* __restrict__ score_post,
                             const float* __restrict__ sc_buf,
                             const int* __restrict__ label,
                             float* __restrict__ out) {
  __shared__ float z[2 * kC];
  __shared__ float collect[kC];
  const int b = blockIdx.x;
  const int tid = threadIdx.x;
  if (tid < kC) {
    int a = tid;
    float s = 0.f, ngt = 0.f;
    for (int c = 0; c < kC; ++c) {
      float m = label[b * kC + c] > 0 ? 1.f : 0.f;
      ngt += m;
      s += m * sc_buf[b * 400 + c * kC + a];
    }
    if (ngt < 1.f) ngt = 1.f;
    float col = s / ngt;
    if (label[b * kC + a] > 0) col = sc_buf[b * 400 + a * kC + a];
    collect[a] = col;
  }
  __syncthreads();
  if (tid < 2 * kC) z[tid] = (tid < kC) ? score_post[b * kC + tid] : collect[tid - kC];
  __syncthreads();
  if (tid == 0) {
    float mx = z[0];
    for (int i = 1; i < 2 * kC; ++i) mx = fmaxf(mx, z[i]);
    float s = 0.f;
    for (int i = 0; i < 2 * kC; ++i) { z[i] = expf(z[i] - mx); s += z[i]; }
    for (int i = 0; i < 2 * kC; ++i) out[80 + b * 2 * kC + i] = z[i] / s;
  }
}

extern "C" void kernel_launch(void* const* d_in, const int* in_sizes, int n_in,
                              void* d_out, int out_size, void* d_ws, size_t ws_size,
                              hipStream_t stream) {
  (void)in_sizes; (void)n_in; (void)out_size; (void)ws_size;
  const float* x    = (const float*)d_in[0];
  const float* w1   = (const float*)d_in[1];
  const float* b1   = (const float*)d_in[2];
  const float* w2   = (const float*)d_in[3];
  const float* b2   = (const float*)d_in[4];
  const float* wc   = (const float*)d_in[5];
  const float* watt = (const float*)d_in[6];
  const float* batt = (const float*)d_in[7];
  const int*   lbl  = (const int*)d_in[8];
  float* out = (float*)d_out;
  char*  wsb = (char*)d_ws;

  // enable 128 KB dynamic LDS for the big GEMM
  hipFuncSetAttribute(reinterpret_cast<const void*>(&gemm_conv_kernel<750>),
                      hipFuncAttributeMaxDynamicSharedMemorySize, 131072);
  hipFuncSetAttribute(reinterpret_cast<const void*>(&gemm_conv_kernel<3>),
                      hipFuncAttributeMaxDynamicSharedMemorySize, 131072);

  // workspace layout (bytes)
  ushort* Wt1   = (ushort*)(wsb + 0);           // 25,165,824  [3][2048][2048]
  ushort* Wt2   = (ushort*)(wsb + 25165824);    // 25,165,824
  ushort* wcb   = (ushort*)(wsb + 50331648);    // 81,920
  ushort* zpage = (ushort*)(wsb + 50413568);    // 4,096
  ushort* xTt   = (ushort*)(wsb + 50417664);    // 6,144,000
  ushort* xJ    = (ushort*)(wsb + 56561664);    // 6,291,456  [6][2048][256]
  ushort* W2b   = (ushort*)(wsb + 62853120);    // 1,572,864  [6][512][256]
  ushort* Ybuf  = (ushort*)(wsb + 64425984);    // 10,321,920 (Y1 / FeatY / Yp)
  ushort* h2    = (ushort*)(wsb + 74747904);    // 6,144,000
  ushort* hP2   = (ushort*)(wsb + 80891904);    // 10,321,920
  float*  seq   = (float*)(wsb + 91213824);     // 120,000
  float*  wab   = (float*)(wsb + 91333824);     // 120,000
  float*  scb   = (float*)(wsb + 91453824);     // 3,200
  float*  Ppart = (float*)(wsb + 91457536);     // <= 62.9 MB

  const int S_main = 5;  // 240 blocks; 192 K-steps of 32: ktn 39/38
  const int S_post = 3;  // 240 blocks; ktn 64

  dim3 blk(256);
  convert_w_kernel<<<dim3(2048, 2), blk, 0, stream>>>(w1, w2, Wt1, Wt2, zpage);
  convert_kernel<<<dim3(40), blk, 0, stream>>>(wc, wcb, kC * kF);
  transpose_kernel<<<dim3(12, 32, 2), blk, 0, stream>>>(x, xTt);
  xj_kernel<<<dim3(4096), blk, 0, stream>>>(x, xJ);
  // main conv1
  gemm_conv_kernel<750><<<dim3(6, 8, S_main), dim3(512), 131072, stream>>>(
      Wt1, xTt, zpage, Ppart, 1500, 1536, 38, 2);
  reduce_kernel<<<dim3(1500, 2), blk, 0, stream>>>(Ppart, b1, Ybuf, 1536, S_main);
  // main conv2
  gemm_conv_kernel<750><<<dim3(6, 8, S_main), dim3(512), 131072, stream>>>(
      Wt2, Ybuf, zpage, Ppart, 1500, 1536, 38, 2);
  reduce_kernel<<<dim3(1500, 2), blk, 0, stream>>>(Ppart, b2, h2, 1536, S_main);
  // attention path (wa fused into seqcas)
  seqcas_kernel<<<dim3(375), blk, 0, stream>>>(h2, wcb, watt, batt, seq, wab);
  score_pre_kernel<<<dim3(40), dim3(64), 0, stream>>>(seq, out);  // out[0..39]
  // fg + bg aggregation as MFMA GEMM -> FeatY (Ybuf)
  ww_build_kernel<<<dim3(6, 16), blk, 0, stream>>>(wab, W2b);
  ww_gemm_kernel<<<dim3(4, 16, 6), blk, 0, stream>>>(xJ, W2b, Ybuf);
  // post conv1
  gemm_conv_kernel<3><<<dim3(10, 8, S_post), dim3(512), 131072, stream>>>(
      Wt1, Ybuf, zpage, Ppart, 2520, 2560, 64, 0);
  reduce_kernel<<<dim3(2520, 2), blk, 0, stream>>>(Ppart, b1, Ybuf, 2560, S_post);
  // post conv2
  gemm_conv_kernel<3><<<dim3(10, 8, S_post), dim3(512), 131072, stream>>>(
      Wt2, Ybuf, zpage, Ppart, 2520, 2560, 64, 0);
  reduce_kernel<<<dim3(2520, 2), blk, 0, stream>>>(Ppart, b2, hP2, 2560, S_post);
  // classifiers + final
  cls_kernel<<<dim3(840), blk, 0, stream>>>(hP2, wc, out + 40, scb);
  final_kernel<<<dim3(2), dim3(64), 0, stream>>>(out + 40, scb, lbl, out);
}